// Round 1
// baseline (4413.197 us; speedup 1.0000x reference)
//
#include <hip/hip_runtime.h>
#include <math.h>

#define L_SEQ 4000
#define DM 768
#define DI 1536
#define DS 16
#define DTRK 48

__device__ __forceinline__ float silu_f(float x) { return x / (1.f + __expf(-x)); }
__device__ __forceinline__ float softplus_f(float x) {
  return fmaxf(x, 0.f) + log1pf(__expf(-fabsf(x)));
}
__device__ __forceinline__ int map_t(int branch, int t) {
  if (branch == 0) return t;
  if (branch == 1) return L_SEQ - 1 - t;
  return (t % 5) * 800 + t / 5;
}

// ---------------- K1: xz[b][e][l] = sum_d hs[b][l][d] * W[e][d] ----------------
__global__ __launch_bounds__(256) void k_inproj(const float* __restrict__ hs,
                                                const float* __restrict__ W,
                                                float* __restrict__ xz) {
  __shared__ float Es[16][68];  // [k][e-local]
  __shared__ float Ls[16][68];  // [k][l-local]
  int b = blockIdx.z;
  int e0 = blockIdx.y * 64;
  int l0 = blockIdx.x * 64;
  int tx = threadIdx.x, ty = threadIdx.y;
  int tid = ty * 16 + tx;
  float acc[4][4] = {};  // [e_i][l_j]
  for (int k0 = 0; k0 < DM; k0 += 16) {
    {
      int row = tid >> 2;           // e-local 0..63
      int c4 = (tid & 3) * 4;       // k offset
      float4 v = *(const float4*)&W[(size_t)(e0 + row) * DM + k0 + c4];
      Es[c4 + 0][row] = v.x; Es[c4 + 1][row] = v.y;
      Es[c4 + 2][row] = v.z; Es[c4 + 3][row] = v.w;
    }
    {
      int row = tid >> 2;           // l-local
      int c4 = (tid & 3) * 4;
      int l = l0 + row;
      float4 v = make_float4(0.f, 0.f, 0.f, 0.f);
      if (l < L_SEQ) v = *(const float4*)&hs[((size_t)b * L_SEQ + l) * DM + k0 + c4];
      Ls[c4 + 0][row] = v.x; Ls[c4 + 1][row] = v.y;
      Ls[c4 + 2][row] = v.z; Ls[c4 + 3][row] = v.w;
    }
    __syncthreads();
#pragma unroll
    for (int k = 0; k < 16; ++k) {
      float a0 = Es[k][tx * 4 + 0], a1 = Es[k][tx * 4 + 1];
      float a2 = Es[k][tx * 4 + 2], a3 = Es[k][tx * 4 + 3];
      float b0 = Ls[k][ty * 4 + 0], b1 = Ls[k][ty * 4 + 1];
      float b2 = Ls[k][ty * 4 + 2], b3 = Ls[k][ty * 4 + 3];
      acc[0][0] += a0 * b0; acc[0][1] += a0 * b1; acc[0][2] += a0 * b2; acc[0][3] += a0 * b3;
      acc[1][0] += a1 * b0; acc[1][1] += a1 * b1; acc[1][2] += a1 * b2; acc[1][3] += a1 * b3;
      acc[2][0] += a2 * b0; acc[2][1] += a2 * b1; acc[2][2] += a2 * b2; acc[2][3] += a2 * b3;
      acc[3][0] += a3 * b0; acc[3][1] += a3 * b1; acc[3][2] += a3 * b2; acc[3][3] += a3 * b3;
    }
    __syncthreads();
  }
  int lw = l0 + ty * 4;
  if (lw < L_SEQ) {
#pragma unroll
    for (int i = 0; i < 4; ++i) {
      int e = e0 + tx * 4 + i;
      float4 o = make_float4(acc[i][0], acc[i][1], acc[i][2], acc[i][3]);
      *(float4*)&xz[((size_t)b * 2 * DI + e) * L_SEQ + lw] = o;
    }
  }
}

// ---------------- K2: depthwise causal conv (branch-remapped time) + silu ----------------
__global__ __launch_bounds__(256) void k_conv(const float* __restrict__ xz,
                                              const float* __restrict__ cw,
                                              float* __restrict__ x_act, int branch) {
  int b = blockIdx.z, d = blockIdx.y;
  int t = blockIdx.x * 256 + threadIdx.x;
  if (t >= L_SEQ) return;
  const float* xrow = xz + ((size_t)b * 2 * DI + d) * L_SEQ;
  float w0 = cw[d * 4 + 0], w1 = cw[d * 4 + 1], w2 = cw[d * 4 + 2], w3 = cw[d * 4 + 3];
  float acc = 0.f;
  int tt;
  tt = t - 3; if (tt >= 0) acc += w0 * xrow[map_t(branch, tt)];
  tt = t - 2; if (tt >= 0) acc += w1 * xrow[map_t(branch, tt)];
  tt = t - 1; if (tt >= 0) acc += w2 * xrow[map_t(branch, tt)];
  acc += w3 * xrow[map_t(branch, t)];
  x_act[((size_t)b * DI + d) * L_SEQ + t] = silu_f(acc);
}

// ---------------- K3: x_dbl[b][j][t] = sum_d xpw[j][d] * x_act[b][d][t], j<80 ----------------
__global__ __launch_bounds__(256) void k_xproj(const float* __restrict__ x_act,
                                               const float* __restrict__ xpw,
                                               float* __restrict__ x_dbl) {
  __shared__ float As[16][68];  // [k][t-local]
  __shared__ float Bs[16][84];  // [k][j]
  int b = blockIdx.y;
  int t0 = blockIdx.x * 64;
  int tid = threadIdx.x;
  int txq = tid & 15;  // t-quad
  int jy = tid >> 4;   // 0..15 -> j base jy*5
  float acc[5][4] = {};
  for (int d0 = 0; d0 < DI; d0 += 16) {
    {
      int row = tid >> 4;        // k 0..15
      int c4 = (tid & 15) * 4;   // t offset
      int t = t0 + c4;
      float4 v = make_float4(0.f, 0.f, 0.f, 0.f);
      if (t < L_SEQ) v = *(const float4*)&x_act[((size_t)b * DI + d0 + row) * L_SEQ + t];
      *(float4*)&As[row][c4] = v;
    }
    for (int i = tid; i < 320; i += 256) {
      int row = i >> 2;          // j 0..79
      int c4 = (i & 3) * 4;      // k offset
      float4 v = *(const float4*)&xpw[(size_t)row * DI + d0 + c4];
      Bs[c4 + 0][row] = v.x; Bs[c4 + 1][row] = v.y;
      Bs[c4 + 2][row] = v.z; Bs[c4 + 3][row] = v.w;
    }
    __syncthreads();
#pragma unroll
    for (int k = 0; k < 16; ++k) {
      float a0 = As[k][txq * 4 + 0], a1 = As[k][txq * 4 + 1];
      float a2 = As[k][txq * 4 + 2], a3 = As[k][txq * 4 + 3];
#pragma unroll
      for (int jj = 0; jj < 5; ++jj) {
        float bv = Bs[k][jy * 5 + jj];
        acc[jj][0] += bv * a0; acc[jj][1] += bv * a1;
        acc[jj][2] += bv * a2; acc[jj][3] += bv * a3;
      }
    }
    __syncthreads();
  }
  int t = t0 + txq * 4;
  if (t < L_SEQ) {
#pragma unroll
    for (int jj = 0; jj < 5; ++jj) {
      int j = jy * 5 + jj;
      float4 o = make_float4(acc[jj][0], acc[jj][1], acc[jj][2], acc[jj][3]);
      *(float4*)&x_dbl[((size_t)b * 80 + j) * L_SEQ + t] = o;
    }
  }
}

// ---------------- K4: delta = softplus(dpw @ dtr + bias) ----------------
__global__ __launch_bounds__(256) void k_dt(const float* __restrict__ x_dbl,
                                            const float* __restrict__ dpw,
                                            const float* __restrict__ dbias,
                                            float* __restrict__ delta) {
  __shared__ float Rs[48][68];  // [r][t-local]
  __shared__ float Ps[48][68];  // [r][dch-local]
  int b = blockIdx.z;
  int dch0 = blockIdx.y * 64;
  int t0 = blockIdx.x * 64;
  int tx = threadIdx.x, ty = threadIdx.y;
  int tid = ty * 16 + tx;
  float acc[4][4] = {};  // [dch_i][t_j]
#pragma unroll
  for (int p = 0; p < 3; ++p) {
    int i = tid + p * 256;
    int row = i >> 4;          // r 0..47
    int c4 = (i & 15) * 4;     // t
    int t = t0 + c4;
    float4 v = make_float4(0.f, 0.f, 0.f, 0.f);
    if (t < L_SEQ) v = *(const float4*)&x_dbl[((size_t)b * 80 + row) * L_SEQ + t];
    *(float4*)&Rs[row][c4] = v;
  }
#pragma unroll
  for (int p = 0; p < 3; ++p) {
    int i = tid + p * 256;
    int row = i / 12;          // dch-local 0..63
    int c4 = (i % 12) * 4;     // r
    float4 v = *(const float4*)&dpw[(size_t)(dch0 + row) * DTRK + c4];
    Ps[c4 + 0][row] = v.x; Ps[c4 + 1][row] = v.y;
    Ps[c4 + 2][row] = v.z; Ps[c4 + 3][row] = v.w;
  }
  __syncthreads();
#pragma unroll 4
  for (int r = 0; r < 48; ++r) {
    float a0 = Rs[r][tx * 4 + 0], a1 = Rs[r][tx * 4 + 1];
    float a2 = Rs[r][tx * 4 + 2], a3 = Rs[r][tx * 4 + 3];
    float b0 = Ps[r][ty * 4 + 0], b1 = Ps[r][ty * 4 + 1];
    float b2 = Ps[r][ty * 4 + 2], b3 = Ps[r][ty * 4 + 3];
    acc[0][0] += b0 * a0; acc[0][1] += b0 * a1; acc[0][2] += b0 * a2; acc[0][3] += b0 * a3;
    acc[1][0] += b1 * a0; acc[1][1] += b1 * a1; acc[1][2] += b1 * a2; acc[1][3] += b1 * a3;
    acc[2][0] += b2 * a0; acc[2][1] += b2 * a1; acc[2][2] += b2 * a2; acc[2][3] += b2 * a3;
    acc[3][0] += b3 * a0; acc[3][1] += b3 * a1; acc[3][2] += b3 * a2; acc[3][3] += b3 * a3;
  }
  int t = t0 + tx * 4;
  if (t < L_SEQ) {
#pragma unroll
    for (int i = 0; i < 4; ++i) {
      int dch = dch0 + ty * 4 + i;
      float bi = dbias[dch];
      float4 o = make_float4(softplus_f(acc[i][0] + bi), softplus_f(acc[i][1] + bi),
                             softplus_f(acc[i][2] + bi), softplus_f(acc[i][3] + bi));
      *(float4*)&delta[((size_t)b * DI + dch) * L_SEQ + t] = o;
    }
  }
}

// ---------------- K5: selective scan + gate + accumulate ----------------
__global__ __launch_bounds__(256) void k_scan(const float* __restrict__ xz,
                                              const float* __restrict__ x_act,
                                              const float* __restrict__ delta,
                                              const float* __restrict__ x_dbl,
                                              const float* __restrict__ A_log,
                                              const float* __restrict__ Dp,
                                              float* __restrict__ outacc, int branch) {
  int b = blockIdx.y;
  int dch = blockIdx.x * 16 + (threadIdx.x >> 4);
  int n = threadIdx.x & 15;
  const float* dl = delta + ((size_t)b * DI + dch) * L_SEQ;
  const float* xa = x_act + ((size_t)b * DI + dch) * L_SEQ;
  const float* Brow = x_dbl + ((size_t)b * 80 + 48 + n) * L_SEQ;
  const float* Crow = x_dbl + ((size_t)b * 80 + 64 + n) * L_SEQ;
  const float* zrow = xz + ((size_t)b * 2 * DI + DI + dch) * L_SEQ;
  float* orow = outacc + ((size_t)b * DI + dch) * L_SEQ;
  float a_neg = -__expf(A_log[((size_t)branch * DI + dch) * DS + n]);
  float Dv = Dp[branch * DI + dch];
  float h = 0.f;
  for (int t = 0; t < L_SEQ; t += 4) {
    float4 d4 = *(const float4*)&dl[t];
    float4 x4 = *(const float4*)&xa[t];
    float4 B4 = *(const float4*)&Brow[t];
    float4 C4 = *(const float4*)&Crow[t];
    float dv[4] = {d4.x, d4.y, d4.z, d4.w};
    float xv[4] = {x4.x, x4.y, x4.z, x4.w};
    float Bv[4] = {B4.x, B4.y, B4.z, B4.w};
    float Cv[4] = {C4.x, C4.y, C4.z, C4.w};
    float y[4];
#pragma unroll
    for (int s = 0; s < 4; ++s) {
      float dt = dv[s];
      h = h * __expf(dt * a_neg) + (dt * xv[s]) * Bv[s];
      float v = h * Cv[s];
      v += __shfl_xor(v, 1, 16);
      v += __shfl_xor(v, 2, 16);
      v += __shfl_xor(v, 4, 16);
      v += __shfl_xor(v, 8, 16);
      y[s] = v + Dv * xv[s];
    }
    if (n < 4) {
      int tt = t + n;
      float yv = (n == 0) ? y[0] : (n == 1) ? y[1] : (n == 2) ? y[2] : y[3];
      int mt = map_t(branch, tt);
      float z = zrow[mt];
      float o = yv * silu_f(z);
      if (branch == 0) orow[mt] = o;
      else orow[mt] += o;
    }
  }
}

// ---------------- K6: out[b][l][o] = sum_d outacc[b][d][l] * opw[o][d] ----------------
__global__ __launch_bounds__(256) void k_outproj(const float* __restrict__ oa,
                                                 const float* __restrict__ opw,
                                                 float* __restrict__ out) {
  __shared__ float As[16][68];  // [k][l-local]
  __shared__ float Bs[16][68];  // [k][o-local]
  int b = blockIdx.z;
  int o0 = blockIdx.y * 64;
  int l0 = blockIdx.x * 64;
  int tx = threadIdx.x, ty = threadIdx.y;
  int tid = ty * 16 + tx;
  float acc[4][4] = {};  // [l_i][o_j]
  for (int k0 = 0; k0 < DI; k0 += 16) {
    {
      int row = tid >> 4;        // k
      int c4 = (tid & 15) * 4;   // l offset
      int l = l0 + c4;
      float4 v = make_float4(0.f, 0.f, 0.f, 0.f);
      if (l < L_SEQ) v = *(const float4*)&oa[((size_t)b * DI + k0 + row) * L_SEQ + l];
      *(float4*)&As[row][c4] = v;
    }
    {
      int row = tid >> 2;        // o-local 0..63
      int c4 = (tid & 3) * 4;    // k offset
      float4 v = *(const float4*)&opw[(size_t)(o0 + row) * DI + k0 + c4];
      Bs[c4 + 0][row] = v.x; Bs[c4 + 1][row] = v.y;
      Bs[c4 + 2][row] = v.z; Bs[c4 + 3][row] = v.w;
    }
    __syncthreads();
#pragma unroll
    for (int k = 0; k < 16; ++k) {
      float a0 = As[k][tx * 4 + 0], a1 = As[k][tx * 4 + 1];
      float a2 = As[k][tx * 4 + 2], a3 = As[k][tx * 4 + 3];
      float b0 = Bs[k][ty * 4 + 0], b1 = Bs[k][ty * 4 + 1];
      float b2 = Bs[k][ty * 4 + 2], b3 = Bs[k][ty * 4 + 3];
      acc[0][0] += a0 * b0; acc[0][1] += a0 * b1; acc[0][2] += a0 * b2; acc[0][3] += a0 * b3;
      acc[1][0] += a1 * b0; acc[1][1] += a1 * b1; acc[1][2] += a1 * b2; acc[1][3] += a1 * b3;
      acc[2][0] += a2 * b0; acc[2][1] += a2 * b1; acc[2][2] += a2 * b2; acc[2][3] += a2 * b3;
      acc[3][0] += a3 * b0; acc[3][1] += a3 * b1; acc[3][2] += a3 * b2; acc[3][3] += a3 * b3;
    }
    __syncthreads();
  }
#pragma unroll
  for (int i = 0; i < 4; ++i) {
    int l = l0 + tx * 4 + i;
    if (l < L_SEQ) {
      float4 o = make_float4(acc[i][0], acc[i][1], acc[i][2], acc[i][3]);
      *(float4*)&out[((size_t)b * L_SEQ + l) * DM + o0 + ty * 4] = o;
    }
  }
}

extern "C" void kernel_launch(void* const* d_in, const int* in_sizes, int n_in,
                              void* d_out, int out_size, void* d_ws, size_t ws_size,
                              hipStream_t stream) {
  const float* hs        = (const float*)d_in[0];
  const float* in_proj_w = (const float*)d_in[1];
  const float* conv_w    = (const float*)d_in[2];
  const float* x_proj_w  = (const float*)d_in[3];
  const float* dt_proj_w = (const float*)d_in[4];
  const float* dt_bias   = (const float*)d_in[5];
  const float* A_log     = (const float*)d_in[6];
  const float* D_param   = (const float*)d_in[7];
  const float* out_proj_w= (const float*)d_in[8];
  float* out = (float*)d_out;
  float* ws = (float*)d_ws;

  float* xz     = ws;                 // 2*3072*4000      = 24,576,000
  float* x_act  = ws + 24576000;      // 2*1536*4000      = 12,288,000
  float* delta  = ws + 36864000;      // 12,288,000
  float* x_dbl  = ws + 49152000;      // 2*80*4000        = 640,000
  float* outacc = ws + 49792000;      // 12,288,000
  // total 62,080,000 floats ~ 248 MB

  k_inproj<<<dim3(63, 48, 2), dim3(16, 16), 0, stream>>>(hs, in_proj_w, xz);
  for (int br = 0; br < 3; ++br) {
    k_conv<<<dim3(16, 1536, 2), 256, 0, stream>>>(xz, conv_w + br * DI * 4, x_act, br);
    k_xproj<<<dim3(63, 2), 256, 0, stream>>>(x_act, x_proj_w + br * 80 * DI, x_dbl);
    k_dt<<<dim3(63, 24, 2), dim3(16, 16), 0, stream>>>(x_dbl, dt_proj_w + br * DI * DTRK,
                                                       dt_bias + br * DI, delta);
    k_scan<<<dim3(96, 2), 256, 0, stream>>>(xz, x_act, delta, x_dbl, A_log, D_param,
                                            outacc, br);
  }
  k_outproj<<<dim3(63, 12, 2), dim3(16, 16), 0, stream>>>(outacc, out_proj_w, out);
}

// Round 2
// 2439.964 us; speedup vs baseline: 1.8087x; 1.8087x over previous
//
#include <hip/hip_runtime.h>
#include <math.h>

#define L_SEQ 4000
#define DM 768
#define DI 1536
#define DS 16
#define DTRK 48
#define NCH 50
#define LC 80

__device__ __forceinline__ float silu_f(float x) { return x / (1.f + __expf(-x)); }
__device__ __forceinline__ float softplus_f(float x) {
  return fmaxf(x, 0.f) + log1pf(__expf(-fabsf(x)));
}
__device__ __forceinline__ int map_t(int branch, int t) {
  if (branch == 0) return t;
  if (branch == 1) return L_SEQ - 1 - t;
  return (t % 5) * 800 + t / 5;
}

// ---------------- K1: in_proj GEMM; x-half -> xT[b][l][d], z-half -> silu -> szT[b][l][d]
__global__ __launch_bounds__(256) void k_inproj(const float* __restrict__ hs,
                                                const float* __restrict__ W,
                                                float* __restrict__ xT,
                                                float* __restrict__ szT) {
  __shared__ float Es[16][68];  // [k][e-local]
  __shared__ float Ls[16][68];  // [k][l-local]
  int b = blockIdx.z;
  int e0 = blockIdx.y * 64;
  int l0 = blockIdx.x * 64;
  int tx = threadIdx.x, ty = threadIdx.y;
  int tid = ty * 16 + tx;
  float acc[4][4] = {};  // [e_i][l_j]
  for (int k0 = 0; k0 < DM; k0 += 16) {
    {
      int row = tid >> 2;
      int c4 = (tid & 3) * 4;
      float4 v = *(const float4*)&W[(size_t)(e0 + row) * DM + k0 + c4];
      Es[c4 + 0][row] = v.x; Es[c4 + 1][row] = v.y;
      Es[c4 + 2][row] = v.z; Es[c4 + 3][row] = v.w;
    }
    {
      int row = tid >> 2;
      int c4 = (tid & 3) * 4;
      int l = l0 + row;
      float4 v = make_float4(0.f, 0.f, 0.f, 0.f);
      if (l < L_SEQ) v = *(const float4*)&hs[((size_t)b * L_SEQ + l) * DM + k0 + c4];
      Ls[c4 + 0][row] = v.x; Ls[c4 + 1][row] = v.y;
      Ls[c4 + 2][row] = v.z; Ls[c4 + 3][row] = v.w;
    }
    __syncthreads();
#pragma unroll
    for (int k = 0; k < 16; ++k) {
      float a0 = Es[k][tx * 4 + 0], a1 = Es[k][tx * 4 + 1];
      float a2 = Es[k][tx * 4 + 2], a3 = Es[k][tx * 4 + 3];
      float b0 = Ls[k][ty * 4 + 0], b1 = Ls[k][ty * 4 + 1];
      float b2 = Ls[k][ty * 4 + 2], b3 = Ls[k][ty * 4 + 3];
      acc[0][0] += a0 * b0; acc[0][1] += a0 * b1; acc[0][2] += a0 * b2; acc[0][3] += a0 * b3;
      acc[1][0] += a1 * b0; acc[1][1] += a1 * b1; acc[1][2] += a1 * b2; acc[1][3] += a1 * b3;
      acc[2][0] += a2 * b0; acc[2][1] += a2 * b1; acc[2][2] += a2 * b2; acc[2][3] += a2 * b3;
      acc[3][0] += a3 * b0; acc[3][1] += a3 * b1; acc[3][2] += a3 * b2; acc[3][3] += a3 * b3;
    }
    __syncthreads();
  }
#pragma unroll
  for (int j = 0; j < 4; ++j) {
    int l = l0 + ty * 4 + j;
    if (l >= L_SEQ) continue;
    float4 o = make_float4(acc[0][j], acc[1][j], acc[2][j], acc[3][j]);
    if (e0 < DI) {
      *(float4*)&xT[((size_t)b * L_SEQ + l) * DI + e0 + tx * 4] = o;
    } else {
      o.x = silu_f(o.x); o.y = silu_f(o.y); o.z = silu_f(o.z); o.w = silu_f(o.w);
      *(float4*)&szT[((size_t)b * L_SEQ + l) * DI + (e0 - DI) + tx * 4] = o;
    }
  }
}

// ---------------- K2: depthwise causal conv (branch time) + silu; xT[b][l][d] -> xaT[b][t][d]
__global__ __launch_bounds__(256) void k_conv(const float* __restrict__ xT,
                                              const float* __restrict__ cw,
                                              float* __restrict__ xaT, int branch) {
  int b = blockIdx.z;
  int d = blockIdx.x * 64 + threadIdx.x;
  int t = blockIdx.y * 4 + threadIdx.y;
  float w0 = cw[d * 4 + 0], w1 = cw[d * 4 + 1], w2 = cw[d * 4 + 2], w3 = cw[d * 4 + 3];
  const float* xb = xT + (size_t)b * L_SEQ * DI;
  float acc = w3 * xb[(size_t)map_t(branch, t) * DI + d];
  if (t >= 1) acc += w2 * xb[(size_t)map_t(branch, t - 1) * DI + d];
  if (t >= 2) acc += w1 * xb[(size_t)map_t(branch, t - 2) * DI + d];
  if (t >= 3) acc += w0 * xb[(size_t)map_t(branch, t - 3) * DI + d];
  xaT[((size_t)b * L_SEQ + t) * DI + d] = silu_f(acc);
}

// ---------------- K3: x_dbl[b][j][t] = sum_d xpw[j][d] * xaT[b][t][d], j<80
__global__ __launch_bounds__(256) void k_xproj(const float* __restrict__ xaT,
                                               const float* __restrict__ xpw,
                                               float* __restrict__ x_dbl) {
  __shared__ float As[16][68];  // [k=d-local][t-local]
  __shared__ float Bs[16][84];  // [k][j]
  int b = blockIdx.y;
  int t0 = blockIdx.x * 64;
  int tid = threadIdx.x;
  int txq = tid & 15;
  int jy = tid >> 4;
  float acc[5][4] = {};
  for (int d0 = 0; d0 < DI; d0 += 16) {
    {
      int row = tid >> 2;        // t-local 0..63
      int c4 = (tid & 3) * 4;    // d offset
      int t = t0 + row;
      float4 v = make_float4(0.f, 0.f, 0.f, 0.f);
      if (t < L_SEQ) v = *(const float4*)&xaT[((size_t)b * L_SEQ + t) * DI + d0 + c4];
      As[c4 + 0][row] = v.x; As[c4 + 1][row] = v.y;
      As[c4 + 2][row] = v.z; As[c4 + 3][row] = v.w;
    }
    for (int i = tid; i < 320; i += 256) {
      int row = i >> 2;
      int c4 = (i & 3) * 4;
      float4 v = *(const float4*)&xpw[(size_t)row * DI + d0 + c4];
      Bs[c4 + 0][row] = v.x; Bs[c4 + 1][row] = v.y;
      Bs[c4 + 2][row] = v.z; Bs[c4 + 3][row] = v.w;
    }
    __syncthreads();
#pragma unroll
    for (int k = 0; k < 16; ++k) {
      float a0 = As[k][txq * 4 + 0], a1 = As[k][txq * 4 + 1];
      float a2 = As[k][txq * 4 + 2], a3 = As[k][txq * 4 + 3];
#pragma unroll
      for (int jj = 0; jj < 5; ++jj) {
        float bv = Bs[k][jy * 5 + jj];
        acc[jj][0] += bv * a0; acc[jj][1] += bv * a1;
        acc[jj][2] += bv * a2; acc[jj][3] += bv * a3;
      }
    }
    __syncthreads();
  }
  int t = t0 + txq * 4;
  if (t < L_SEQ) {
#pragma unroll
    for (int jj = 0; jj < 5; ++jj) {
      int j = jy * 5 + jj;
      float4 o = make_float4(acc[jj][0], acc[jj][1], acc[jj][2], acc[jj][3]);
      *(float4*)&x_dbl[((size_t)b * 80 + j) * L_SEQ + t] = o;
    }
  }
}

// ---------------- K4: scan phase 1 — per-chunk local state + decay product
__global__ __launch_bounds__(256) void k_scan1(const float* __restrict__ xaT,
                                               const float* __restrict__ x_dbl,
                                               const float* __restrict__ dpw,
                                               const float* __restrict__ dbias,
                                               const float* __restrict__ A_log,
                                               float* __restrict__ hO,
                                               float* __restrict__ Pp, int branch) {
  __shared__ float dtrS[LC][48];  // [t][r]
  __shared__ float BtS[LC][16];   // [t][n]
  int b = blockIdx.z, ch = blockIdx.y;
  int d = blockIdx.x * 256 + threadIdx.x;
  int tid = threadIdx.x;
  int t0 = ch * LC;
  // stage dtr rows 0..47 and B rows 48..63, transposed
  for (int i = tid; i < 64 * (LC / 4); i += 256) {
    int row = i / (LC / 4);
    int c4 = (i % (LC / 4)) * 4;
    float4 v = *(const float4*)&x_dbl[((size_t)b * 80 + row) * L_SEQ + t0 + c4];
    if (row < 48) {
      dtrS[c4 + 0][row] = v.x; dtrS[c4 + 1][row] = v.y;
      dtrS[c4 + 2][row] = v.z; dtrS[c4 + 3][row] = v.w;
    } else {
      int n = row - 48;
      BtS[c4 + 0][n] = v.x; BtS[c4 + 1][n] = v.y;
      BtS[c4 + 2][n] = v.z; BtS[c4 + 3][n] = v.w;
    }
  }
  float4 dpwr[12];
#pragma unroll
  for (int r4 = 0; r4 < 12; ++r4)
    dpwr[r4] = *(const float4*)&dpw[((size_t)branch * DI + d) * DTRK + r4 * 4];
  float a_neg[16];
#pragma unroll
  for (int g = 0; g < 4; ++g) {
    float4 v = *(const float4*)&A_log[(((size_t)branch * DI + d) * DS) + g * 4];
    a_neg[g * 4 + 0] = -__expf(v.x); a_neg[g * 4 + 1] = -__expf(v.y);
    a_neg[g * 4 + 2] = -__expf(v.z); a_neg[g * 4 + 3] = -__expf(v.w);
  }
  float db = dbias[branch * DI + d];
  float h[16], P[16];
#pragma unroll
  for (int n = 0; n < 16; ++n) { h[n] = 0.f; P[n] = 1.f; }
  __syncthreads();
  for (int t = 0; t < LC; ++t) {
    float a0 = 0.f, a1 = 0.f, a2 = 0.f, a3 = 0.f;
#pragma unroll
    for (int r4 = 0; r4 < 12; ++r4) {
      float4 s = *(const float4*)&dtrS[t][r4 * 4];
      a0 = fmaf(dpwr[r4].x, s.x, a0); a1 = fmaf(dpwr[r4].y, s.y, a1);
      a2 = fmaf(dpwr[r4].z, s.z, a2); a3 = fmaf(dpwr[r4].w, s.w, a3);
    }
    float delta = softplus_f((a0 + a1) + (a2 + a3) + db);
    float x = xaT[((size_t)b * L_SEQ + t0 + t) * DI + d];
    float dtx = delta * x;
#pragma unroll
    for (int g = 0; g < 4; ++g) {
      float4 Bv = *(const float4*)&BtS[t][g * 4];
      float Ba[4] = {Bv.x, Bv.y, Bv.z, Bv.w};
#pragma unroll
      for (int k = 0; k < 4; ++k) {
        int n = g * 4 + k;
        float dec = __expf(delta * a_neg[n]);
        h[n] = fmaf(h[n], dec, dtx * Ba[k]);
        P[n] *= dec;
      }
    }
  }
  size_t base = (((size_t)b * NCH + ch) * DI + d) * 16;
#pragma unroll
  for (int g = 0; g < 4; ++g) {
    *(float4*)&hO[base + g * 4] = make_float4(h[g * 4], h[g * 4 + 1], h[g * 4 + 2], h[g * 4 + 3]);
    *(float4*)&Pp[base + g * 4] = make_float4(P[g * 4], P[g * 4 + 1], P[g * 4 + 2], P[g * 4 + 3]);
  }
}

// ---------------- K5: scan phase 2 — sequential combine over chunks (in-place: hO becomes entry state)
__global__ __launch_bounds__(256) void k_scan2(float* __restrict__ hO,
                                               const float* __restrict__ Pp) {
  int idx = blockIdx.x * 256 + threadIdx.x;  // (b*DI + d)*16 + n
  int b = idx / (DI * 16);
  int rem = idx % (DI * 16);
  float H = 0.f;
  for (int c = 0; c < NCH; ++c) {
    size_t p = ((size_t)b * NCH + c) * (DI * 16) + rem;
    float th = hO[p];
    float tP = Pp[p];
    hO[p] = H;
    H = fmaf(tP, H, th);
  }
}

// ---------------- K6: scan phase 3 — re-run chunk from entry state, gate, accumulate
__global__ __launch_bounds__(256) void k_scan3(const float* __restrict__ xaT,
                                               const float* __restrict__ x_dbl,
                                               const float* __restrict__ dpw,
                                               const float* __restrict__ dbias,
                                               const float* __restrict__ A_log,
                                               const float* __restrict__ Dp,
                                               const float* __restrict__ hO,
                                               const float* __restrict__ szT,
                                               float* __restrict__ outT, int branch) {
  __shared__ float dtrS[LC][48];  // [t][r]
  __shared__ float BCt[LC][32];   // [t][n] B:0..15 C:16..31
  int b = blockIdx.z, ch = blockIdx.y;
  int d = blockIdx.x * 256 + threadIdx.x;
  int tid = threadIdx.x;
  int t0 = ch * LC;
  for (int i = tid; i < 80 * (LC / 4); i += 256) {
    int row = i / (LC / 4);
    int c4 = (i % (LC / 4)) * 4;
    float4 v = *(const float4*)&x_dbl[((size_t)b * 80 + row) * L_SEQ + t0 + c4];
    if (row < 48) {
      dtrS[c4 + 0][row] = v.x; dtrS[c4 + 1][row] = v.y;
      dtrS[c4 + 2][row] = v.z; dtrS[c4 + 3][row] = v.w;
    } else {
      int n = row - 48;
      BCt[c4 + 0][n] = v.x; BCt[c4 + 1][n] = v.y;
      BCt[c4 + 2][n] = v.z; BCt[c4 + 3][n] = v.w;
    }
  }
  float4 dpwr[12];
#pragma unroll
  for (int r4 = 0; r4 < 12; ++r4)
    dpwr[r4] = *(const float4*)&dpw[((size_t)branch * DI + d) * DTRK + r4 * 4];
  float a_neg[16];
#pragma unroll
  for (int g = 0; g < 4; ++g) {
    float4 v = *(const float4*)&A_log[(((size_t)branch * DI + d) * DS) + g * 4];
    a_neg[g * 4 + 0] = -__expf(v.x); a_neg[g * 4 + 1] = -__expf(v.y);
    a_neg[g * 4 + 2] = -__expf(v.z); a_neg[g * 4 + 3] = -__expf(v.w);
  }
  float db = dbias[branch * DI + d];
  float Dv = Dp[branch * DI + d];
  float h[16];
  size_t hbase = (((size_t)b * NCH + ch) * DI + d) * 16;
#pragma unroll
  for (int g = 0; g < 4; ++g) {
    float4 v = *(const float4*)&hO[hbase + g * 4];
    h[g * 4 + 0] = v.x; h[g * 4 + 1] = v.y; h[g * 4 + 2] = v.z; h[g * 4 + 3] = v.w;
  }
  __syncthreads();
  for (int t = 0; t < LC; ++t) {
    float a0 = 0.f, a1 = 0.f, a2 = 0.f, a3 = 0.f;
#pragma unroll
    for (int r4 = 0; r4 < 12; ++r4) {
      float4 s = *(const float4*)&dtrS[t][r4 * 4];
      a0 = fmaf(dpwr[r4].x, s.x, a0); a1 = fmaf(dpwr[r4].y, s.y, a1);
      a2 = fmaf(dpwr[r4].z, s.z, a2); a3 = fmaf(dpwr[r4].w, s.w, a3);
    }
    float delta = softplus_f((a0 + a1) + (a2 + a3) + db);
    int tg = t0 + t;
    float x = xaT[((size_t)b * L_SEQ + tg) * DI + d];
    float dtx = delta * x;
    float y0 = 0.f, y1 = 0.f, y2 = 0.f, y3 = 0.f;
#pragma unroll
    for (int g = 0; g < 4; ++g) {
      float4 Bv = *(const float4*)&BCt[t][g * 4];
      float4 Cv = *(const float4*)&BCt[t][16 + g * 4];
      float Ba[4] = {Bv.x, Bv.y, Bv.z, Bv.w};
      float Ca[4] = {Cv.x, Cv.y, Cv.z, Cv.w};
#pragma unroll
      for (int k = 0; k < 4; ++k) {
        int n = g * 4 + k;
        float dec = __expf(delta * a_neg[n]);
        h[n] = fmaf(h[n], dec, dtx * Ba[k]);
        if (k == 0) y0 = fmaf(h[n], Ca[k], y0);
        else if (k == 1) y1 = fmaf(h[n], Ca[k], y1);
        else if (k == 2) y2 = fmaf(h[n], Ca[k], y2);
        else y3 = fmaf(h[n], Ca[k], y3);
      }
    }
    float y = (y0 + y1) + (y2 + y3) + Dv * x;
    int mt = map_t(branch, tg);
    size_t oi = ((size_t)b * L_SEQ + mt) * DI + d;
    float o = y * szT[oi];
    if (branch == 0) outT[oi] = o;
    else outT[oi] += o;
  }
}

// ---------------- K7: out[b][l][o] = sum_d outT[b][l][d] * opw[o][d]
__global__ __launch_bounds__(256) void k_outproj(const float* __restrict__ oaT,
                                                 const float* __restrict__ opw,
                                                 float* __restrict__ out) {
  __shared__ float As[16][68];  // [k][l-local]
  __shared__ float Bs[16][68];  // [k][o-local]
  int b = blockIdx.z;
  int o0 = blockIdx.y * 64;
  int l0 = blockIdx.x * 64;
  int tx = threadIdx.x, ty = threadIdx.y;
  int tid = ty * 16 + tx;
  float acc[4][4] = {};  // [l_i][o_j]
  for (int k0 = 0; k0 < DI; k0 += 16) {
    {
      int row = tid >> 2;        // l-local
      int c4 = (tid & 3) * 4;    // k offset
      int l = l0 + row;
      float4 v = make_float4(0.f, 0.f, 0.f, 0.f);
      if (l < L_SEQ) v = *(const float4*)&oaT[((size_t)b * L_SEQ + l) * DI + k0 + c4];
      As[c4 + 0][row] = v.x; As[c4 + 1][row] = v.y;
      As[c4 + 2][row] = v.z; As[c4 + 3][row] = v.w;
    }
    {
      int row = tid >> 2;        // o-local
      int c4 = (tid & 3) * 4;    // k offset
      float4 v = *(const float4*)&opw[(size_t)(o0 + row) * DI + k0 + c4];
      Bs[c4 + 0][row] = v.x; Bs[c4 + 1][row] = v.y;
      Bs[c4 + 2][row] = v.z; Bs[c4 + 3][row] = v.w;
    }
    __syncthreads();
#pragma unroll
    for (int k = 0; k < 16; ++k) {
      float a0 = As[k][tx * 4 + 0], a1 = As[k][tx * 4 + 1];
      float a2 = As[k][tx * 4 + 2], a3 = As[k][tx * 4 + 3];
      float b0 = Bs[k][ty * 4 + 0], b1 = Bs[k][ty * 4 + 1];
      float b2 = Bs[k][ty * 4 + 2], b3 = Bs[k][ty * 4 + 3];
      acc[0][0] += a0 * b0; acc[0][1] += a0 * b1; acc[0][2] += a0 * b2; acc[0][3] += a0 * b3;
      acc[1][0] += a1 * b0; acc[1][1] += a1 * b1; acc[1][2] += a1 * b2; acc[1][3] += a1 * b3;
      acc[2][0] += a2 * b0; acc[2][1] += a2 * b1; acc[2][2] += a2 * b2; acc[2][3] += a2 * b3;
      acc[3][0] += a3 * b0; acc[3][1] += a3 * b1; acc[3][2] += a3 * b2; acc[3][3] += a3 * b3;
    }
    __syncthreads();
  }
#pragma unroll
  for (int i = 0; i < 4; ++i) {
    int l = l0 + tx * 4 + i;
    if (l < L_SEQ) {
      float4 o = make_float4(acc[i][0], acc[i][1], acc[i][2], acc[i][3]);
      *(float4*)&out[((size_t)b * L_SEQ + l) * DM + o0 + ty * 4] = o;
    }
  }
}

extern "C" void kernel_launch(void* const* d_in, const int* in_sizes, int n_in,
                              void* d_out, int out_size, void* d_ws, size_t ws_size,
                              hipStream_t stream) {
  const float* hs        = (const float*)d_in[0];
  const float* in_proj_w = (const float*)d_in[1];
  const float* conv_w    = (const float*)d_in[2];
  const float* x_proj_w  = (const float*)d_in[3];
  const float* dt_proj_w = (const float*)d_in[4];
  const float* dt_bias   = (const float*)d_in[5];
  const float* A_log     = (const float*)d_in[6];
  const float* D_param   = (const float*)d_in[7];
  const float* out_proj_w= (const float*)d_in[8];
  float* out = (float*)d_out;
  float* ws = (float*)d_ws;

  float* xT    = ws;                 // [b][l][d]  12,288,000
  float* szT   = ws + 12288000;      // [b][l][d]  12,288,000
  float* xaT   = ws + 24576000;      // [b][t][d]  12,288,000
  float* x_dbl = ws + 36864000;      // [b][80][t]    640,000
  float* outT  = ws + 37504000;      // [b][l][d]  12,288,000
  float* hO    = ws + 49792000;      // [b][ch][d][16] 2,457,600
  float* Pp    = ws + 52249600;      // [b][ch][d][16] 2,457,600
  // total 54,707,200 floats ~ 219 MB

  k_inproj<<<dim3(63, 48, 2), dim3(16, 16), 0, stream>>>(hs, in_proj_w, xT, szT);
  for (int br = 0; br < 3; ++br) {
    k_conv<<<dim3(24, 1000, 2), dim3(64, 4), 0, stream>>>(xT, conv_w + br * DI * 4, xaT, br);
    k_xproj<<<dim3(63, 2), 256, 0, stream>>>(xaT, x_proj_w + br * 80 * DI, x_dbl);
    k_scan1<<<dim3(6, NCH, 2), 256, 0, stream>>>(xaT, x_dbl, dt_proj_w, dt_bias, A_log,
                                                 hO, Pp, br);
    k_scan2<<<192, 256, 0, stream>>>(hO, Pp);
    k_scan3<<<dim3(6, NCH, 2), 256, 0, stream>>>(xaT, x_dbl, dt_proj_w, dt_bias, A_log,
                                                 D_param, hO, szT, outT, br);
  }
  k_outproj<<<dim3(63, 12, 2), dim3(16, 16), 0, stream>>>(outT, out_proj_w, out);
}

// Round 3
// 1756.787 us; speedup vs baseline: 2.5121x; 1.3889x over previous
//
#include <hip/hip_runtime.h>
#include <math.h>

#define L_SEQ 4000
#define DM 768
#define DI 1536
#define DS 16
#define DTRK 48
#define NCH 50
#define LC 80
#define NBL 8000

typedef __attribute__((ext_vector_type(8))) short short8;
typedef __attribute__((ext_vector_type(8))) unsigned short ushort8;
typedef __attribute__((ext_vector_type(4))) float floatx4;

__device__ __forceinline__ float silu_f(float x) { return x / (1.f + __expf(-x)); }
__device__ __forceinline__ float softplus_f(float x) {
  return fmaxf(x, 0.f) + log1pf(__expf(-fabsf(x)));
}
__device__ __forceinline__ int map_t(int branch, int t) {
  if (branch == 0) return t;
  if (branch == 1) return L_SEQ - 1 - t;
  return (t % 5) * 800 + t / 5;
}
__device__ __forceinline__ unsigned short f2bf(float f) {
  unsigned int u = __float_as_uint(f);
  u = (u + 0x7fffu + ((u >> 16) & 1u)) >> 16;
  return (unsigned short)u;
}
__device__ __forceinline__ void glds16(const void* g, void* l) {
  __builtin_amdgcn_global_load_lds((const __attribute__((address_space(1))) void*)g,
                                   (__attribute__((address_space(3))) void*)l, 16, 0, 0);
}

// ---------------- cast fp32 -> bf16 (raw ushort) ----------------
__global__ __launch_bounds__(256) void k_cast_bf16(const float* __restrict__ src,
                                                   unsigned short* __restrict__ dst, int n) {
  int i = (blockIdx.x * 256 + threadIdx.x) * 8;
  if (i >= n) return;
  float4 v0 = *(const float4*)&src[i];
  float4 v1 = *(const float4*)&src[i + 4];
  ushort8 r;
  r[0] = f2bf(v0.x); r[1] = f2bf(v0.y); r[2] = f2bf(v0.z); r[3] = f2bf(v0.w);
  r[4] = f2bf(v1.x); r[5] = f2bf(v1.y); r[6] = f2bf(v1.z); r[7] = f2bf(v1.w);
  *(ushort8*)&dst[i] = r;
}

// ---------------- MFMA GEMM (bt): C[m][n] = sum_k A[m][k]*B[n][k], store [n][m] ----
// MODE 0: out_proj -> O0[n*DM + m]
// MODE 1: in_proj  -> m<DI: O0[n*DI+m] ; else silu -> O1[n*DI+m-DI]
template <int KDIM, int MODE>
__global__ __launch_bounds__(256) void k_gemm_bt(const unsigned short* __restrict__ A,
                                                 const unsigned short* __restrict__ B,
                                                 float* __restrict__ O0,
                                                 float* __restrict__ O1) {
  __shared__ unsigned short As[128 * 32];
  __shared__ unsigned short Bs[128 * 32];
  int m0 = blockIdx.y * 128;
  int n0 = blockIdx.x * 128;
  int tid = threadIdx.x;
  int lane = tid & 63;
  int wm = (tid >> 6) & 1;
  int wn = tid >> 7;
  int srow = tid >> 2;          // 0..63
  int skof = (tid & 3) * 8;     // k offset in elements
  int brow0 = n0 + srow;       if (brow0 >= NBL) brow0 = NBL - 1;
  int brow1 = n0 + srow + 64;  if (brow1 >= NBL) brow1 = NBL - 1;
  floatx4 zero = {0.f, 0.f, 0.f, 0.f};
  floatx4 acc[4][4];
#pragma unroll
  for (int i = 0; i < 4; ++i)
#pragma unroll
    for (int j = 0; j < 4; ++j) acc[i][j] = zero;
  int ar = wm * 64 + (lane & 15);
  int br = wn * 64 + (lane & 15);
  int kq = (lane >> 4) * 8;
  for (int k0 = 0; k0 < KDIM; k0 += 32) {
    glds16(&A[(size_t)(m0 + srow) * KDIM + k0 + skof],      &As[tid * 8]);
    glds16(&A[(size_t)(m0 + srow + 64) * KDIM + k0 + skof], &As[tid * 8 + 2048]);
    glds16(&B[(size_t)brow0 * KDIM + k0 + skof], &Bs[tid * 8]);
    glds16(&B[(size_t)brow1 * KDIM + k0 + skof], &Bs[tid * 8 + 2048]);
    __syncthreads();
    short8 a[4], b[4];
#pragma unroll
    for (int i = 0; i < 4; ++i) a[i] = *(const short8*)&As[(ar + i * 16) * 32 + kq];
#pragma unroll
    for (int i = 0; i < 4; ++i) b[i] = *(const short8*)&Bs[(br + i * 16) * 32 + kq];
#pragma unroll
    for (int mt = 0; mt < 4; ++mt)
#pragma unroll
      for (int nt = 0; nt < 4; ++nt)
        acc[mt][nt] = __builtin_amdgcn_mfma_f32_16x16x32_bf16(a[mt], b[nt], acc[mt][nt], 0, 0, 0);
    __syncthreads();
  }
  int mq = m0 + wm * 64 + ((lane >> 4) << 2);
  int nq = n0 + wn * 64 + (lane & 15);
#pragma unroll
  for (int nt = 0; nt < 4; ++nt) {
    int n = nq + nt * 16;
    if (n >= NBL) continue;
#pragma unroll
    for (int mt = 0; mt < 4; ++mt) {
      int m = mq + mt * 16;
      floatx4 v = acc[mt][nt];
      if (MODE == 0) {
        *(floatx4*)&O0[(size_t)n * DM + m] = v;
      } else {
        if (m < DI) {
          *(floatx4*)&O0[(size_t)n * DI + m] = v;
        } else {
          floatx4 s;
          s[0] = silu_f(v[0]); s[1] = silu_f(v[1]); s[2] = silu_f(v[2]); s[3] = silu_f(v[3]);
          *(floatx4*)&O1[(size_t)n * DI + m - DI] = s;
        }
      }
    }
  }
}

// ---------------- K2: depthwise causal conv (branch time) + silu; xT[b][l][d] -> xaT[b][t][d]
__global__ __launch_bounds__(256) void k_conv(const float* __restrict__ xT,
                                              const float* __restrict__ cw,
                                              float* __restrict__ xaT, int branch) {
  int b = blockIdx.z;
  int d = blockIdx.x * 64 + threadIdx.x;
  int t = blockIdx.y * 4 + threadIdx.y;
  float w0 = cw[d * 4 + 0], w1 = cw[d * 4 + 1], w2 = cw[d * 4 + 2], w3 = cw[d * 4 + 3];
  const float* xb = xT + (size_t)b * L_SEQ * DI;
  float acc = w3 * xb[(size_t)map_t(branch, t) * DI + d];
  if (t >= 1) acc += w2 * xb[(size_t)map_t(branch, t - 1) * DI + d];
  if (t >= 2) acc += w1 * xb[(size_t)map_t(branch, t - 2) * DI + d];
  if (t >= 3) acc += w0 * xb[(size_t)map_t(branch, t - 3) * DI + d];
  xaT[((size_t)b * L_SEQ + t) * DI + d] = silu_f(acc);
}

// ---------------- K3: x_dbl[b][j][t] = sum_d xpw[j][d] * xaT[b][t][d], j<80
__global__ __launch_bounds__(256) void k_xproj(const float* __restrict__ xaT,
                                               const float* __restrict__ xpw,
                                               float* __restrict__ x_dbl) {
  __shared__ float As[16][68];  // [k=d-local][t-local]
  __shared__ float Bs[16][84];  // [k][j]
  int b = blockIdx.y;
  int t0 = blockIdx.x * 64;
  int tid = threadIdx.x;
  int txq = tid & 15;
  int jy = tid >> 4;
  float acc[5][4] = {};
  for (int d0 = 0; d0 < DI; d0 += 16) {
    {
      int row = tid >> 2;        // t-local 0..63
      int c4 = (tid & 3) * 4;    // d offset
      int t = t0 + row;
      float4 v = make_float4(0.f, 0.f, 0.f, 0.f);
      if (t < L_SEQ) v = *(const float4*)&xaT[((size_t)b * L_SEQ + t) * DI + d0 + c4];
      As[c4 + 0][row] = v.x; As[c4 + 1][row] = v.y;
      As[c4 + 2][row] = v.z; As[c4 + 3][row] = v.w;
    }
    for (int i = tid; i < 320; i += 256) {
      int row = i >> 2;
      int c4 = (i & 3) * 4;
      float4 v = *(const float4*)&xpw[(size_t)row * DI + d0 + c4];
      Bs[c4 + 0][row] = v.x; Bs[c4 + 1][row] = v.y;
      Bs[c4 + 2][row] = v.z; Bs[c4 + 3][row] = v.w;
    }
    __syncthreads();
#pragma unroll
    for (int k = 0; k < 16; ++k) {
      float a0 = As[k][txq * 4 + 0], a1 = As[k][txq * 4 + 1];
      float a2 = As[k][txq * 4 + 2], a3 = As[k][txq * 4 + 3];
#pragma unroll
      for (int jj = 0; jj < 5; ++jj) {
        float bv = Bs[k][jy * 5 + jj];
        acc[jj][0] += bv * a0; acc[jj][1] += bv * a1;
        acc[jj][2] += bv * a2; acc[jj][3] += bv * a3;
      }
    }
    __syncthreads();
  }
  int t = t0 + txq * 4;
  if (t < L_SEQ) {
#pragma unroll
    for (int jj = 0; jj < 5; ++jj) {
      int j = jy * 5 + jj;
      float4 o = make_float4(acc[jj][0], acc[jj][1], acc[jj][2], acc[jj][3]);
      *(float4*)&x_dbl[((size_t)b * 80 + j) * L_SEQ + t] = o;
    }
  }
}

// ---------------- K4: scan phase 1 — per-chunk local state + decay product
__global__ __launch_bounds__(256) void k_scan1(const float* __restrict__ xaT,
                                               const float* __restrict__ x_dbl,
                                               const float* __restrict__ dpw,
                                               const float* __restrict__ dbias,
                                               const float* __restrict__ A_log,
                                               float* __restrict__ hO,
                                               float* __restrict__ Pp, int branch) {
  __shared__ float dtrS[LC][48];  // [t][r]
  __shared__ float BtS[LC][16];   // [t][n]
  int b = blockIdx.z, ch = blockIdx.y;
  int d = blockIdx.x * 256 + threadIdx.x;
  int tid = threadIdx.x;
  int t0 = ch * LC;
  for (int i = tid; i < 64 * (LC / 4); i += 256) {
    int row = i / (LC / 4);
    int c4 = (i % (LC / 4)) * 4;
    float4 v = *(const float4*)&x_dbl[((size_t)b * 80 + row) * L_SEQ + t0 + c4];
    if (row < 48) {
      dtrS[c4 + 0][row] = v.x; dtrS[c4 + 1][row] = v.y;
      dtrS[c4 + 2][row] = v.z; dtrS[c4 + 3][row] = v.w;
    } else {
      int n = row - 48;
      BtS[c4 + 0][n] = v.x; BtS[c4 + 1][n] = v.y;
      BtS[c4 + 2][n] = v.z; BtS[c4 + 3][n] = v.w;
    }
  }
  float4 dpwr[12];
#pragma unroll
  for (int r4 = 0; r4 < 12; ++r4)
    dpwr[r4] = *(const float4*)&dpw[((size_t)branch * DI + d) * DTRK + r4 * 4];
  float a_neg[16];
#pragma unroll
  for (int g = 0; g < 4; ++g) {
    float4 v = *(const float4*)&A_log[(((size_t)branch * DI + d) * DS) + g * 4];
    a_neg[g * 4 + 0] = -__expf(v.x); a_neg[g * 4 + 1] = -__expf(v.y);
    a_neg[g * 4 + 2] = -__expf(v.z); a_neg[g * 4 + 3] = -__expf(v.w);
  }
  float db = dbias[branch * DI + d];
  float h[16], P[16];
#pragma unroll
  for (int n = 0; n < 16; ++n) { h[n] = 0.f; P[n] = 1.f; }
  __syncthreads();
  for (int t = 0; t < LC; ++t) {
    float a0 = 0.f, a1 = 0.f, a2 = 0.f, a3 = 0.f;
#pragma unroll
    for (int r4 = 0; r4 < 12; ++r4) {
      float4 s = *(const float4*)&dtrS[t][r4 * 4];
      a0 = fmaf(dpwr[r4].x, s.x, a0); a1 = fmaf(dpwr[r4].y, s.y, a1);
      a2 = fmaf(dpwr[r4].z, s.z, a2); a3 = fmaf(dpwr[r4].w, s.w, a3);
    }
    float delta = softplus_f((a0 + a1) + (a2 + a3) + db);
    float x = xaT[((size_t)b * L_SEQ + t0 + t) * DI + d];
    float dtx = delta * x;
#pragma unroll
    for (int g = 0; g < 4; ++g) {
      float4 Bv = *(const float4*)&BtS[t][g * 4];
      float Ba[4] = {Bv.x, Bv.y, Bv.z, Bv.w};
#pragma unroll
      for (int k = 0; k < 4; ++k) {
        int n = g * 4 + k;
        float dec = __expf(delta * a_neg[n]);
        h[n] = fmaf(h[n], dec, dtx * Ba[k]);
        P[n] *= dec;
      }
    }
  }
  size_t base = (((size_t)b * NCH + ch) * DI + d) * 16;
#pragma unroll
  for (int g = 0; g < 4; ++g) {
    *(float4*)&hO[base + g * 4] = make_float4(h[g * 4], h[g * 4 + 1], h[g * 4 + 2], h[g * 4 + 3]);
    *(float4*)&Pp[base + g * 4] = make_float4(P[g * 4], P[g * 4 + 1], P[g * 4 + 2], P[g * 4 + 3]);
  }
}

// ---------------- K5: scan phase 2 — sequential combine over chunks
__global__ __launch_bounds__(256) void k_scan2(float* __restrict__ hO,
                                               const float* __restrict__ Pp) {
  int idx = blockIdx.x * 256 + threadIdx.x;
  int b = idx / (DI * 16);
  int rem = idx % (DI * 16);
  float H = 0.f;
  for (int c = 0; c < NCH; ++c) {
    size_t p = ((size_t)b * NCH + c) * (DI * 16) + rem;
    float th = hO[p];
    float tP = Pp[p];
    hO[p] = H;
    H = fmaf(tP, H, th);
  }
}

// ---------------- K6: scan phase 3 — re-run chunk from entry state, gate, accumulate
__global__ __launch_bounds__(256) void k_scan3(const float* __restrict__ xaT,
                                               const float* __restrict__ x_dbl,
                                               const float* __restrict__ dpw,
                                               const float* __restrict__ dbias,
                                               const float* __restrict__ A_log,
                                               const float* __restrict__ Dp,
                                               const float* __restrict__ hO,
                                               const float* __restrict__ szT,
                                               float* __restrict__ outT, int branch) {
  __shared__ float dtrS[LC][48];
  __shared__ float BCt[LC][32];
  int b = blockIdx.z, ch = blockIdx.y;
  int d = blockIdx.x * 256 + threadIdx.x;
  int tid = threadIdx.x;
  int t0 = ch * LC;
  for (int i = tid; i < 80 * (LC / 4); i += 256) {
    int row = i / (LC / 4);
    int c4 = (i % (LC / 4)) * 4;
    float4 v = *(const float4*)&x_dbl[((size_t)b * 80 + row) * L_SEQ + t0 + c4];
    if (row < 48) {
      dtrS[c4 + 0][row] = v.x; dtrS[c4 + 1][row] = v.y;
      dtrS[c4 + 2][row] = v.z; dtrS[c4 + 3][row] = v.w;
    } else {
      int n = row - 48;
      BCt[c4 + 0][n] = v.x; BCt[c4 + 1][n] = v.y;
      BCt[c4 + 2][n] = v.z; BCt[c4 + 3][n] = v.w;
    }
  }
  float4 dpwr[12];
#pragma unroll
  for (int r4 = 0; r4 < 12; ++r4)
    dpwr[r4] = *(const float4*)&dpw[((size_t)branch * DI + d) * DTRK + r4 * 4];
  float a_neg[16];
#pragma unroll
  for (int g = 0; g < 4; ++g) {
    float4 v = *(const float4*)&A_log[(((size_t)branch * DI + d) * DS) + g * 4];
    a_neg[g * 4 + 0] = -__expf(v.x); a_neg[g * 4 + 1] = -__expf(v.y);
    a_neg[g * 4 + 2] = -__expf(v.z); a_neg[g * 4 + 3] = -__expf(v.w);
  }
  float db = dbias[branch * DI + d];
  float Dv = Dp[branch * DI + d];
  float h[16];
  size_t hbase = (((size_t)b * NCH + ch) * DI + d) * 16;
#pragma unroll
  for (int g = 0; g < 4; ++g) {
    float4 v = *(const float4*)&hO[hbase + g * 4];
    h[g * 4 + 0] = v.x; h[g * 4 + 1] = v.y; h[g * 4 + 2] = v.z; h[g * 4 + 3] = v.w;
  }
  __syncthreads();
  for (int t = 0; t < LC; ++t) {
    float a0 = 0.f, a1 = 0.f, a2 = 0.f, a3 = 0.f;
#pragma unroll
    for (int r4 = 0; r4 < 12; ++r4) {
      float4 s = *(const float4*)&dtrS[t][r4 * 4];
      a0 = fmaf(dpwr[r4].x, s.x, a0); a1 = fmaf(dpwr[r4].y, s.y, a1);
      a2 = fmaf(dpwr[r4].z, s.z, a2); a3 = fmaf(dpwr[r4].w, s.w, a3);
    }
    float delta = softplus_f((a0 + a1) + (a2 + a3) + db);
    int tg = t0 + t;
    float x = xaT[((size_t)b * L_SEQ + tg) * DI + d];
    float dtx = delta * x;
    float y0 = 0.f, y1 = 0.f, y2 = 0.f, y3 = 0.f;
#pragma unroll
    for (int g = 0; g < 4; ++g) {
      float4 Bv = *(const float4*)&BCt[t][g * 4];
      float4 Cv = *(const float4*)&BCt[t][16 + g * 4];
      float Ba[4] = {Bv.x, Bv.y, Bv.z, Bv.w};
      float Ca[4] = {Cv.x, Cv.y, Cv.z, Cv.w};
#pragma unroll
      for (int k = 0; k < 4; ++k) {
        int n = g * 4 + k;
        float dec = __expf(delta * a_neg[n]);
        h[n] = fmaf(h[n], dec, dtx * Ba[k]);
        if (k == 0) y0 = fmaf(h[n], Ca[k], y0);
        else if (k == 1) y1 = fmaf(h[n], Ca[k], y1);
        else if (k == 2) y2 = fmaf(h[n], Ca[k], y2);
        else y3 = fmaf(h[n], Ca[k], y3);
      }
    }
    float y = (y0 + y1) + (y2 + y3) + Dv * x;
    int mt = map_t(branch, tg);
    size_t oi = ((size_t)b * L_SEQ + mt) * DI + d;
    float o = y * szT[oi];
    if (branch == 0) outT[oi] = o;
    else outT[oi] += o;
  }
}

extern "C" void kernel_launch(void* const* d_in, const int* in_sizes, int n_in,
                              void* d_out, int out_size, void* d_ws, size_t ws_size,
                              hipStream_t stream) {
  const float* hs        = (const float*)d_in[0];
  const float* in_proj_w = (const float*)d_in[1];
  const float* conv_w    = (const float*)d_in[2];
  const float* x_proj_w  = (const float*)d_in[3];
  const float* dt_proj_w = (const float*)d_in[4];
  const float* dt_bias   = (const float*)d_in[5];
  const float* A_log     = (const float*)d_in[6];
  const float* D_param   = (const float*)d_in[7];
  const float* out_proj_w= (const float*)d_in[8];
  float* out = (float*)d_out;
  float* ws = (float*)d_ws;

  float* xT    = ws;                 // [bl][d]   12,288,000
  float* szT   = ws + 12288000;      // [bl][d]   12,288,000
  float* xaT   = ws + 24576000;      // [bt][d]   12,288,000
  float* x_dbl = ws + 36864000;      // [b][80][t]   640,000
  float* outT  = ws + 37504000;      // [bl][d]   12,288,000
  float* hO    = ws + 49792000;      // 2,457,600
  float* Pp    = ws + 52249600;      // 2,457,600
  unsigned short* hsB   = (unsigned short*)(ws + 54707200);  // 6,144,000 sh (aliased w/ outTb)
  unsigned short* Wb    = hsB + 6144000;                     // 2,359,296 sh
  unsigned short* outTb = hsB;                               // 12,288,000 sh (after hsB/Wb dead)
  unsigned short* OWb   = (unsigned short*)(ws + 60851200);  // 1,179,648 sh
  // end: 61,441,024 floats = 245.8 MB (round-0 used 248.3 MB OK)

  k_cast_bf16<<<6144000 / 2048, 256, 0, stream>>>(hs, hsB, 6144000);
  k_cast_bf16<<<2359296 / 2048, 256, 0, stream>>>(in_proj_w, Wb, 2359296);
  k_cast_bf16<<<1179648 / 2048, 256, 0, stream>>>(out_proj_w, OWb, 1179648);

  k_gemm_bt<DM, 1><<<dim3(63, 24), 256, 0, stream>>>(Wb, hsB, xT, szT);

  for (int br = 0; br < 3; ++br) {
    k_conv<<<dim3(24, 1000, 2), dim3(64, 4), 0, stream>>>(xT, conv_w + br * DI * 4, xaT, br);
    k_xproj<<<dim3(63, 2), 256, 0, stream>>>(xaT, x_proj_w + br * 80 * DI, x_dbl);
    k_scan1<<<dim3(6, NCH, 2), 256, 0, stream>>>(xaT, x_dbl, dt_proj_w, dt_bias, A_log,
                                                 hO, Pp, br);
    k_scan2<<<192, 256, 0, stream>>>(hO, Pp);
    k_scan3<<<dim3(6, NCH, 2), 256, 0, stream>>>(xaT, x_dbl, dt_proj_w, dt_bias, A_log,
                                                 D_param, hO, szT, outT, br);
  }

  k_cast_bf16<<<12288000 / 2048, 256, 0, stream>>>(outT, outTb, 12288000);
  k_gemm_bt<DI, 0><<<dim3(63, 6), 256, 0, stream>>>(OWb, outTb, out, nullptr);
}

// Round 4
// 1212.792 us; speedup vs baseline: 3.6389x; 1.4485x over previous
//
#include <hip/hip_runtime.h>
#include <math.h>

#define L_SEQ 4000
#define DM 768
#define DI 1536
#define DS 16
#define DTRK 48
#define NCH 50
#define LC 80
#define NBL 8000

typedef __attribute__((ext_vector_type(8))) short short8;
typedef __attribute__((ext_vector_type(8))) unsigned short ushort8;
typedef __attribute__((ext_vector_type(4))) unsigned short ushort4v;
typedef __attribute__((ext_vector_type(4))) float floatx4;

__device__ __forceinline__ float silu_f(float x) { return x / (1.f + __expf(-x)); }
__device__ __forceinline__ float softplus_f(float x) {
  return fmaxf(x, 0.f) + log1pf(__expf(-fabsf(x)));
}
__device__ __forceinline__ int map_t(int branch, int t) {
  if (branch == 0) return t;
  if (branch == 1) return L_SEQ - 1 - t;
  return (t % 5) * 800 + t / 5;
}
__device__ __forceinline__ unsigned short f2bf(float f) {
  unsigned int u = __float_as_uint(f);
  u = (u + 0x7fffu + ((u >> 16) & 1u)) >> 16;
  return (unsigned short)u;
}
__device__ __forceinline__ float bf2f(unsigned short u) {
  return __uint_as_float(((unsigned int)u) << 16);
}
__device__ __forceinline__ void glds16(const void* g, void* l) {
  __builtin_amdgcn_global_load_lds((const __attribute__((address_space(1))) void*)g,
                                   (__attribute__((address_space(3))) void*)l, 16, 0, 0);
}
// depthwise causal conv at one (t,d), branch-remapped time, + silu. x is bf16 [t][DI].
__device__ __forceinline__ float conv_silu_1(const unsigned short* __restrict__ xrow,
                                             float4 w, int br, int tg, int d) {
  float acc = w.w * bf2f(xrow[(size_t)map_t(br, tg) * DI + d]);
  if (tg >= 1) acc = fmaf(w.z, bf2f(xrow[(size_t)map_t(br, tg - 1) * DI + d]), acc);
  if (tg >= 2) acc = fmaf(w.y, bf2f(xrow[(size_t)map_t(br, tg - 2) * DI + d]), acc);
  if (tg >= 3) acc = fmaf(w.x, bf2f(xrow[(size_t)map_t(br, tg - 3) * DI + d]), acc);
  return silu_f(acc);
}
// conv+silu for a quad of d (dbase..dbase+3) at time tg
__device__ __forceinline__ float4 conv4_silu(const unsigned short* __restrict__ xrow,
                                             const float* __restrict__ cwb,
                                             int br, int tg, int dbase) {
  float4 w0 = *(const float4*)&cwb[(size_t)(dbase + 0) * 4];
  float4 w1 = *(const float4*)&cwb[(size_t)(dbase + 1) * 4];
  float4 w2 = *(const float4*)&cwb[(size_t)(dbase + 2) * 4];
  float4 w3 = *(const float4*)&cwb[(size_t)(dbase + 3) * 4];
  const float* W0 = (const float*)&w0; const float* W1 = (const float*)&w1;
  const float* W2 = (const float*)&w2; const float* W3 = (const float*)&w3;
  float a0 = 0.f, a1 = 0.f, a2 = 0.f, a3 = 0.f;
#pragma unroll
  for (int k = 0; k < 4; ++k) {
    int tt = tg - 3 + k;
    if (tt < 0) continue;
    ushort4v u = *(const ushort4v*)&xrow[(size_t)map_t(br, tt) * DI + dbase];
    a0 = fmaf(W0[k], bf2f(u[0]), a0);
    a1 = fmaf(W1[k], bf2f(u[1]), a1);
    a2 = fmaf(W2[k], bf2f(u[2]), a2);
    a3 = fmaf(W3[k], bf2f(u[3]), a3);
  }
  return make_float4(silu_f(a0), silu_f(a1), silu_f(a2), silu_f(a3));
}

// ---------------- cast fp32 -> bf16 ----------------
__global__ __launch_bounds__(256) void k_cast_bf16(const float* __restrict__ src,
                                                   unsigned short* __restrict__ dst, int n) {
  int i = (blockIdx.x * 256 + threadIdx.x) * 8;
  if (i >= n) return;
  float4 v0 = *(const float4*)&src[i];
  float4 v1 = *(const float4*)&src[i + 4];
  ushort8 r;
  r[0] = f2bf(v0.x); r[1] = f2bf(v0.y); r[2] = f2bf(v0.z); r[3] = f2bf(v0.w);
  r[4] = f2bf(v1.x); r[5] = f2bf(v1.y); r[6] = f2bf(v1.z); r[7] = f2bf(v1.w);
  *(ushort8*)&dst[i] = r;
}

// ---------------- MFMA GEMM (bt): C[m][n] = sum_k A[m][(k%KA)]*B[n][k] ----
// MODE 0: fp32 out[n*DM+m].  MODE 1: m<DI -> bf16 O0h[n*DI+m]; else silu -> O1h.
template <int KDIM, int KA, int MODE>
__global__ __launch_bounds__(256) void k_gemm_bt(const unsigned short* __restrict__ A,
                                                 const unsigned short* __restrict__ B,
                                                 float* __restrict__ O0f,
                                                 unsigned short* __restrict__ O0h,
                                                 unsigned short* __restrict__ O1h) {
  __shared__ unsigned short As[128 * 32];
  __shared__ unsigned short Bs[128 * 32];
  int m0 = blockIdx.y * 128;
  int n0 = blockIdx.x * 128;
  int tid = threadIdx.x;
  int lane = tid & 63;
  int wm = (tid >> 6) & 1;
  int wn = tid >> 7;
  int srow = tid >> 2;
  int skof = (tid & 3) * 8;
  int brow0 = n0 + srow;       if (brow0 >= NBL) brow0 = NBL - 1;
  int brow1 = n0 + srow + 64;  if (brow1 >= NBL) brow1 = NBL - 1;
  floatx4 zero = {0.f, 0.f, 0.f, 0.f};
  floatx4 acc[4][4];
#pragma unroll
  for (int i = 0; i < 4; ++i)
#pragma unroll
    for (int j = 0; j < 4; ++j) acc[i][j] = zero;
  int ar = wm * 64 + (lane & 15);
  int br = wn * 64 + (lane & 15);
  int kq = (lane >> 4) * 8;
  for (int k0 = 0; k0 < KDIM; k0 += 32) {
    int ka = (k0 % KA);
    glds16(&A[(size_t)(m0 + srow) * KA + ka + skof],      &As[tid * 8]);
    glds16(&A[(size_t)(m0 + srow + 64) * KA + ka + skof], &As[tid * 8 + 2048]);
    glds16(&B[(size_t)brow0 * KDIM + k0 + skof], &Bs[tid * 8]);
    glds16(&B[(size_t)brow1 * KDIM + k0 + skof], &Bs[tid * 8 + 2048]);
    __syncthreads();
    short8 a[4], b[4];
#pragma unroll
    for (int i = 0; i < 4; ++i) a[i] = *(const short8*)&As[(ar + i * 16) * 32 + kq];
#pragma unroll
    for (int i = 0; i < 4; ++i) b[i] = *(const short8*)&Bs[(br + i * 16) * 32 + kq];
#pragma unroll
    for (int mt = 0; mt < 4; ++mt)
#pragma unroll
      for (int nt = 0; nt < 4; ++nt)
        acc[mt][nt] = __builtin_amdgcn_mfma_f32_16x16x32_bf16(a[mt], b[nt], acc[mt][nt], 0, 0, 0);
    __syncthreads();
  }
  int mq = m0 + wm * 64 + ((lane >> 4) << 2);
  int nq = n0 + wn * 64 + (lane & 15);
#pragma unroll
  for (int nt = 0; nt < 4; ++nt) {
    int n = nq + nt * 16;
    if (n >= NBL) continue;
#pragma unroll
    for (int mt = 0; mt < 4; ++mt) {
      int m = mq + mt * 16;
      floatx4 v = acc[mt][nt];
      if (MODE == 0) {
        *(floatx4*)&O0f[(size_t)n * DM + m] = v;
      } else {
        if (m < DI) {
          ushort4v r;
          r[0] = f2bf(v[0]); r[1] = f2bf(v[1]); r[2] = f2bf(v[2]); r[3] = f2bf(v[3]);
          *(ushort4v*)&O0h[(size_t)n * DI + m] = r;
        } else {
          ushort4v r;
          r[0] = f2bf(silu_f(v[0])); r[1] = f2bf(silu_f(v[1]));
          r[2] = f2bf(silu_f(v[2])); r[3] = f2bf(silu_f(v[3]));
          *(ushort4v*)&O1h[(size_t)n * DI + m - DI] = r;
        }
      }
    }
  }
}

// ---------------- xproj (fused conv), all 6 (br,b) in z:
// dtr (j<48) -> dtrB[z][t][48] bf16 ; B/C (j>=48) -> BC[z][j-48][t] fp32
__global__ __launch_bounds__(256) void k_xprojb(const unsigned short* __restrict__ xTB,
                                                const float* __restrict__ xpw_all,
                                                const float* __restrict__ cw_all,
                                                unsigned short* __restrict__ dtrB,
                                                float* __restrict__ BC) {
  __shared__ float As[16][68];  // [d-local][t-local]
  __shared__ float Bs[16][84];  // [d-local][j]
  int z = blockIdx.y;
  int brn = z >> 1, b = z & 1;
  const unsigned short* xrow = xTB + (size_t)b * L_SEQ * DI;
  const float* xpw = xpw_all + (size_t)brn * 80 * DI;
  const float* cwb = cw_all + (size_t)brn * DI * 4;
  int t0 = blockIdx.x * 64;
  int tid = threadIdx.x;
  int txq = tid & 15;
  int jy = tid >> 4;
  float acc[5][4] = {};
  for (int d0 = 0; d0 < DI; d0 += 16) {
    {
      int row = tid >> 2;        // t-local 0..63
      int c4 = (tid & 3) * 4;    // d offset
      int t = t0 + row;
      float4 v = make_float4(0.f, 0.f, 0.f, 0.f);
      if (t < L_SEQ) v = conv4_silu(xrow, cwb, brn, t, d0 + c4);
      As[c4 + 0][row] = v.x; As[c4 + 1][row] = v.y;
      As[c4 + 2][row] = v.z; As[c4 + 3][row] = v.w;
    }
    for (int i = tid; i < 320; i += 256) {
      int row = i >> 2;
      int c4 = (i & 3) * 4;
      float4 v = *(const float4*)&xpw[(size_t)row * DI + d0 + c4];
      Bs[c4 + 0][row] = v.x; Bs[c4 + 1][row] = v.y;
      Bs[c4 + 2][row] = v.z; Bs[c4 + 3][row] = v.w;
    }
    __syncthreads();
#pragma unroll
    for (int k = 0; k < 16; ++k) {
      float a0 = As[k][txq * 4 + 0], a1 = As[k][txq * 4 + 1];
      float a2 = As[k][txq * 4 + 2], a3 = As[k][txq * 4 + 3];
#pragma unroll
      for (int jj = 0; jj < 5; ++jj) {
        float bv = Bs[k][jy * 5 + jj];
        acc[jj][0] += bv * a0; acc[jj][1] += bv * a1;
        acc[jj][2] += bv * a2; acc[jj][3] += bv * a3;
      }
    }
    __syncthreads();
  }
  int t = t0 + txq * 4;
  if (t < L_SEQ) {
#pragma unroll
    for (int jj = 0; jj < 5; ++jj) {
      int j = jy * 5 + jj;
      if (j < 48) {
#pragma unroll
        for (int i = 0; i < 4; ++i)
          dtrB[((size_t)z * L_SEQ + t + i) * DTRK + j] = f2bf(acc[jj][i]);
      } else {
        float4 o = make_float4(acc[jj][0], acc[jj][1], acc[jj][2], acc[jj][3]);
        *(float4*)&BC[((size_t)z * 32 + (j - 48)) * L_SEQ + t] = o;
      }
    }
  }
}

// ---------------- delta GEMM (MFMA, K=48 padded to 64) + softplus -> bf16 [z][t][d]
__global__ __launch_bounds__(256) void k_dtg(const unsigned short* __restrict__ dpwB,
                                             const unsigned short* __restrict__ dtrB,
                                             const float* __restrict__ dbias,
                                             unsigned short* __restrict__ dT) {
  __shared__ unsigned short As[128 * 64];
  __shared__ unsigned short Bs[128 * 64];
  int z = blockIdx.z;
  int brn = z >> 1;
  int m0 = blockIdx.y * 128;  // d
  int n0 = blockIdx.x * 128;  // t
  int tid = threadIdx.x;
  int lane = tid & 63;
  int wm = (tid >> 6) & 1;
  int wn = tid >> 7;
  {  // zero pad cols 48..63
    int zr = tid >> 1, zc = 48 + (tid & 1) * 8;
    ushort8 zz = {0, 0, 0, 0, 0, 0, 0, 0};
    *(ushort8*)&As[zr * 64 + zc] = zz;
    *(ushort8*)&Bs[zr * 64 + zc] = zz;
  }
  {  // stage cols 0..47
    int row = tid >> 1;
    int p0 = (tid & 1) * 3;
    const unsigned short* Ag = dpwB + (size_t)brn * DI * DTRK + (size_t)(m0 + row) * DTRK;
    int bro = n0 + row; if (bro > L_SEQ - 1) bro = L_SEQ - 1;
    const unsigned short* Bg = dtrB + ((size_t)z * L_SEQ + bro) * DTRK;
#pragma unroll
    for (int i = 0; i < 3; ++i) {
      int off = (p0 + i) * 8;
      *(ushort8*)&As[row * 64 + off] = *(const ushort8*)&Ag[off];
      *(ushort8*)&Bs[row * 64 + off] = *(const ushort8*)&Bg[off];
    }
  }
  __syncthreads();
  int ar = wm * 64 + (lane & 15);
  int brr = wn * 64 + (lane & 15);
  int kq = (lane >> 4) * 8;
  floatx4 zero = {0.f, 0.f, 0.f, 0.f};
  floatx4 acc[4][4];
#pragma unroll
  for (int i = 0; i < 4; ++i)
#pragma unroll
    for (int j = 0; j < 4; ++j) acc[i][j] = zero;
#pragma unroll
  for (int kk = 0; kk < 2; ++kk) {
    short8 a[4], b[4];
#pragma unroll
    for (int i = 0; i < 4; ++i) a[i] = *(const short8*)&As[(ar + i * 16) * 64 + kk * 32 + kq];
#pragma unroll
    for (int i = 0; i < 4; ++i) b[i] = *(const short8*)&Bs[(brr + i * 16) * 64 + kk * 32 + kq];
#pragma unroll
    for (int mt = 0; mt < 4; ++mt)
#pragma unroll
      for (int nt = 0; nt < 4; ++nt)
        acc[mt][nt] = __builtin_amdgcn_mfma_f32_16x16x32_bf16(a[mt], b[nt], acc[mt][nt], 0, 0, 0);
  }
  int mq = m0 + wm * 64 + ((lane >> 4) << 2);
  int nq = n0 + wn * 64 + (lane & 15);
#pragma unroll
  for (int nt = 0; nt < 4; ++nt) {
    int n = nq + nt * 16;
    if (n >= L_SEQ) continue;
#pragma unroll
    for (int mt = 0; mt < 4; ++mt) {
      int m = mq + mt * 16;
      float4 bi = *(const float4*)&dbias[(size_t)brn * DI + m];
      floatx4 v = acc[mt][nt];
      ushort4v r;
      r[0] = f2bf(softplus_f(v[0] + bi.x));
      r[1] = f2bf(softplus_f(v[1] + bi.y));
      r[2] = f2bf(softplus_f(v[2] + bi.z));
      r[3] = f2bf(softplus_f(v[3] + bi.w));
      *(ushort4v*)&dT[((size_t)z * L_SEQ + n) * DI + m] = r;
    }
  }
}

// ---------------- scan phase 1 (all branches): per-chunk local state + decay product
__global__ __launch_bounds__(256) void k_scan1c(const unsigned short* __restrict__ xTB,
                                                const unsigned short* __restrict__ dT,
                                                const float* __restrict__ BC,
                                                const float* __restrict__ cw_all,
                                                const float* __restrict__ A_log,
                                                float* __restrict__ hO,
                                                float* __restrict__ Pp) {
  __shared__ float BtS[LC][16];
  int z = blockIdx.z;
  int brn = z >> 1, b = z & 1;
  int ch = blockIdx.y;
  int t0 = ch * LC;
  int d = blockIdx.x * 256 + threadIdx.x;
  int tid = threadIdx.x;
  for (int i = tid; i < 320; i += 256) {
    int row = i / 20;
    int c4 = (i % 20) * 4;
    float4 v = *(const float4*)&BC[((size_t)z * 32 + row) * L_SEQ + t0 + c4];
    BtS[c4 + 0][row] = v.x; BtS[c4 + 1][row] = v.y;
    BtS[c4 + 2][row] = v.z; BtS[c4 + 3][row] = v.w;
  }
  float4 w = *(const float4*)&cw_all[((size_t)brn * DI + d) * 4];
  float a2[16];
#pragma unroll
  for (int g = 0; g < 4; ++g) {
    float4 v = *(const float4*)&A_log[((size_t)brn * DI + d) * DS + g * 4];
    a2[g * 4 + 0] = -__expf(v.x) * 1.44269504f;
    a2[g * 4 + 1] = -__expf(v.y) * 1.44269504f;
    a2[g * 4 + 2] = -__expf(v.z) * 1.44269504f;
    a2[g * 4 + 3] = -__expf(v.w) * 1.44269504f;
  }
  const unsigned short* xrow = xTB + (size_t)b * L_SEQ * DI;
  const unsigned short* drow = dT + (size_t)z * L_SEQ * DI;
  float h[16], P[16];
#pragma unroll
  for (int n = 0; n < 16; ++n) { h[n] = 0.f; P[n] = 1.f; }
  __syncthreads();
  float del_n = bf2f(drow[(size_t)t0 * DI + d]);
  float xa_n = conv_silu_1(xrow, w, brn, t0, d);
  for (int t = 0; t < LC; ++t) {
    float del = del_n, xa = xa_n;
    if (t + 1 < LC) {
      del_n = bf2f(drow[(size_t)(t0 + t + 1) * DI + d]);
      xa_n = conv_silu_1(xrow, w, brn, t0 + t + 1, d);
    }
    float dtx = del * xa;
#pragma unroll
    for (int g = 0; g < 4; ++g) {
      float4 Bv = *(const float4*)&BtS[t][g * 4];
      const float* Bp = (const float*)&Bv;
#pragma unroll
      for (int k = 0; k < 4; ++k) {
        int n = g * 4 + k;
        float dec = exp2f(del * a2[n]);
        h[n] = fmaf(h[n], dec, dtx * Bp[k]);
        P[n] *= dec;
      }
    }
  }
  size_t base = (((size_t)z * NCH + ch) * DI + d) * 16;
#pragma unroll
  for (int g = 0; g < 4; ++g) {
    *(float4*)&hO[base + g * 4] = make_float4(h[g * 4], h[g * 4 + 1], h[g * 4 + 2], h[g * 4 + 3]);
    *(float4*)&Pp[base + g * 4] = make_float4(P[g * 4], P[g * 4 + 1], P[g * 4 + 2], P[g * 4 + 3]);
  }
}

// ---------------- scan phase 2 (all branches): sequential combine over chunks
__global__ __launch_bounds__(256) void k_scan2c(float* __restrict__ hO,
                                                const float* __restrict__ Pp) {
  int idx = blockIdx.x * 256 + threadIdx.x;  // z*(DI*16) + d*16 + n
  int z = idx / (DI * 16);
  int rem = idx % (DI * 16);
  float H = 0.f;
  for (int c = 0; c < NCH; ++c) {
    size_t p = ((size_t)z * NCH + c) * (DI * 16) + rem;
    float th = hO[p];
    float tP = Pp[p];
    hO[p] = H;
    H = fmaf(tP, H, th);
  }
}

// ---------------- scan phase 3 (all branches): re-run chunk, gate, write ybuf bf16
__global__ __launch_bounds__(256) void k_scan3c(const unsigned short* __restrict__ xTB,
                                                const unsigned short* __restrict__ dT,
                                                const float* __restrict__ BC,
                                                const float* __restrict__ cw_all,
                                                const float* __restrict__ A_log,
                                                const float* __restrict__ Dp,
                                                const float* __restrict__ hO,
                                                const unsigned short* __restrict__ szTB,
                                                unsigned short* __restrict__ ybuf) {
  __shared__ float BCt[LC][32];  // [t][n] B:0..15 C:16..31
  int z = blockIdx.z;
  int brn = z >> 1, b = z & 1;
  int ch = blockIdx.y;
  int t0 = ch * LC;
  int d = blockIdx.x * 256 + threadIdx.x;
  int tid = threadIdx.x;
  for (int i = tid; i < 640; i += 256) {
    int row = i / 20;
    int c4 = (i % 20) * 4;
    float4 v = *(const float4*)&BC[((size_t)z * 32 + row) * L_SEQ + t0 + c4];
    BCt[c4 + 0][row] = v.x; BCt[c4 + 1][row] = v.y;
    BCt[c4 + 2][row] = v.z; BCt[c4 + 3][row] = v.w;
  }
  float4 w = *(const float4*)&cw_all[((size_t)brn * DI + d) * 4];
  float a2[16];
#pragma unroll
  for (int g = 0; g < 4; ++g) {
    float4 v = *(const float4*)&A_log[((size_t)brn * DI + d) * DS + g * 4];
    a2[g * 4 + 0] = -__expf(v.x) * 1.44269504f;
    a2[g * 4 + 1] = -__expf(v.y) * 1.44269504f;
    a2[g * 4 + 2] = -__expf(v.z) * 1.44269504f;
    a2[g * 4 + 3] = -__expf(v.w) * 1.44269504f;
  }
  float Dv = Dp[(size_t)brn * DI + d];
  const unsigned short* xrow = xTB + (size_t)b * L_SEQ * DI;
  const unsigned short* drow = dT + (size_t)z * L_SEQ * DI;
  const unsigned short* szrow = szTB + (size_t)b * L_SEQ * DI;
  float h[16];
  size_t hbase = (((size_t)z * NCH + ch) * DI + d) * 16;
#pragma unroll
  for (int g = 0; g < 4; ++g) {
    float4 v = *(const float4*)&hO[hbase + g * 4];
    h[g * 4 + 0] = v.x; h[g * 4 + 1] = v.y; h[g * 4 + 2] = v.z; h[g * 4 + 3] = v.w;
  }
  __syncthreads();
  float del_n = bf2f(drow[(size_t)t0 * DI + d]);
  float xa_n = conv_silu_1(xrow, w, brn, t0, d);
  int mt_n = map_t(brn, t0);
  float sz_n = bf2f(szrow[(size_t)mt_n * DI + d]);
  for (int t = 0; t < LC; ++t) {
    float del = del_n, xa = xa_n, sz = sz_n;
    int mt = mt_n;
    if (t + 1 < LC) {
      int tg1 = t0 + t + 1;
      del_n = bf2f(drow[(size_t)tg1 * DI + d]);
      xa_n = conv_silu_1(xrow, w, brn, tg1, d);
      mt_n = map_t(brn, tg1);
      sz_n = bf2f(szrow[(size_t)mt_n * DI + d]);
    }
    float dtx = del * xa;
    float y0 = 0.f, y1 = 0.f, y2 = 0.f, y3 = 0.f;
#pragma unroll
    for (int g = 0; g < 4; ++g) {
      float4 Bv = *(const float4*)&BCt[t][g * 4];
      float4 Cv = *(const float4*)&BCt[t][16 + g * 4];
      const float* Bp = (const float*)&Bv;
      const float* Cp = (const float*)&Cv;
#pragma unroll
      for (int k = 0; k < 4; ++k) {
        int n = g * 4 + k;
        float dec = exp2f(del * a2[n]);
        h[n] = fmaf(h[n], dec, dtx * Bp[k]);
        if (k == 0) y0 = fmaf(h[n], Cp[k], y0);
        else if (k == 1) y1 = fmaf(h[n], Cp[k], y1);
        else if (k == 2) y2 = fmaf(h[n], Cp[k], y2);
        else y3 = fmaf(h[n], Cp[k], y3);
      }
    }
    float y = (y0 + y1) + (y2 + y3) + Dv * xa;
    float o = y * sz;
    ybuf[((size_t)b * L_SEQ + mt) * (3 * DI) + (size_t)brn * DI + d] = f2bf(o);
  }
}

extern "C" void kernel_launch(void* const* d_in, const int* in_sizes, int n_in,
                              void* d_out, int out_size, void* d_ws, size_t ws_size,
                              hipStream_t stream) {
  const float* hs        = (const float*)d_in[0];
  const float* in_proj_w = (const float*)d_in[1];
  const float* conv_w    = (const float*)d_in[2];
  const float* x_proj_w  = (const float*)d_in[3];
  const float* dt_proj_w = (const float*)d_in[4];
  const float* dt_bias   = (const float*)d_in[5];
  const float* A_log     = (const float*)d_in[6];
  const float* D_param   = (const float*)d_in[7];
  const float* out_proj_w= (const float*)d_in[8];
  float* out = (float*)d_out;
  float* ws = (float*)d_ws;

  // layout (float offsets); R region shares {hsB,Wb} -> {Pp} -> {ybuf} (disjoint lifetimes)
  unsigned short* xTB  = (unsigned short*)(ws);             // 12,288,000 sh
  unsigned short* szTB = (unsigned short*)(ws + 6144000);   // 12,288,000 sh
  unsigned short* dtrB = (unsigned short*)(ws + 12288000);  // 1,152,000 sh
  float* BC            = ws + 12864000;                     // 768,000 f
  unsigned short* dT   = (unsigned short*)(ws + 13632000);  // 36,864,000 sh
  float* hO            = ws + 32064000;                     // 7,372,800 f
  unsigned short* dpwB = (unsigned short*)(ws + 39436800);  // 221,184 sh
  unsigned short* OWb  = (unsigned short*)(ws + 39547392);  // 1,179,648 sh
  unsigned short* hsB  = (unsigned short*)(ws + 40137216);  // 6,144,000 sh
  unsigned short* Wb   = (unsigned short*)(ws + 43209216);  // 2,359,296 sh
  float* Pp            = ws + 40137216;                     // 7,372,800 f
  unsigned short* ybuf = (unsigned short*)(ws + 40137216);  // 36,864,000 sh
  // total: 58,569,216 floats = 234.3 MB

  k_cast_bf16<<<3000, 256, 0, stream>>>(hs, hsB, 6144000);
  k_cast_bf16<<<1152, 256, 0, stream>>>(in_proj_w, Wb, 2359296);
  k_cast_bf16<<<576, 256, 0, stream>>>(out_proj_w, OWb, 1179648);
  k_cast_bf16<<<108, 256, 0, stream>>>(dt_proj_w, dpwB, 221184);

  k_gemm_bt<DM, DM, 1><<<dim3(63, 24), 256, 0, stream>>>(Wb, hsB, nullptr, xTB, szTB);

  k_xprojb<<<dim3(63, 6), 256, 0, stream>>>(xTB, x_proj_w, conv_w, dtrB, BC);
  k_dtg<<<dim3(32, 12, 6), 256, 0, stream>>>(dpwB, dtrB, dt_bias, dT);

  k_scan1c<<<dim3(6, NCH, 6), 256, 0, stream>>>(xTB, dT, BC, conv_w, A_log, hO, Pp);
  k_scan2c<<<576, 256, 0, stream>>>(hO, Pp);
  k_scan3c<<<dim3(6, NCH, 6), 256, 0, stream>>>(xTB, dT, BC, conv_w, A_log, D_param,
                                                hO, szTB, ybuf);

  k_gemm_bt<3 * DI, DI, 0><<<dim3(63, 6), 256, 0, stream>>>(OWb, ybuf, out, nullptr, nullptr);
}

// Round 5
// 869.812 us; speedup vs baseline: 5.0737x; 1.3943x over previous
//
#include <hip/hip_runtime.h>
#include <math.h>

#define L_SEQ 4000
#define DM 768
#define DI 1536
#define DS 16
#define DTRK 48
#define NCH 50
#define LC 80
#define NBL 8000

typedef __attribute__((ext_vector_type(8))) short short8;
typedef __attribute__((ext_vector_type(8))) unsigned short ushort8;
typedef __attribute__((ext_vector_type(4))) unsigned short ushort4v;
typedef __attribute__((ext_vector_type(4))) float floatx4;

__device__ __forceinline__ float silu_f(float x) { return x / (1.f + __expf(-x)); }
__device__ __forceinline__ float softplus_f(float x) {
  return fmaxf(x, 0.f) + log1pf(__expf(-fabsf(x)));
}
__device__ __forceinline__ int map_t(int branch, int t) {
  if (branch == 0) return t;
  if (branch == 1) return L_SEQ - 1 - t;
  return (t % 5) * 800 + t / 5;
}
__device__ __forceinline__ unsigned short f2bf(float f) {
  unsigned int u = __float_as_uint(f);
  u = (u + 0x7fffu + ((u >> 16) & 1u)) >> 16;
  return (unsigned short)u;
}
__device__ __forceinline__ float bf2f(unsigned short u) {
  return __uint_as_float(((unsigned int)u) << 16);
}
__device__ __forceinline__ void glds16(const void* g, void* l) {
  __builtin_amdgcn_global_load_lds((const __attribute__((address_space(1))) void*)g,
                                   (__attribute__((address_space(3))) void*)l, 16, 0, 0);
}
// conv+silu for a quad of d (dbase..dbase+3) at time tg (used by xproj staging)
__device__ __forceinline__ float4 conv4_silu(const unsigned short* __restrict__ xrow,
                                             const float* __restrict__ cwb,
                                             int br, int tg, int dbase) {
  float4 w0 = *(const float4*)&cwb[(size_t)(dbase + 0) * 4];
  float4 w1 = *(const float4*)&cwb[(size_t)(dbase + 1) * 4];
  float4 w2 = *(const float4*)&cwb[(size_t)(dbase + 2) * 4];
  float4 w3 = *(const float4*)&cwb[(size_t)(dbase + 3) * 4];
  const float* W0 = (const float*)&w0; const float* W1 = (const float*)&w1;
  const float* W2 = (const float*)&w2; const float* W3 = (const float*)&w3;
  float a0 = 0.f, a1 = 0.f, a2 = 0.f, a3 = 0.f;
#pragma unroll
  for (int k = 0; k < 4; ++k) {
    int tt = tg - 3 + k;
    if (tt < 0) continue;
    ushort4v u = *(const ushort4v*)&xrow[(size_t)map_t(br, tt) * DI + dbase];
    a0 = fmaf(W0[k], bf2f(u[0]), a0);
    a1 = fmaf(W1[k], bf2f(u[1]), a1);
    a2 = fmaf(W2[k], bf2f(u[2]), a2);
    a3 = fmaf(W3[k], bf2f(u[3]), a3);
  }
  return make_float4(silu_f(a0), silu_f(a1), silu_f(a2), silu_f(a3));
}
// binary power ladder: dc[n] = E^(n+1), depth 4, 15 muls
__device__ __forceinline__ void pow_ladder(float E1, float* dc) {
  float E2 = E1 * E1, E4 = E2 * E2, E8 = E4 * E4;
  float E3 = E2 * E1, E5 = E4 * E1, E6 = E4 * E2, E7 = E4 * E3;
  dc[0] = E1; dc[1] = E2; dc[2] = E3; dc[3] = E4;
  dc[4] = E5; dc[5] = E6; dc[6] = E7; dc[7] = E8;
  dc[8] = E8 * E1; dc[9] = E8 * E2; dc[10] = E8 * E3; dc[11] = E8 * E4;
  dc[12] = E8 * E5; dc[13] = E8 * E6; dc[14] = E8 * E7; dc[15] = E8 * E8;
}

// ---------------- cast fp32 -> bf16 ----------------
__global__ __launch_bounds__(256) void k_cast_bf16(const float* __restrict__ src,
                                                   unsigned short* __restrict__ dst, int n) {
  int i = (blockIdx.x * 256 + threadIdx.x) * 8;
  if (i >= n) return;
  float4 v0 = *(const float4*)&src[i];
  float4 v1 = *(const float4*)&src[i + 4];
  ushort8 r;
  r[0] = f2bf(v0.x); r[1] = f2bf(v0.y); r[2] = f2bf(v0.z); r[3] = f2bf(v0.w);
  r[4] = f2bf(v1.x); r[5] = f2bf(v1.y); r[6] = f2bf(v1.z); r[7] = f2bf(v1.w);
  *(ushort8*)&dst[i] = r;
}

// ---------------- MFMA GEMM (bt): C[m][n] = sum_k A[m][(k%KA)]*B[n][k] ----
template <int KDIM, int KA, int MODE>
__global__ __launch_bounds__(256) void k_gemm_bt(const unsigned short* __restrict__ A,
                                                 const unsigned short* __restrict__ B,
                                                 float* __restrict__ O0f,
                                                 unsigned short* __restrict__ O0h,
                                                 unsigned short* __restrict__ O1h) {
  __shared__ unsigned short As[128 * 32];
  __shared__ unsigned short Bs[128 * 32];
  int m0 = blockIdx.y * 128;
  int n0 = blockIdx.x * 128;
  int tid = threadIdx.x;
  int lane = tid & 63;
  int wm = (tid >> 6) & 1;
  int wn = tid >> 7;
  int srow = tid >> 2;
  int skof = (tid & 3) * 8;
  int brow0 = n0 + srow;       if (brow0 >= NBL) brow0 = NBL - 1;
  int brow1 = n0 + srow + 64;  if (brow1 >= NBL) brow1 = NBL - 1;
  floatx4 zero = {0.f, 0.f, 0.f, 0.f};
  floatx4 acc[4][4];
#pragma unroll
  for (int i = 0; i < 4; ++i)
#pragma unroll
    for (int j = 0; j < 4; ++j) acc[i][j] = zero;
  int ar = wm * 64 + (lane & 15);
  int br = wn * 64 + (lane & 15);
  int kq = (lane >> 4) * 8;
  for (int k0 = 0; k0 < KDIM; k0 += 32) {
    int ka = (k0 % KA);
    glds16(&A[(size_t)(m0 + srow) * KA + ka + skof],      &As[tid * 8]);
    glds16(&A[(size_t)(m0 + srow + 64) * KA + ka + skof], &As[tid * 8 + 2048]);
    glds16(&B[(size_t)brow0 * KDIM + k0 + skof], &Bs[tid * 8]);
    glds16(&B[(size_t)brow1 * KDIM + k0 + skof], &Bs[tid * 8 + 2048]);
    __syncthreads();
    short8 a[4], b[4];
#pragma unroll
    for (int i = 0; i < 4; ++i) a[i] = *(const short8*)&As[(ar + i * 16) * 32 + kq];
#pragma unroll
    for (int i = 0; i < 4; ++i) b[i] = *(const short8*)&Bs[(br + i * 16) * 32 + kq];
#pragma unroll
    for (int mt = 0; mt < 4; ++mt)
#pragma unroll
      for (int nt = 0; nt < 4; ++nt)
        acc[mt][nt] = __builtin_amdgcn_mfma_f32_16x16x32_bf16(a[mt], b[nt], acc[mt][nt], 0, 0, 0);
    __syncthreads();
  }
  int mq = m0 + wm * 64 + ((lane >> 4) << 2);
  int nq = n0 + wn * 64 + (lane & 15);
#pragma unroll
  for (int nt = 0; nt < 4; ++nt) {
    int n = nq + nt * 16;
    if (n >= NBL) continue;
#pragma unroll
    for (int mt = 0; mt < 4; ++mt) {
      int m = mq + mt * 16;
      floatx4 v = acc[mt][nt];
      if (MODE == 0) {
        *(floatx4*)&O0f[(size_t)n * DM + m] = v;
      } else {
        if (m < DI) {
          ushort4v r;
          r[0] = f2bf(v[0]); r[1] = f2bf(v[1]); r[2] = f2bf(v[2]); r[3] = f2bf(v[3]);
          *(ushort4v*)&O0h[(size_t)n * DI + m] = r;
        } else {
          ushort4v r;
          r[0] = f2bf(silu_f(v[0])); r[1] = f2bf(silu_f(v[1]));
          r[2] = f2bf(silu_f(v[2])); r[3] = f2bf(silu_f(v[3]));
          *(ushort4v*)&O1h[(size_t)n * DI + m - DI] = r;
        }
      }
    }
  }
}

// ---------------- xproj (fused conv), all 6 (br,b) in z ----------------
__global__ __launch_bounds__(256) void k_xprojb(const unsigned short* __restrict__ xTB,
                                                const float* __restrict__ xpw_all,
                                                const float* __restrict__ cw_all,
                                                unsigned short* __restrict__ dtrB,
                                                float* __restrict__ BC) {
  __shared__ float As[16][68];
  __shared__ float Bs[16][84];
  int z = blockIdx.y;
  int brn = z >> 1, b = z & 1;
  const unsigned short* xrow = xTB + (size_t)b * L_SEQ * DI;
  const float* xpw = xpw_all + (size_t)brn * 80 * DI;
  const float* cwb = cw_all + (size_t)brn * DI * 4;
  int t0 = blockIdx.x * 64;
  int tid = threadIdx.x;
  int txq = tid & 15;
  int jy = tid >> 4;
  float acc[5][4] = {};
  for (int d0 = 0; d0 < DI; d0 += 16) {
    {
      int row = tid >> 2;
      int c4 = (tid & 3) * 4;
      int t = t0 + row;
      float4 v = make_float4(0.f, 0.f, 0.f, 0.f);
      if (t < L_SEQ) v = conv4_silu(xrow, cwb, brn, t, d0 + c4);
      As[c4 + 0][row] = v.x; As[c4 + 1][row] = v.y;
      As[c4 + 2][row] = v.z; As[c4 + 3][row] = v.w;
    }
    for (int i = tid; i < 320; i += 256) {
      int row = i >> 2;
      int c4 = (i & 3) * 4;
      float4 v = *(const float4*)&xpw[(size_t)row * DI + d0 + c4];
      Bs[c4 + 0][row] = v.x; Bs[c4 + 1][row] = v.y;
      Bs[c4 + 2][row] = v.z; Bs[c4 + 3][row] = v.w;
    }
    __syncthreads();
#pragma unroll
    for (int k = 0; k < 16; ++k) {
      float a0 = As[k][txq * 4 + 0], a1 = As[k][txq * 4 + 1];
      float a2 = As[k][txq * 4 + 2], a3 = As[k][txq * 4 + 3];
#pragma unroll
      for (int jj = 0; jj < 5; ++jj) {
        float bv = Bs[k][jy * 5 + jj];
        acc[jj][0] += bv * a0; acc[jj][1] += bv * a1;
        acc[jj][2] += bv * a2; acc[jj][3] += bv * a3;
      }
    }
    __syncthreads();
  }
  int t = t0 + txq * 4;
  if (t < L_SEQ) {
#pragma unroll
    for (int jj = 0; jj < 5; ++jj) {
      int j = jy * 5 + jj;
      if (j < 48) {
#pragma unroll
        for (int i = 0; i < 4; ++i)
          dtrB[((size_t)z * L_SEQ + t + i) * DTRK + j] = f2bf(acc[jj][i]);
      } else {
        float4 o = make_float4(acc[jj][0], acc[jj][1], acc[jj][2], acc[jj][3]);
        *(float4*)&BC[((size_t)z * 32 + (j - 48)) * L_SEQ + t] = o;
      }
    }
  }
}

// ---------------- delta GEMM (MFMA, K=48 padded to 64) + softplus -> bf16 [z][t][d]
__global__ __launch_bounds__(256) void k_dtg(const unsigned short* __restrict__ dpwB,
                                             const unsigned short* __restrict__ dtrB,
                                             const float* __restrict__ dbias,
                                             unsigned short* __restrict__ dT) {
  __shared__ unsigned short As[128 * 64];
  __shared__ unsigned short Bs[128 * 64];
  int z = blockIdx.z;
  int brn = z >> 1;
  int m0 = blockIdx.y * 128;
  int n0 = blockIdx.x * 128;
  int tid = threadIdx.x;
  int lane = tid & 63;
  int wm = (tid >> 6) & 1;
  int wn = tid >> 7;
  {
    int zr = tid >> 1, zc = 48 + (tid & 1) * 8;
    ushort8 zz = {0, 0, 0, 0, 0, 0, 0, 0};
    *(ushort8*)&As[zr * 64 + zc] = zz;
    *(ushort8*)&Bs[zr * 64 + zc] = zz;
  }
  {
    int row = tid >> 1;
    int p0 = (tid & 1) * 3;
    const unsigned short* Ag = dpwB + (size_t)brn * DI * DTRK + (size_t)(m0 + row) * DTRK;
    int bro = n0 + row; if (bro > L_SEQ - 1) bro = L_SEQ - 1;
    const unsigned short* Bg = dtrB + ((size_t)z * L_SEQ + bro) * DTRK;
#pragma unroll
    for (int i = 0; i < 3; ++i) {
      int off = (p0 + i) * 8;
      *(ushort8*)&As[row * 64 + off] = *(const ushort8*)&Ag[off];
      *(ushort8*)&Bs[row * 64 + off] = *(const ushort8*)&Bg[off];
    }
  }
  __syncthreads();
  int ar = wm * 64 + (lane & 15);
  int brr = wn * 64 + (lane & 15);
  int kq = (lane >> 4) * 8;
  floatx4 zero = {0.f, 0.f, 0.f, 0.f};
  floatx4 acc[4][4];
#pragma unroll
  for (int i = 0; i < 4; ++i)
#pragma unroll
    for (int j = 0; j < 4; ++j) acc[i][j] = zero;
#pragma unroll
  for (int kk = 0; kk < 2; ++kk) {
    short8 a[4], b[4];
#pragma unroll
    for (int i = 0; i < 4; ++i) a[i] = *(const short8*)&As[(ar + i * 16) * 64 + kk * 32 + kq];
#pragma unroll
    for (int i = 0; i < 4; ++i) b[i] = *(const short8*)&Bs[(brr + i * 16) * 64 + kk * 32 + kq];
#pragma unroll
    for (int mt = 0; mt < 4; ++mt)
#pragma unroll
      for (int nt = 0; nt < 4; ++nt)
        acc[mt][nt] = __builtin_amdgcn_mfma_f32_16x16x32_bf16(a[mt], b[nt], acc[mt][nt], 0, 0, 0);
  }
  int mq = m0 + wm * 64 + ((lane >> 4) << 2);
  int nq = n0 + wn * 64 + (lane & 15);
#pragma unroll
  for (int nt = 0; nt < 4; ++nt) {
    int n = nq + nt * 16;
    if (n >= L_SEQ) continue;
#pragma unroll
    for (int mt = 0; mt < 4; ++mt) {
      int m = mq + mt * 16;
      float4 bi = *(const float4*)&dbias[(size_t)brn * DI + m];
      floatx4 v = acc[mt][nt];
      ushort4v r;
      r[0] = f2bf(softplus_f(v[0] + bi.x));
      r[1] = f2bf(softplus_f(v[1] + bi.y));
      r[2] = f2bf(softplus_f(v[2] + bi.z));
      r[3] = f2bf(softplus_f(v[3] + bi.w));
      *(ushort4v*)&dT[((size_t)z * L_SEQ + n) * DI + m] = r;
    }
  }
}

// ---------------- scan phase 1: per-chunk local state + delta-sum ----------------
__global__ __launch_bounds__(256) void k_scan1c(const unsigned short* __restrict__ xTB,
                                                const unsigned short* __restrict__ dT,
                                                const float* __restrict__ BC,
                                                const float* __restrict__ cw_all,
                                                const float* __restrict__ A_log,
                                                float* __restrict__ hO,
                                                float* __restrict__ Sc) {
  __shared__ float BtS[LC][16];
  int z = blockIdx.z;
  int brn = z >> 1, b = z & 1;
  int ch = blockIdx.y;
  int t0 = ch * LC;
  int d = blockIdx.x * 256 + threadIdx.x;
  int tid = threadIdx.x;
  for (int i = tid; i < 320; i += 256) {
    int row = i / 20;
    int c4 = (i % 20) * 4;
    float4 v = *(const float4*)&BC[((size_t)z * 32 + row) * L_SEQ + t0 + c4];
    BtS[c4 + 0][row] = v.x; BtS[c4 + 1][row] = v.y;
    BtS[c4 + 2][row] = v.z; BtS[c4 + 3][row] = v.w;
  }
  float4 w = *(const float4*)&cw_all[((size_t)brn * DI + d) * 4];
  float a2[16];
  bool fastp = true;
#pragma unroll
  for (int g = 0; g < 4; ++g) {
    float4 v = *(const float4*)&A_log[((size_t)brn * DI + d) * DS + g * 4];
    float av0 = __expf(v.x), av1 = __expf(v.y), av2 = __expf(v.z), av3 = __expf(v.w);
    a2[g * 4 + 0] = -av0 * 1.44269504f; a2[g * 4 + 1] = -av1 * 1.44269504f;
    a2[g * 4 + 2] = -av2 * 1.44269504f; a2[g * 4 + 3] = -av3 * 1.44269504f;
    fastp = fastp && fabsf(av0 - (float)(g * 4 + 1)) < 1e-3f
                  && fabsf(av1 - (float)(g * 4 + 2)) < 1e-3f
                  && fabsf(av2 - (float)(g * 4 + 3)) < 1e-3f
                  && fabsf(av3 - (float)(g * 4 + 4)) < 1e-3f;
  }
  const unsigned short* xrow = xTB + (size_t)b * L_SEQ * DI;
  const unsigned short* drow = dT + (size_t)z * L_SEQ * DI;
  float h[16];
#pragma unroll
  for (int n = 0; n < 16; ++n) h[n] = 0.f;
  float S = 0.f;
  __syncthreads();
  // rolling conv window over the REMAPPED sequence
  float xm3 = (t0 >= 3) ? bf2f(xrow[(size_t)map_t(brn, t0 - 3) * DI + d]) : 0.f;
  float xm2 = (t0 >= 2) ? bf2f(xrow[(size_t)map_t(brn, t0 - 2) * DI + d]) : 0.f;
  float xm1 = (t0 >= 1) ? bf2f(xrow[(size_t)map_t(brn, t0 - 1) * DI + d]) : 0.f;
  float xc  = bf2f(xrow[(size_t)map_t(brn, t0) * DI + d]);
  float del = bf2f(drow[(size_t)t0 * DI + d]);
  for (int t = 0; t < LC; ++t) {
    float xn = 0.f, deln = 0.f;
    if (t + 1 < LC) {
      int tg1 = t0 + t + 1;
      xn = bf2f(xrow[(size_t)map_t(brn, tg1) * DI + d]);
      deln = bf2f(drow[(size_t)tg1 * DI + d]);
    }
    float xa = silu_f(fmaf(w.w, xc, fmaf(w.z, xm1, fmaf(w.y, xm2, w.x * xm3))));
    float dtx = del * xa;
    S += del;
    float dc[16];
    if (fastp) {
      pow_ladder(exp2f(-del * 1.44269504f), dc);
    } else {
#pragma unroll
      for (int n = 0; n < 16; ++n) dc[n] = exp2f(del * a2[n]);
    }
#pragma unroll
    for (int g = 0; g < 4; ++g) {
      float4 Bv = *(const float4*)&BtS[t][g * 4];
      const float* Bp = (const float*)&Bv;
#pragma unroll
      for (int k = 0; k < 4; ++k) {
        int n = g * 4 + k;
        h[n] = fmaf(h[n], dc[n], dtx * Bp[k]);
      }
    }
    xm3 = xm2; xm2 = xm1; xm1 = xc; xc = xn; del = deln;
  }
  size_t base = (((size_t)z * NCH + ch) * DI + d) * 16;
#pragma unroll
  for (int g = 0; g < 4; ++g)
    *(float4*)&hO[base + g * 4] = make_float4(h[g * 4], h[g * 4 + 1], h[g * 4 + 2], h[g * 4 + 3]);
  Sc[((size_t)z * NCH + ch) * DI + d] = S;
}

// ---------------- scan phase 2: sequential combine over chunks ----------------
__global__ __launch_bounds__(256) void k_scan2c(float* __restrict__ hO,
                                                const float* __restrict__ Sc,
                                                const float* __restrict__ A_log) {
  int idx = blockIdx.x * 256 + threadIdx.x;  // z*(DI*16) + d*16 + n
  int z = idx / (DI * 16);
  int rem = idx % (DI * 16);
  int brn = z >> 1;
  float a2 = -__expf(A_log[(size_t)brn * DI * DS + rem]) * 1.44269504f;
  float H = 0.f;
  for (int c = 0; c < NCH; ++c) {
    size_t p = ((size_t)z * NCH + c) * (DI * 16) + rem;
    float th = hO[p];
    float P = exp2f(Sc[((size_t)z * NCH + c) * DI + (rem >> 4)] * a2);
    hO[p] = H;
    H = fmaf(P, H, th);
  }
}

// ---------------- scan phase 3: re-run chunk from entry state, gate, write ybuf
__global__ __launch_bounds__(256) void k_scan3c(const unsigned short* __restrict__ xTB,
                                                const unsigned short* __restrict__ dT,
                                                const float* __restrict__ BC,
                                                const float* __restrict__ cw_all,
                                                const float* __restrict__ A_log,
                                                const float* __restrict__ Dp,
                                                const float* __restrict__ hO,
                                                const unsigned short* __restrict__ szTB,
                                                unsigned short* __restrict__ ybuf) {
  __shared__ float BCt[LC][32];  // [t][n] B:0..15 C:16..31
  int z = blockIdx.z;
  int brn = z >> 1, b = z & 1;
  int ch = blockIdx.y;
  int t0 = ch * LC;
  int d = blockIdx.x * 256 + threadIdx.x;
  int tid = threadIdx.x;
  for (int i = tid; i < 640; i += 256) {
    int row = i / 20;
    int c4 = (i % 20) * 4;
    float4 v = *(const float4*)&BC[((size_t)z * 32 + row) * L_SEQ + t0 + c4];
    BCt[c4 + 0][row] = v.x; BCt[c4 + 1][row] = v.y;
    BCt[c4 + 2][row] = v.z; BCt[c4 + 3][row] = v.w;
  }
  float4 w = *(const float4*)&cw_all[((size_t)brn * DI + d) * 4];
  float a2[16];
  bool fastp = true;
#pragma unroll
  for (int g = 0; g < 4; ++g) {
    float4 v = *(const float4*)&A_log[((size_t)brn * DI + d) * DS + g * 4];
    float av0 = __expf(v.x), av1 = __expf(v.y), av2 = __expf(v.z), av3 = __expf(v.w);
    a2[g * 4 + 0] = -av0 * 1.44269504f; a2[g * 4 + 1] = -av1 * 1.44269504f;
    a2[g * 4 + 2] = -av2 * 1.44269504f; a2[g * 4 + 3] = -av3 * 1.44269504f;
    fastp = fastp && fabsf(av0 - (float)(g * 4 + 1)) < 1e-3f
                  && fabsf(av1 - (float)(g * 4 + 2)) < 1e-3f
                  && fabsf(av2 - (float)(g * 4 + 3)) < 1e-3f
                  && fabsf(av3 - (float)(g * 4 + 4)) < 1e-3f;
  }
  float Dv = Dp[(size_t)brn * DI + d];
  const unsigned short* xrow = xTB + (size_t)b * L_SEQ * DI;
  const unsigned short* drow = dT + (size_t)z * L_SEQ * DI;
  const unsigned short* szrow = szTB + (size_t)b * L_SEQ * DI;
  float h[16];
  size_t hbase = (((size_t)z * NCH + ch) * DI + d) * 16;
#pragma unroll
  for (int g = 0; g < 4; ++g) {
    float4 v = *(const float4*)&hO[hbase + g * 4];
    h[g * 4 + 0] = v.x; h[g * 4 + 1] = v.y; h[g * 4 + 2] = v.z; h[g * 4 + 3] = v.w;
  }
  __syncthreads();
  float xm3 = (t0 >= 3) ? bf2f(xrow[(size_t)map_t(brn, t0 - 3) * DI + d]) : 0.f;
  float xm2 = (t0 >= 2) ? bf2f(xrow[(size_t)map_t(brn, t0 - 2) * DI + d]) : 0.f;
  float xm1 = (t0 >= 1) ? bf2f(xrow[(size_t)map_t(brn, t0 - 1) * DI + d]) : 0.f;
  int mt = map_t(brn, t0);
  float xc  = bf2f(xrow[(size_t)mt * DI + d]);
  float del = bf2f(drow[(size_t)t0 * DI + d]);
  float sz  = bf2f(szrow[(size_t)mt * DI + d]);
  for (int t = 0; t < LC; ++t) {
    float xn = 0.f, deln = 0.f, szn = 0.f;
    int mtn = 0;
    if (t + 1 < LC) {
      int tg1 = t0 + t + 1;
      mtn = map_t(brn, tg1);
      xn = bf2f(xrow[(size_t)mtn * DI + d]);
      deln = bf2f(drow[(size_t)tg1 * DI + d]);
      szn = bf2f(szrow[(size_t)mtn * DI + d]);
    }
    float xa = silu_f(fmaf(w.w, xc, fmaf(w.z, xm1, fmaf(w.y, xm2, w.x * xm3))));
    float dtx = del * xa;
    float dc[16];
    if (fastp) {
      pow_ladder(exp2f(-del * 1.44269504f), dc);
    } else {
#pragma unroll
      for (int n = 0; n < 16; ++n) dc[n] = exp2f(del * a2[n]);
    }
    float y0 = 0.f, y1 = 0.f, y2 = 0.f, y3 = 0.f;
#pragma unroll
    for (int g = 0; g < 4; ++g) {
      float4 Bv = *(const float4*)&BCt[t][g * 4];
      float4 Cv = *(const float4*)&BCt[t][16 + g * 4];
      const float* Bp = (const float*)&Bv;
      const float* Cp = (const float*)&Cv;
#pragma unroll
      for (int k = 0; k < 4; ++k) {
        int n = g * 4 + k;
        h[n] = fmaf(h[n], dc[n], dtx * Bp[k]);
        if (k == 0) y0 = fmaf(h[n], Cp[k], y0);
        else if (k == 1) y1 = fmaf(h[n], Cp[k], y1);
        else if (k == 2) y2 = fmaf(h[n], Cp[k], y2);
        else y3 = fmaf(h[n], Cp[k], y3);
      }
    }
    float y = (y0 + y1) + (y2 + y3) + Dv * xa;
    ybuf[((size_t)b * L_SEQ + mt) * (3 * DI) + (size_t)brn * DI + d] = f2bf(y * sz);
    xm3 = xm2; xm2 = xm1; xm1 = xc; xc = xn; del = deln; sz = szn; mt = mtn;
  }
}

extern "C" void kernel_launch(void* const* d_in, const int* in_sizes, int n_in,
                              void* d_out, int out_size, void* d_ws, size_t ws_size,
                              hipStream_t stream) {
  const float* hs        = (const float*)d_in[0];
  const float* in_proj_w = (const float*)d_in[1];
  const float* conv_w    = (const float*)d_in[2];
  const float* x_proj_w  = (const float*)d_in[3];
  const float* dt_proj_w = (const float*)d_in[4];
  const float* dt_bias   = (const float*)d_in[5];
  const float* A_log     = (const float*)d_in[6];
  const float* D_param   = (const float*)d_in[7];
  const float* out_proj_w= (const float*)d_in[8];
  float* out = (float*)d_out;
  float* ws = (float*)d_ws;

  unsigned short* xTB  = (unsigned short*)(ws);             // 12,288,000 sh
  unsigned short* szTB = (unsigned short*)(ws + 6144000);   // 12,288,000 sh
  unsigned short* dtrB = (unsigned short*)(ws + 12288000);  // 1,152,000 sh
  float* BC            = ws + 12864000;                     // 768,000 f
  unsigned short* dT   = (unsigned short*)(ws + 13632000);  // 36,864,000 sh
  float* hO            = ws + 32064000;                     // 7,372,800 f
  float* Sc            = ws + 39436800;                     // 460,800 f
  unsigned short* dpwB = (unsigned short*)(ws + 39897600);  // 221,184 sh
  unsigned short* OWb  = (unsigned short*)(ws + 40008192);  // 1,179,648 sh
  // region R (disjoint lifetimes): {hsB, Wb} then {ybuf}
  unsigned short* hsB  = (unsigned short*)(ws + 40598016);  // 6,144,000 sh
  unsigned short* Wb   = hsB + 6144000;                     // 2,359,296 sh
  unsigned short* ybuf = (unsigned short*)(ws + 40598016);  // 36,864,000 sh
  // total: 40,598,016 + 18,432,000 = 59,030,016 floats = 236.1 MB

  k_cast_bf16<<<3000, 256, 0, stream>>>(hs, hsB, 6144000);
  k_cast_bf16<<<1152, 256, 0, stream>>>(in_proj_w, Wb, 2359296);
  k_cast_bf16<<<576, 256, 0, stream>>>(out_proj_w, OWb, 1179648);
  k_cast_bf16<<<108, 256, 0, stream>>>(dt_proj_w, dpwB, 221184);

  k_gemm_bt<DM, DM, 1><<<dim3(63, 24), 256, 0, stream>>>(Wb, hsB, nullptr, xTB, szTB);

  k_xprojb<<<dim3(63, 6), 256, 0, stream>>>(xTB, x_proj_w, conv_w, dtrB, BC);
  k_dtg<<<dim3(32, 12, 6), 256, 0, stream>>>(dpwB, dtrB, dt_bias, dT);

  k_scan1c<<<dim3(6, NCH, 6), 256, 0, stream>>>(xTB, dT, BC, conv_w, A_log, hO, Sc);
  k_scan2c<<<576, 256, 0, stream>>>(hO, Sc, A_log);
  k_scan3c<<<dim3(6, NCH, 6), 256, 0, stream>>>(xTB, dT, BC, conv_w, A_log, D_param,
                                                hO, szTB, ybuf);

  k_gemm_bt<3 * DI, DI, 0><<<dim3(63, 6), 256, 0, stream>>>(OWb, ybuf, out, nullptr, nullptr);
}

// Round 6
// 704.022 us; speedup vs baseline: 6.2685x; 1.2355x over previous
//
#include <hip/hip_runtime.h>
#include <math.h>

#define L_SEQ 4000
#define DM 768
#define DI 1536
#define DS 16
#define DTRK 48
#define NCH 50
#define LC 80
#define NBL 8000

typedef __attribute__((ext_vector_type(8))) short short8;
typedef __attribute__((ext_vector_type(8))) unsigned short ushort8;
typedef __attribute__((ext_vector_type(4))) unsigned short ushort4v;
typedef __attribute__((ext_vector_type(4))) float floatx4;

__device__ __forceinline__ float silu_f(float x) { return x / (1.f + __expf(-x)); }
__device__ __forceinline__ float softplus_f(float x) {
  return fmaxf(x, 0.f) + log1pf(__expf(-fabsf(x)));
}
__device__ __forceinline__ int map_t(int branch, int t) {
  if (branch == 0) return t;
  if (branch == 1) return L_SEQ - 1 - t;
  return (t % 5) * 800 + t / 5;
}
__device__ __forceinline__ unsigned short f2bf(float f) {
  unsigned int u = __float_as_uint(f);
  u = (u + 0x7fffu + ((u >> 16) & 1u)) >> 16;
  return (unsigned short)u;
}
__device__ __forceinline__ float bf2f(unsigned short u) {
  return __uint_as_float(((unsigned int)u) << 16);
}
__device__ __forceinline__ void glds16(const void* g, void* l) {
  __builtin_amdgcn_global_load_lds((const __attribute__((address_space(1))) void*)g,
                                   (__attribute__((address_space(3))) void*)l, 16, 0, 0);
}
// binary power ladder: dc[n] = E^(n+1), depth 4, 15 muls
__device__ __forceinline__ void pow_ladder(float E1, float* dc) {
  float E2 = E1 * E1, E4 = E2 * E2, E8 = E4 * E4;
  float E3 = E2 * E1, E5 = E4 * E1, E6 = E4 * E2, E7 = E4 * E3;
  dc[0] = E1; dc[1] = E2; dc[2] = E3; dc[3] = E4;
  dc[4] = E5; dc[5] = E6; dc[6] = E7; dc[7] = E8;
  dc[8] = E8 * E1; dc[9] = E8 * E2; dc[10] = E8 * E3; dc[11] = E8 * E4;
  dc[12] = E8 * E5; dc[13] = E8 * E6; dc[14] = E8 * E7; dc[15] = E8 * E8;
}

// ---------------- cast fp32 -> bf16 ----------------
__global__ __launch_bounds__(256) void k_cast_bf16(const float* __restrict__ src,
                                                   unsigned short* __restrict__ dst, int n) {
  int i = (blockIdx.x * 256 + threadIdx.x) * 8;
  if (i >= n) return;
  float4 v0 = *(const float4*)&src[i];
  float4 v1 = *(const float4*)&src[i + 4];
  ushort8 r;
  r[0] = f2bf(v0.x); r[1] = f2bf(v0.y); r[2] = f2bf(v0.z); r[3] = f2bf(v0.w);
  r[4] = f2bf(v1.x); r[5] = f2bf(v1.y); r[6] = f2bf(v1.z); r[7] = f2bf(v1.w);
  *(ushort8*)&dst[i] = r;
}

// ---------------- MFMA GEMM (bt): C[m][n] = sum_k A[m][(k%KA)]*B[n][k] ----
template <int KDIM, int KA, int MODE>
__global__ __launch_bounds__(256) void k_gemm_bt(const unsigned short* __restrict__ A,
                                                 const unsigned short* __restrict__ B,
                                                 float* __restrict__ O0f,
                                                 unsigned short* __restrict__ O0h,
                                                 unsigned short* __restrict__ O1h) {
  __shared__ unsigned short As[128 * 32];
  __shared__ unsigned short Bs[128 * 32];
  int m0 = blockIdx.y * 128;
  int n0 = blockIdx.x * 128;
  int tid = threadIdx.x;
  int lane = tid & 63;
  int wm = (tid >> 6) & 1;
  int wn = tid >> 7;
  int srow = tid >> 2;
  int skof = (tid & 3) * 8;
  int brow0 = n0 + srow;       if (brow0 >= NBL) brow0 = NBL - 1;
  int brow1 = n0 + srow + 64;  if (brow1 >= NBL) brow1 = NBL - 1;
  floatx4 zero = {0.f, 0.f, 0.f, 0.f};
  floatx4 acc[4][4];
#pragma unroll
  for (int i = 0; i < 4; ++i)
#pragma unroll
    for (int j = 0; j < 4; ++j) acc[i][j] = zero;
  int ar = wm * 64 + (lane & 15);
  int br = wn * 64 + (lane & 15);
  int kq = (lane >> 4) * 8;
  for (int k0 = 0; k0 < KDIM; k0 += 32) {
    int ka = (k0 % KA);
    glds16(&A[(size_t)(m0 + srow) * KA + ka + skof],      &As[tid * 8]);
    glds16(&A[(size_t)(m0 + srow + 64) * KA + ka + skof], &As[tid * 8 + 2048]);
    glds16(&B[(size_t)brow0 * KDIM + k0 + skof], &Bs[tid * 8]);
    glds16(&B[(size_t)brow1 * KDIM + k0 + skof], &Bs[tid * 8 + 2048]);
    __syncthreads();
    short8 a[4], b[4];
#pragma unroll
    for (int i = 0; i < 4; ++i) a[i] = *(const short8*)&As[(ar + i * 16) * 32 + kq];
#pragma unroll
    for (int i = 0; i < 4; ++i) b[i] = *(const short8*)&Bs[(br + i * 16) * 32 + kq];
#pragma unroll
    for (int mt = 0; mt < 4; ++mt)
#pragma unroll
      for (int nt = 0; nt < 4; ++nt)
        acc[mt][nt] = __builtin_amdgcn_mfma_f32_16x16x32_bf16(a[mt], b[nt], acc[mt][nt], 0, 0, 0);
    __syncthreads();
  }
  int mq = m0 + wm * 64 + ((lane >> 4) << 2);
  int nq = n0 + wn * 64 + (lane & 15);
#pragma unroll
  for (int nt = 0; nt < 4; ++nt) {
    int n = nq + nt * 16;
    if (n >= NBL) continue;
#pragma unroll
    for (int mt = 0; mt < 4; ++mt) {
      int m = mq + mt * 16;
      floatx4 v = acc[mt][nt];
      if (MODE == 0) {
        *(floatx4*)&O0f[(size_t)n * DM + m] = v;
      } else {
        if (m < DI) {
          ushort4v r;
          r[0] = f2bf(v[0]); r[1] = f2bf(v[1]); r[2] = f2bf(v[2]); r[3] = f2bf(v[3]);
          *(ushort4v*)&O0h[(size_t)n * DI + m] = r;
        } else {
          ushort4v r;
          r[0] = f2bf(silu_f(v[0])); r[1] = f2bf(silu_f(v[1]));
          r[2] = f2bf(silu_f(v[2])); r[3] = f2bf(silu_f(v[3]));
          *(ushort4v*)&O1h[(size_t)n * DI + m - DI] = r;
        }
      }
    }
  }
}

// ---------------- conv+silu materialization: xTB[b][l][d] -> xaB[z][t][d] bf16 ----------------
__global__ __launch_bounds__(256) void k_conv_all(const unsigned short* __restrict__ xTB,
                                                  const float* __restrict__ cw_all,
                                                  unsigned short* __restrict__ xaB) {
  int z = blockIdx.z;
  int brn = z >> 1, b = z & 1;
  int d = blockIdx.x * 256 + threadIdx.x;
  int t0 = blockIdx.y * 8;
  const unsigned short* xrow = xTB + (size_t)b * L_SEQ * DI;
  float4 w = *(const float4*)&cw_all[((size_t)brn * DI + d) * 4];
  float xm3 = (t0 >= 3) ? bf2f(xrow[(size_t)map_t(brn, t0 - 3) * DI + d]) : 0.f;
  float xm2 = (t0 >= 2) ? bf2f(xrow[(size_t)map_t(brn, t0 - 2) * DI + d]) : 0.f;
  float xm1 = (t0 >= 1) ? bf2f(xrow[(size_t)map_t(brn, t0 - 1) * DI + d]) : 0.f;
#pragma unroll
  for (int i = 0; i < 8; ++i) {
    int t = t0 + i;
    float xc = bf2f(xrow[(size_t)map_t(brn, t) * DI + d]);
    float xa = silu_f(fmaf(w.w, xc, fmaf(w.z, xm1, fmaf(w.y, xm2, w.x * xm3))));
    xaB[((size_t)z * L_SEQ + t) * DI + d] = f2bf(xa);
    xm3 = xm2; xm2 = xm1; xm1 = xc;
  }
}

// ---------------- xproj MFMA: C[j][t] = sum_d xpw[j][d]*xa[z][t][d] ----------------
// j<48 -> dtrB[z][t][48] bf16 ; 48<=j<80 -> BC[z][j-48][t] fp32
__global__ __launch_bounds__(256) void k_xprojm(const unsigned short* __restrict__ xpwB,
                                                const unsigned short* __restrict__ xaB,
                                                unsigned short* __restrict__ dtrB,
                                                float* __restrict__ BC) {
  __shared__ unsigned short As[128 * 32];
  __shared__ unsigned short Bs[128 * 32];
  int z = blockIdx.z;
  int brn = z >> 1;
  int n0 = blockIdx.x * 128;  // t tile
  int tid = threadIdx.x;
  int lane = tid & 63;
  int wm = (tid >> 6) & 1;
  int wn = tid >> 7;
  int srow = tid >> 2;
  int skof = (tid & 3) * 8;
  int arow0 = srow;       if (arow0 > 79) arow0 = 79;
  int arow1 = srow + 64;  if (arow1 > 79) arow1 = 79;
  int brow0 = n0 + srow;       if (brow0 >= L_SEQ) brow0 = L_SEQ - 1;
  int brow1 = n0 + srow + 64;  if (brow1 >= L_SEQ) brow1 = L_SEQ - 1;
  const unsigned short* A = xpwB + (size_t)brn * 80 * DI;
  const unsigned short* Bm = xaB + (size_t)z * L_SEQ * DI;
  floatx4 zero = {0.f, 0.f, 0.f, 0.f};
  floatx4 acc[4][4];
#pragma unroll
  for (int i = 0; i < 4; ++i)
#pragma unroll
    for (int j = 0; j < 4; ++j) acc[i][j] = zero;
  int ar = wm * 64 + (lane & 15);
  int br = wn * 64 + (lane & 15);
  int kq = (lane >> 4) * 8;
  for (int k0 = 0; k0 < DI; k0 += 32) {
    glds16(&A[(size_t)arow0 * DI + k0 + skof], &As[tid * 8]);
    glds16(&A[(size_t)arow1 * DI + k0 + skof], &As[tid * 8 + 2048]);
    glds16(&Bm[(size_t)brow0 * DI + k0 + skof], &Bs[tid * 8]);
    glds16(&Bm[(size_t)brow1 * DI + k0 + skof], &Bs[tid * 8 + 2048]);
    __syncthreads();
    short8 a[4], b[4];
#pragma unroll
    for (int i = 0; i < 4; ++i) a[i] = *(const short8*)&As[(ar + i * 16) * 32 + kq];
#pragma unroll
    for (int i = 0; i < 4; ++i) b[i] = *(const short8*)&Bs[(br + i * 16) * 32 + kq];
#pragma unroll
    for (int mt = 0; mt < 4; ++mt)
#pragma unroll
      for (int nt = 0; nt < 4; ++nt)
        acc[mt][nt] = __builtin_amdgcn_mfma_f32_16x16x32_bf16(a[mt], b[nt], acc[mt][nt], 0, 0, 0);
    __syncthreads();
  }
  int mq = wm * 64 + ((lane >> 4) << 2);
  int nq = n0 + wn * 64 + (lane & 15);
#pragma unroll
  for (int nt = 0; nt < 4; ++nt) {
    int t = nq + nt * 16;
    if (t >= L_SEQ) continue;
#pragma unroll
    for (int mt = 0; mt < 4; ++mt) {
      int j = mq + mt * 16;
      if (j >= 80) continue;
      floatx4 v = acc[mt][nt];
      if (j < 48) {
        ushort4v r;
        r[0] = f2bf(v[0]); r[1] = f2bf(v[1]); r[2] = f2bf(v[2]); r[3] = f2bf(v[3]);
        *(ushort4v*)&dtrB[((size_t)z * L_SEQ + t) * DTRK + j] = r;
      } else {
#pragma unroll
        for (int r = 0; r < 4; ++r)
          BC[((size_t)z * 32 + (j + r - 48)) * L_SEQ + t] = v[r];
      }
    }
  }
}

// ---------------- delta GEMM (MFMA, K=48 padded to 64) + softplus -> bf16 [z][t][d]
__global__ __launch_bounds__(256) void k_dtg(const unsigned short* __restrict__ dpwB,
                                             const unsigned short* __restrict__ dtrB,
                                             const float* __restrict__ dbias,
                                             unsigned short* __restrict__ dT) {
  __shared__ unsigned short As[128 * 64];
  __shared__ unsigned short Bs[128 * 64];
  int z = blockIdx.z;
  int brn = z >> 1;
  int m0 = blockIdx.y * 128;
  int n0 = blockIdx.x * 128;
  int tid = threadIdx.x;
  int lane = tid & 63;
  int wm = (tid >> 6) & 1;
  int wn = tid >> 7;
  {
    int zr = tid >> 1, zc = 48 + (tid & 1) * 8;
    ushort8 zz = {0, 0, 0, 0, 0, 0, 0, 0};
    *(ushort8*)&As[zr * 64 + zc] = zz;
    *(ushort8*)&Bs[zr * 64 + zc] = zz;
  }
  {
    int row = tid >> 1;
    int p0 = (tid & 1) * 3;
    const unsigned short* Ag = dpwB + (size_t)brn * DI * DTRK + (size_t)(m0 + row) * DTRK;
    int bro = n0 + row; if (bro > L_SEQ - 1) bro = L_SEQ - 1;
    const unsigned short* Bg = dtrB + ((size_t)z * L_SEQ + bro) * DTRK;
#pragma unroll
    for (int i = 0; i < 3; ++i) {
      int off = (p0 + i) * 8;
      *(ushort8*)&As[row * 64 + off] = *(const ushort8*)&Ag[off];
      *(ushort8*)&Bs[row * 64 + off] = *(const ushort8*)&Bg[off];
    }
  }
  __syncthreads();
  int ar = wm * 64 + (lane & 15);
  int brr = wn * 64 + (lane & 15);
  int kq = (lane >> 4) * 8;
  floatx4 zero = {0.f, 0.f, 0.f, 0.f};
  floatx4 acc[4][4];
#pragma unroll
  for (int i = 0; i < 4; ++i)
#pragma unroll
    for (int j = 0; j < 4; ++j) acc[i][j] = zero;
#pragma unroll
  for (int kk = 0; kk < 2; ++kk) {
    short8 a[4], b[4];
#pragma unroll
    for (int i = 0; i < 4; ++i) a[i] = *(const short8*)&As[(ar + i * 16) * 64 + kk * 32 + kq];
#pragma unroll
    for (int i = 0; i < 4; ++i) b[i] = *(const short8*)&Bs[(brr + i * 16) * 64 + kk * 32 + kq];
#pragma unroll
    for (int mt = 0; mt < 4; ++mt)
#pragma unroll
      for (int nt = 0; nt < 4; ++nt)
        acc[mt][nt] = __builtin_amdgcn_mfma_f32_16x16x32_bf16(a[mt], b[nt], acc[mt][nt], 0, 0, 0);
  }
  int mq = m0 + wm * 64 + ((lane >> 4) << 2);
  int nq = n0 + wn * 64 + (lane & 15);
#pragma unroll
  for (int nt = 0; nt < 4; ++nt) {
    int n = nq + nt * 16;
    if (n >= L_SEQ) continue;
#pragma unroll
    for (int mt = 0; mt < 4; ++mt) {
      int m = mq + mt * 16;
      float4 bi = *(const float4*)&dbias[(size_t)brn * DI + m];
      floatx4 v = acc[mt][nt];
      ushort4v r;
      r[0] = f2bf(softplus_f(v[0] + bi.x));
      r[1] = f2bf(softplus_f(v[1] + bi.y));
      r[2] = f2bf(softplus_f(v[2] + bi.z));
      r[3] = f2bf(softplus_f(v[3] + bi.w));
      *(ushort4v*)&dT[((size_t)z * L_SEQ + n) * DI + m] = r;
    }
  }
}

// ---------------- scan phase 1: per-chunk local state + delta-sum ----------------
__global__ __launch_bounds__(256) void k_scan1c(const unsigned short* __restrict__ xTB,
                                                const unsigned short* __restrict__ dT,
                                                const float* __restrict__ BC,
                                                const float* __restrict__ cw_all,
                                                const float* __restrict__ A_log,
                                                float* __restrict__ hO,
                                                float* __restrict__ Sc) {
  __shared__ float BtS[LC][16];
  int z = blockIdx.z;
  int brn = z >> 1, b = z & 1;
  int ch = blockIdx.y;
  int t0 = ch * LC;
  int d = blockIdx.x * 256 + threadIdx.x;
  int tid = threadIdx.x;
  for (int i = tid; i < 320; i += 256) {
    int row = i / 20;
    int c4 = (i % 20) * 4;
    float4 v = *(const float4*)&BC[((size_t)z * 32 + row) * L_SEQ + t0 + c4];
    BtS[c4 + 0][row] = v.x; BtS[c4 + 1][row] = v.y;
    BtS[c4 + 2][row] = v.z; BtS[c4 + 3][row] = v.w;
  }
  float4 w = *(const float4*)&cw_all[((size_t)brn * DI + d) * 4];
  float a2[16];
  bool fastp = true;
#pragma unroll
  for (int g = 0; g < 4; ++g) {
    float4 v = *(const float4*)&A_log[((size_t)brn * DI + d) * DS + g * 4];
    float av0 = __expf(v.x), av1 = __expf(v.y), av2 = __expf(v.z), av3 = __expf(v.w);
    a2[g * 4 + 0] = -av0 * 1.44269504f; a2[g * 4 + 1] = -av1 * 1.44269504f;
    a2[g * 4 + 2] = -av2 * 1.44269504f; a2[g * 4 + 3] = -av3 * 1.44269504f;
    fastp = fastp && fabsf(av0 - (float)(g * 4 + 1)) < 1e-3f
                  && fabsf(av1 - (float)(g * 4 + 2)) < 1e-3f
                  && fabsf(av2 - (float)(g * 4 + 3)) < 1e-3f
                  && fabsf(av3 - (float)(g * 4 + 4)) < 1e-3f;
  }
  const unsigned short* xrow = xTB + (size_t)b * L_SEQ * DI;
  const unsigned short* drow = dT + (size_t)z * L_SEQ * DI;
  float h[16];
#pragma unroll
  for (int n = 0; n < 16; ++n) h[n] = 0.f;
  float S = 0.f;
  __syncthreads();
  float xm3 = (t0 >= 3) ? bf2f(xrow[(size_t)map_t(brn, t0 - 3) * DI + d]) : 0.f;
  float xm2 = (t0 >= 2) ? bf2f(xrow[(size_t)map_t(brn, t0 - 2) * DI + d]) : 0.f;
  float xm1 = (t0 >= 1) ? bf2f(xrow[(size_t)map_t(brn, t0 - 1) * DI + d]) : 0.f;
  float xc  = bf2f(xrow[(size_t)map_t(brn, t0) * DI + d]);
  float del = bf2f(drow[(size_t)t0 * DI + d]);
  for (int t = 0; t < LC; ++t) {
    float xn = 0.f, deln = 0.f;
    if (t + 1 < LC) {
      int tg1 = t0 + t + 1;
      xn = bf2f(xrow[(size_t)map_t(brn, tg1) * DI + d]);
      deln = bf2f(drow[(size_t)tg1 * DI + d]);
    }
    float xa = silu_f(fmaf(w.w, xc, fmaf(w.z, xm1, fmaf(w.y, xm2, w.x * xm3))));
    float dtx = del * xa;
    S += del;
    float dc[16];
    if (fastp) {
      pow_ladder(exp2f(-del * 1.44269504f), dc);
    } else {
#pragma unroll
      for (int n = 0; n < 16; ++n) dc[n] = exp2f(del * a2[n]);
    }
#pragma unroll
    for (int g = 0; g < 4; ++g) {
      float4 Bv = *(const float4*)&BtS[t][g * 4];
      const float* Bp = (const float*)&Bv;
#pragma unroll
      for (int k = 0; k < 4; ++k) {
        int n = g * 4 + k;
        h[n] = fmaf(h[n], dc[n], dtx * Bp[k]);
      }
    }
    xm3 = xm2; xm2 = xm1; xm1 = xc; xc = xn; del = deln;
  }
  size_t base = (((size_t)z * NCH + ch) * DI + d) * 16;
#pragma unroll
  for (int g = 0; g < 4; ++g)
    *(float4*)&hO[base + g * 4] = make_float4(h[g * 4], h[g * 4 + 1], h[g * 4 + 2], h[g * 4 + 3]);
  Sc[((size_t)z * NCH + ch) * DI + d] = S;
}

// ---------------- scan phase 2: sequential combine over chunks ----------------
__global__ __launch_bounds__(256) void k_scan2c(float* __restrict__ hO,
                                                const float* __restrict__ Sc,
                                                const float* __restrict__ A_log) {
  int idx = blockIdx.x * 256 + threadIdx.x;
  int z = idx / (DI * 16);
  int rem = idx % (DI * 16);
  int brn = z >> 1;
  float a2 = -__expf(A_log[(size_t)brn * DI * DS + rem]) * 1.44269504f;
  float H = 0.f;
  for (int c = 0; c < NCH; ++c) {
    size_t p = ((size_t)z * NCH + c) * (DI * 16) + rem;
    float th = hO[p];
    float P = exp2f(Sc[((size_t)z * NCH + c) * DI + (rem >> 4)] * a2);
    hO[p] = H;
    H = fmaf(P, H, th);
  }
}

// ---------------- scan phase 3: re-run chunk from entry state, gate, write ybuf
__global__ __launch_bounds__(256) void k_scan3c(const unsigned short* __restrict__ xTB,
                                                const unsigned short* __restrict__ dT,
                                                const float* __restrict__ BC,
                                                const float* __restrict__ cw_all,
                                                const float* __restrict__ A_log,
                                                const float* __restrict__ Dp,
                                                const float* __restrict__ hO,
                                                const unsigned short* __restrict__ szTB,
                                                unsigned short* __restrict__ ybuf) {
  __shared__ float BCt[LC][32];
  int z = blockIdx.z;
  int brn = z >> 1, b = z & 1;
  int ch = blockIdx.y;
  int t0 = ch * LC;
  int d = blockIdx.x * 256 + threadIdx.x;
  int tid = threadIdx.x;
  for (int i = tid; i < 640; i += 256) {
    int row = i / 20;
    int c4 = (i % 20) * 4;
    float4 v = *(const float4*)&BC[((size_t)z * 32 + row) * L_SEQ + t0 + c4];
    BCt[c4 + 0][row] = v.x; BCt[c4 + 1][row] = v.y;
    BCt[c4 + 2][row] = v.z; BCt[c4 + 3][row] = v.w;
  }
  float4 w = *(const float4*)&cw_all[((size_t)brn * DI + d) * 4];
  float a2[16];
  bool fastp = true;
#pragma unroll
  for (int g = 0; g < 4; ++g) {
    float4 v = *(const float4*)&A_log[((size_t)brn * DI + d) * DS + g * 4];
    float av0 = __expf(v.x), av1 = __expf(v.y), av2 = __expf(v.z), av3 = __expf(v.w);
    a2[g * 4 + 0] = -av0 * 1.44269504f; a2[g * 4 + 1] = -av1 * 1.44269504f;
    a2[g * 4 + 2] = -av2 * 1.44269504f; a2[g * 4 + 3] = -av3 * 1.44269504f;
    fastp = fastp && fabsf(av0 - (float)(g * 4 + 1)) < 1e-3f
                  && fabsf(av1 - (float)(g * 4 + 2)) < 1e-3f
                  && fabsf(av2 - (float)(g * 4 + 3)) < 1e-3f
                  && fabsf(av3 - (float)(g * 4 + 4)) < 1e-3f;
  }
  float Dv = Dp[(size_t)brn * DI + d];
  const unsigned short* xrow = xTB + (size_t)b * L_SEQ * DI;
  const unsigned short* drow = dT + (size_t)z * L_SEQ * DI;
  const unsigned short* szrow = szTB + (size_t)b * L_SEQ * DI;
  float h[16];
  size_t hbase = (((size_t)z * NCH + ch) * DI + d) * 16;
#pragma unroll
  for (int g = 0; g < 4; ++g) {
    float4 v = *(const float4*)&hO[hbase + g * 4];
    h[g * 4 + 0] = v.x; h[g * 4 + 1] = v.y; h[g * 4 + 2] = v.z; h[g * 4 + 3] = v.w;
  }
  __syncthreads();
  float xm3 = (t0 >= 3) ? bf2f(xrow[(size_t)map_t(brn, t0 - 3) * DI + d]) : 0.f;
  float xm2 = (t0 >= 2) ? bf2f(xrow[(size_t)map_t(brn, t0 - 2) * DI + d]) : 0.f;
  float xm1 = (t0 >= 1) ? bf2f(xrow[(size_t)map_t(brn, t0 - 1) * DI + d]) : 0.f;
  int mt = map_t(brn, t0);
  float xc  = bf2f(xrow[(size_t)mt * DI + d]);
  float del = bf2f(drow[(size_t)t0 * DI + d]);
  float sz  = bf2f(szrow[(size_t)mt * DI + d]);
  for (int t = 0; t < LC; ++t) {
    float xn = 0.f, deln = 0.f, szn = 0.f;
    int mtn = 0;
    if (t + 1 < LC) {
      int tg1 = t0 + t + 1;
      mtn = map_t(brn, tg1);
      xn = bf2f(xrow[(size_t)mtn * DI + d]);
      deln = bf2f(drow[(size_t)tg1 * DI + d]);
      szn = bf2f(szrow[(size_t)mtn * DI + d]);
    }
    float xa = silu_f(fmaf(w.w, xc, fmaf(w.z, xm1, fmaf(w.y, xm2, w.x * xm3))));
    float dtx = del * xa;
    float dc[16];
    if (fastp) {
      pow_ladder(exp2f(-del * 1.44269504f), dc);
    } else {
#pragma unroll
      for (int n = 0; n < 16; ++n) dc[n] = exp2f(del * a2[n]);
    }
    float y0 = 0.f, y1 = 0.f, y2 = 0.f, y3 = 0.f;
#pragma unroll
    for (int g = 0; g < 4; ++g) {
      float4 Bv = *(const float4*)&BCt[t][g * 4];
      float4 Cv = *(const float4*)&BCt[t][16 + g * 4];
      const float* Bp = (const float*)&Bv;
      const float* Cp = (const float*)&Cv;
#pragma unroll
      for (int k = 0; k < 4; ++k) {
        int n = g * 4 + k;
        h[n] = fmaf(h[n], dc[n], dtx * Bp[k]);
        if (k == 0) y0 = fmaf(h[n], Cp[k], y0);
        else if (k == 1) y1 = fmaf(h[n], Cp[k], y1);
        else if (k == 2) y2 = fmaf(h[n], Cp[k], y2);
        else y3 = fmaf(h[n], Cp[k], y3);
      }
    }
    float y = (y0 + y1) + (y2 + y3) + Dv * xa;
    ybuf[((size_t)b * L_SEQ + mt) * (3 * DI) + (size_t)brn * DI + d] = f2bf(y * sz);
    xm3 = xm2; xm2 = xm1; xm1 = xc; xc = xn; del = deln; sz = szn; mt = mtn;
  }
}

extern "C" void kernel_launch(void* const* d_in, const int* in_sizes, int n_in,
                              void* d_out, int out_size, void* d_ws, size_t ws_size,
                              hipStream_t stream) {
  const float* hs        = (const float*)d_in[0];
  const float* in_proj_w = (const float*)d_in[1];
  const float* conv_w    = (const float*)d_in[2];
  const float* x_proj_w  = (const float*)d_in[3];
  const float* dt_proj_w = (const float*)d_in[4];
  const float* dt_bias   = (const float*)d_in[5];
  const float* A_log     = (const float*)d_in[6];
  const float* D_param   = (const float*)d_in[7];
  const float* out_proj_w= (const float*)d_in[8];
  float* out = (float*)d_out;
  float* ws = (float*)d_ws;

  unsigned short* xTB  = (unsigned short*)(ws);             // 12,288,000 sh
  unsigned short* szTB = (unsigned short*)(ws + 6144000);   // 12,288,000 sh
  unsigned short* dtrB = (unsigned short*)(ws + 12288000);  // 1,152,000 sh
  float* BC            = ws + 12864000;                     // 768,000 f
  unsigned short* dT   = (unsigned short*)(ws + 13632000);  // 36,864,000 sh
  float* hO            = ws + 32064000;                     // 7,372,800 f
  float* Sc            = ws + 39436800;                     // 460,800 f
  unsigned short* dpwB = (unsigned short*)(ws + 39897600);  // 221,184 sh
  unsigned short* OWb  = (unsigned short*)(ws + 40008192);  // 1,179,648 sh
  // region R (disjoint lifetimes): {hsB, Wb} -> {xaB} -> {ybuf}
  unsigned short* hsB  = (unsigned short*)(ws + 40598016);  // 6,144,000 sh
  unsigned short* Wb   = hsB + 6144000;                     // 2,359,296 sh
  unsigned short* xaB  = (unsigned short*)(ws + 40598016);  // 36,864,000 sh
  unsigned short* ybuf = (unsigned short*)(ws + 40598016);  // 36,864,000 sh
  unsigned short* xpwB = (unsigned short*)(ws + 59030016);  // 368,640 sh
  // total: 59,214,336 floats = 236.9 MB

  k_cast_bf16<<<3000, 256, 0, stream>>>(hs, hsB, 6144000);
  k_cast_bf16<<<1152, 256, 0, stream>>>(in_proj_w, Wb, 2359296);
  k_cast_bf16<<<576, 256, 0, stream>>>(out_proj_w, OWb, 1179648);
  k_cast_bf16<<<108, 256, 0, stream>>>(dt_proj_w, dpwB, 221184);
  k_cast_bf16<<<180, 256, 0, stream>>>(x_proj_w, xpwB, 368640);

  k_gemm_bt<DM, DM, 1><<<dim3(63, 24), 256, 0, stream>>>(Wb, hsB, nullptr, xTB, szTB);

  k_conv_all<<<dim3(6, 500, 6), 256, 0, stream>>>(xTB, conv_w, xaB);
  k_xprojm<<<dim3(32, 1, 6), 256, 0, stream>>>(xpwB, xaB, dtrB, BC);
  k_dtg<<<dim3(32, 12, 6), 256, 0, stream>>>(dpwB, dtrB, dt_bias, dT);

  k_scan1c<<<dim3(6, NCH, 6), 256, 0, stream>>>(xTB, dT, BC, conv_w, A_log, hO, Sc);
  k_scan2c<<<576, 256, 0, stream>>>(hO, Sc, A_log);
  k_scan3c<<<dim3(6, NCH, 6), 256, 0, stream>>>(xTB, dT, BC, conv_w, A_log, D_param,
                                                hO, szTB, ybuf);

  k_gemm_bt<3 * DI, DI, 0><<<dim3(63, 6), 256, 0, stream>>>(OWb, ybuf, out, nullptr, nullptr);
}

// Round 7
// 663.373 us; speedup vs baseline: 6.6527x; 1.0613x over previous
//
#include <hip/hip_runtime.h>
#include <math.h>

#define L_SEQ 4000
#define DM 768
#define DI 1536
#define DS 16
#define DTRK 48
#define NCH 50
#define LC 80
#define NBL 8000

typedef __attribute__((ext_vector_type(8))) short short8;
typedef __attribute__((ext_vector_type(8))) unsigned short ushort8;
typedef __attribute__((ext_vector_type(4))) unsigned short ushort4v;
typedef __attribute__((ext_vector_type(4))) float floatx4;
typedef __attribute__((ext_vector_type(2))) float float2v;

__device__ __forceinline__ float silu_f(float x) { return x / (1.f + __expf(-x)); }
__device__ __forceinline__ float softplus_f(float x) {
  return fmaxf(x, 0.f) + log1pf(__expf(-fabsf(x)));
}
__device__ __forceinline__ int map_t(int branch, int t) {
  if (branch == 0) return t;
  if (branch == 1) return L_SEQ - 1 - t;
  return (t % 5) * 800 + t / 5;
}
__device__ __forceinline__ unsigned short f2bf(float f) {
  unsigned int u = __float_as_uint(f);
  u = (u + 0x7fffu + ((u >> 16) & 1u)) >> 16;
  return (unsigned short)u;
}
__device__ __forceinline__ float bf2f(unsigned short u) {
  return __uint_as_float(((unsigned int)u) << 16);
}
__device__ __forceinline__ void glds16(const void* g, void* l) {
  __builtin_amdgcn_global_load_lds((const __attribute__((address_space(1))) void*)g,
                                   (__attribute__((address_space(3))) void*)l, 16, 0, 0);
}
// packed power ladder: dc2[i] = {E^(2i+1), E^(2i+2)} for i=0..7
__device__ __forceinline__ void pow_ladder2(float E1, float2v* dc2) {
  float E2 = E1 * E1;
  float2v Ev = {E2, E2};
  dc2[0] = (float2v){E1, E2};
#pragma unroll
  for (int i = 1; i < 8; ++i) dc2[i] = dc2[i - 1] * Ev;
}

// ---------------- merged cast fp32 -> bf16 for all 5 weight/input arrays ----------------
__device__ __forceinline__ void cast_seg(const float* __restrict__ src,
                                         unsigned short* __restrict__ dst,
                                         int blk, int n) {
  int i = (blk * 256 + (int)threadIdx.x) * 8;
  if (i >= n) return;
  float4 v0 = *(const float4*)&src[i];
  float4 v1 = *(const float4*)&src[i + 4];
  ushort8 r;
  r[0] = f2bf(v0.x); r[1] = f2bf(v0.y); r[2] = f2bf(v0.z); r[3] = f2bf(v0.w);
  r[4] = f2bf(v1.x); r[5] = f2bf(v1.y); r[6] = f2bf(v1.z); r[7] = f2bf(v1.w);
  *(ushort8*)&dst[i] = r;
}
__global__ __launch_bounds__(256) void k_cast5(const float* s0, unsigned short* d0,
                                               const float* s1, unsigned short* d1,
                                               const float* s2, unsigned short* d2,
                                               const float* s3, unsigned short* d3,
                                               const float* s4, unsigned short* d4) {
  int blk = blockIdx.x;
  if (blk < 3000)      cast_seg(s0, d0, blk,        6144000);
  else if (blk < 4152) cast_seg(s1, d1, blk - 3000, 2359296);
  else if (blk < 4728) cast_seg(s2, d2, blk - 4152, 1179648);
  else if (blk < 4836) cast_seg(s3, d3, blk - 4728, 221184);
  else                 cast_seg(s4, d4, blk - 4836, 368640);
}

// ---------------- MFMA GEMM (bt): C[m][n] = sum_k A[m][(k%KA)]*B[n][k] ----
template <int KDIM, int KA, int MODE>
__global__ __launch_bounds__(256) void k_gemm_bt(const unsigned short* __restrict__ A,
                                                 const unsigned short* __restrict__ B,
                                                 float* __restrict__ O0f,
                                                 unsigned short* __restrict__ O0h,
                                                 unsigned short* __restrict__ O1h) {
  __shared__ unsigned short As[128 * 32];
  __shared__ unsigned short Bs[128 * 32];
  int m0 = blockIdx.y * 128;
  int n0 = blockIdx.x * 128;
  int tid = threadIdx.x;
  int lane = tid & 63;
  int wm = (tid >> 6) & 1;
  int wn = tid >> 7;
  int srow = tid >> 2;
  int skof = (tid & 3) * 8;
  int brow0 = n0 + srow;       if (brow0 >= NBL) brow0 = NBL - 1;
  int brow1 = n0 + srow + 64;  if (brow1 >= NBL) brow1 = NBL - 1;
  floatx4 zero = {0.f, 0.f, 0.f, 0.f};
  floatx4 acc[4][4];
#pragma unroll
  for (int i = 0; i < 4; ++i)
#pragma unroll
    for (int j = 0; j < 4; ++j) acc[i][j] = zero;
  int ar = wm * 64 + (lane & 15);
  int br = wn * 64 + (lane & 15);
  int kq = (lane >> 4) * 8;
  for (int k0 = 0; k0 < KDIM; k0 += 32) {
    int ka = (k0 % KA);
    glds16(&A[(size_t)(m0 + srow) * KA + ka + skof],      &As[tid * 8]);
    glds16(&A[(size_t)(m0 + srow + 64) * KA + ka + skof], &As[tid * 8 + 2048]);
    glds16(&B[(size_t)brow0 * KDIM + k0 + skof], &Bs[tid * 8]);
    glds16(&B[(size_t)brow1 * KDIM + k0 + skof], &Bs[tid * 8 + 2048]);
    __syncthreads();
    short8 a[4], b[4];
#pragma unroll
    for (int i = 0; i < 4; ++i) a[i] = *(const short8*)&As[(ar + i * 16) * 32 + kq];
#pragma unroll
    for (int i = 0; i < 4; ++i) b[i] = *(const short8*)&Bs[(br + i * 16) * 32 + kq];
#pragma unroll
    for (int mt = 0; mt < 4; ++mt)
#pragma unroll
      for (int nt = 0; nt < 4; ++nt)
        acc[mt][nt] = __builtin_amdgcn_mfma_f32_16x16x32_bf16(a[mt], b[nt], acc[mt][nt], 0, 0, 0);
    __syncthreads();
  }
  int mq = m0 + wm * 64 + ((lane >> 4) << 2);
  int nq = n0 + wn * 64 + (lane & 15);
#pragma unroll
  for (int nt = 0; nt < 4; ++nt) {
    int n = nq + nt * 16;
    if (n >= NBL) continue;
#pragma unroll
    for (int mt = 0; mt < 4; ++mt) {
      int m = mq + mt * 16;
      floatx4 v = acc[mt][nt];
      if (MODE == 0) {
        *(floatx4*)&O0f[(size_t)n * DM + m] = v;
      } else {
        if (m < DI) {
          ushort4v r;
          r[0] = f2bf(v[0]); r[1] = f2bf(v[1]); r[2] = f2bf(v[2]); r[3] = f2bf(v[3]);
          *(ushort4v*)&O0h[(size_t)n * DI + m] = r;
        } else {
          ushort4v r;
          r[0] = f2bf(silu_f(v[0])); r[1] = f2bf(silu_f(v[1]));
          r[2] = f2bf(silu_f(v[2])); r[3] = f2bf(silu_f(v[3]));
          *(ushort4v*)&O1h[(size_t)n * DI + m - DI] = r;
        }
      }
    }
  }
}

// ---------------- conv+silu materialization: xTB[b][l][d] -> xaB[z][t][d] bf16 ----------------
__global__ __launch_bounds__(256) void k_conv_all(const unsigned short* __restrict__ xTB,
                                                  const float* __restrict__ cw_all,
                                                  unsigned short* __restrict__ xaB) {
  int z = blockIdx.z;
  int brn = z >> 1, b = z & 1;
  int d = blockIdx.x * 256 + threadIdx.x;
  int t0 = blockIdx.y * 8;
  const unsigned short* xrow = xTB + (size_t)b * L_SEQ * DI;
  float4 w = *(const float4*)&cw_all[((size_t)brn * DI + d) * 4];
  float xm3 = (t0 >= 3) ? bf2f(xrow[(size_t)map_t(brn, t0 - 3) * DI + d]) : 0.f;
  float xm2 = (t0 >= 2) ? bf2f(xrow[(size_t)map_t(brn, t0 - 2) * DI + d]) : 0.f;
  float xm1 = (t0 >= 1) ? bf2f(xrow[(size_t)map_t(brn, t0 - 1) * DI + d]) : 0.f;
#pragma unroll
  for (int i = 0; i < 8; ++i) {
    int t = t0 + i;
    float xc = bf2f(xrow[(size_t)map_t(brn, t) * DI + d]);
    float xa = silu_f(fmaf(w.w, xc, fmaf(w.z, xm1, fmaf(w.y, xm2, w.x * xm3))));
    xaB[((size_t)z * L_SEQ + t) * DI + d] = f2bf(xa);
    xm3 = xm2; xm2 = xm1; xm1 = xc;
  }
}

// ---------------- xproj MFMA: C[j][t] = sum_d xpw[j][d]*xa[z][t][d] ----------------
__global__ __launch_bounds__(256) void k_xprojm(const unsigned short* __restrict__ xpwB,
                                                const unsigned short* __restrict__ xaB,
                                                unsigned short* __restrict__ dtrB,
                                                float* __restrict__ BC) {
  __shared__ unsigned short As[128 * 32];
  __shared__ unsigned short Bs[128 * 32];
  int z = blockIdx.z;
  int brn = z >> 1;
  int n0 = blockIdx.x * 128;
  int tid = threadIdx.x;
  int lane = tid & 63;
  int wm = (tid >> 6) & 1;
  int wn = tid >> 7;
  int srow = tid >> 2;
  int skof = (tid & 3) * 8;
  int arow0 = srow;       if (arow0 > 79) arow0 = 79;
  int arow1 = srow + 64;  if (arow1 > 79) arow1 = 79;
  int brow0 = n0 + srow;       if (brow0 >= L_SEQ) brow0 = L_SEQ - 1;
  int brow1 = n0 + srow + 64;  if (brow1 >= L_SEQ) brow1 = L_SEQ - 1;
  const unsigned short* A = xpwB + (size_t)brn * 80 * DI;
  const unsigned short* Bm = xaB + (size_t)z * L_SEQ * DI;
  floatx4 zero = {0.f, 0.f, 0.f, 0.f};
  floatx4 acc[4][4];
#pragma unroll
  for (int i = 0; i < 4; ++i)
#pragma unroll
    for (int j = 0; j < 4; ++j) acc[i][j] = zero;
  int ar = wm * 64 + (lane & 15);
  int br = wn * 64 + (lane & 15);
  int kq = (lane >> 4) * 8;
  for (int k0 = 0; k0 < DI; k0 += 32) {
    glds16(&A[(size_t)arow0 * DI + k0 + skof], &As[tid * 8]);
    glds16(&A[(size_t)arow1 * DI + k0 + skof], &As[tid * 8 + 2048]);
    glds16(&Bm[(size_t)brow0 * DI + k0 + skof], &Bs[tid * 8]);
    glds16(&Bm[(size_t)brow1 * DI + k0 + skof], &Bs[tid * 8 + 2048]);
    __syncthreads();
    short8 a[4], b[4];
#pragma unroll
    for (int i = 0; i < 4; ++i) a[i] = *(const short8*)&As[(ar + i * 16) * 32 + kq];
#pragma unroll
    for (int i = 0; i < 4; ++i) b[i] = *(const short8*)&Bs[(br + i * 16) * 32 + kq];
#pragma unroll
    for (int mt = 0; mt < 4; ++mt)
#pragma unroll
      for (int nt = 0; nt < 4; ++nt)
        acc[mt][nt] = __builtin_amdgcn_mfma_f32_16x16x32_bf16(a[mt], b[nt], acc[mt][nt], 0, 0, 0);
    __syncthreads();
  }
  int mq = wm * 64 + ((lane >> 4) << 2);
  int nq = n0 + wn * 64 + (lane & 15);
#pragma unroll
  for (int nt = 0; nt < 4; ++nt) {
    int t = nq + nt * 16;
    if (t >= L_SEQ) continue;
#pragma unroll
    for (int mt = 0; mt < 4; ++mt) {
      int j = mq + mt * 16;
      if (j >= 80) continue;
      floatx4 v = acc[mt][nt];
      if (j < 48) {
        ushort4v r;
        r[0] = f2bf(v[0]); r[1] = f2bf(v[1]); r[2] = f2bf(v[2]); r[3] = f2bf(v[3]);
        *(ushort4v*)&dtrB[((size_t)z * L_SEQ + t) * DTRK + j] = r;
      } else {
#pragma unroll
        for (int r = 0; r < 4; ++r)
          BC[((size_t)z * 32 + (j + r - 48)) * L_SEQ + t] = v[r];
      }
    }
  }
}

// ---------------- delta GEMM (MFMA, K=48 padded to 64) + softplus -> bf16 [z][t][d]
__global__ __launch_bounds__(256) void k_dtg(const unsigned short* __restrict__ dpwB,
                                             const unsigned short* __restrict__ dtrB,
                                             const float* __restrict__ dbias,
                                             unsigned short* __restrict__ dT) {
  __shared__ unsigned short As[128 * 64];
  __shared__ unsigned short Bs[128 * 64];
  int z = blockIdx.z;
  int brn = z >> 1;
  int m0 = blockIdx.y * 128;
  int n0 = blockIdx.x * 128;
  int tid = threadIdx.x;
  int lane = tid & 63;
  int wm = (tid >> 6) & 1;
  int wn = tid >> 7;
  {
    int zr = tid >> 1, zc = 48 + (tid & 1) * 8;
    ushort8 zz = {0, 0, 0, 0, 0, 0, 0, 0};
    *(ushort8*)&As[zr * 64 + zc] = zz;
    *(ushort8*)&Bs[zr * 64 + zc] = zz;
  }
  {
    int row = tid >> 1;
    int p0 = (tid & 1) * 3;
    const unsigned short* Ag = dpwB + (size_t)brn * DI * DTRK + (size_t)(m0 + row) * DTRK;
    int bro = n0 + row; if (bro > L_SEQ - 1) bro = L_SEQ - 1;
    const unsigned short* Bg = dtrB + ((size_t)z * L_SEQ + bro) * DTRK;
#pragma unroll
    for (int i = 0; i < 3; ++i) {
      int off = (p0 + i) * 8;
      *(ushort8*)&As[row * 64 + off] = *(const ushort8*)&Ag[off];
      *(ushort8*)&Bs[row * 64 + off] = *(const ushort8*)&Bg[off];
    }
  }
  __syncthreads();
  int ar = wm * 64 + (lane & 15);
  int brr = wn * 64 + (lane & 15);
  int kq = (lane >> 4) * 8;
  floatx4 zero = {0.f, 0.f, 0.f, 0.f};
  floatx4 acc[4][4];
#pragma unroll
  for (int i = 0; i < 4; ++i)
#pragma unroll
    for (int j = 0; j < 4; ++j) acc[i][j] = zero;
#pragma unroll
  for (int kk = 0; kk < 2; ++kk) {
    short8 a[4], b[4];
#pragma unroll
    for (int i = 0; i < 4; ++i) a[i] = *(const short8*)&As[(ar + i * 16) * 64 + kk * 32 + kq];
#pragma unroll
    for (int i = 0; i < 4; ++i) b[i] = *(const short8*)&Bs[(brr + i * 16) * 64 + kk * 32 + kq];
#pragma unroll
    for (int mt = 0; mt < 4; ++mt)
#pragma unroll
      for (int nt = 0; nt < 4; ++nt)
        acc[mt][nt] = __builtin_amdgcn_mfma_f32_16x16x32_bf16(a[mt], b[nt], acc[mt][nt], 0, 0, 0);
  }
  int mq = m0 + wm * 64 + ((lane >> 4) << 2);
  int nq = n0 + wn * 64 + (lane & 15);
#pragma unroll
  for (int nt = 0; nt < 4; ++nt) {
    int n = nq + nt * 16;
    if (n >= L_SEQ) continue;
#pragma unroll
    for (int mt = 0; mt < 4; ++mt) {
      int m = mq + mt * 16;
      float4 bi = *(const float4*)&dbias[(size_t)brn * DI + m];
      floatx4 v = acc[mt][nt];
      ushort4v r;
      r[0] = f2bf(softplus_f(v[0] + bi.x));
      r[1] = f2bf(softplus_f(v[1] + bi.y));
      r[2] = f2bf(softplus_f(v[2] + bi.z));
      r[3] = f2bf(softplus_f(v[3] + bi.w));
      *(ushort4v*)&dT[((size_t)z * L_SEQ + n) * DI + m] = r;
    }
  }
}

// per-branch incremental time-map parameters
__device__ __forceinline__ void mt_params(int brn, int& per, int& dA, int& dB) {
  if (brn == 0) { per = 1 << 30; dA = 1; dB = 1; }
  else if (brn == 1) { per = 1 << 30; dA = -1; dB = -1; }
  else { per = 5; dA = 800; dB = -3199; }
}

// ---------------- scan phase 1: per-chunk local state + delta-sum (packed fp32) ----------------
__global__ __launch_bounds__(256) void k_scan1c(const unsigned short* __restrict__ xTB,
                                                const unsigned short* __restrict__ dT,
                                                const float* __restrict__ BC,
                                                const float* __restrict__ cw_all,
                                                const float* __restrict__ A_log,
                                                float* __restrict__ hO,
                                                float* __restrict__ Sc) {
  __shared__ float BtS[LC][16];
  int z = blockIdx.z;
  int brn = z >> 1, b = z & 1;
  int ch = blockIdx.y;
  int t0 = ch * LC;
  int d = blockIdx.x * 256 + threadIdx.x;
  int tid = threadIdx.x;
  for (int i = tid; i < 320; i += 256) {
    int row = i / 20;
    int c4 = (i % 20) * 4;
    float4 v = *(const float4*)&BC[((size_t)z * 32 + row) * L_SEQ + t0 + c4];
    BtS[c4 + 0][row] = v.x; BtS[c4 + 1][row] = v.y;
    BtS[c4 + 2][row] = v.z; BtS[c4 + 3][row] = v.w;
  }
  float4 w = *(const float4*)&cw_all[((size_t)brn * DI + d) * 4];
  float a2[16];
  bool fastp = true;
#pragma unroll
  for (int g = 0; g < 4; ++g) {
    float4 v = *(const float4*)&A_log[((size_t)brn * DI + d) * DS + g * 4];
    float av0 = __expf(v.x), av1 = __expf(v.y), av2 = __expf(v.z), av3 = __expf(v.w);
    a2[g * 4 + 0] = -av0 * 1.44269504f; a2[g * 4 + 1] = -av1 * 1.44269504f;
    a2[g * 4 + 2] = -av2 * 1.44269504f; a2[g * 4 + 3] = -av3 * 1.44269504f;
    fastp = fastp && fabsf(av0 - (float)(g * 4 + 1)) < 1e-3f
                  && fabsf(av1 - (float)(g * 4 + 2)) < 1e-3f
                  && fabsf(av2 - (float)(g * 4 + 3)) < 1e-3f
                  && fabsf(av3 - (float)(g * 4 + 4)) < 1e-3f;
  }
  const unsigned short* xrow = xTB + (size_t)b * L_SEQ * DI;
  const unsigned short* drow = dT + (size_t)z * L_SEQ * DI;
  float2v h2[8];
#pragma unroll
  for (int i = 0; i < 8; ++i) h2[i] = (float2v){0.f, 0.f};
  float S = 0.f;
  int per, dA, dB;
  mt_params(brn, per, dA, dB);
  int p5 = t0 % 5;
  int mt = map_t(brn, t0);
  __syncthreads();
  float xm3 = (t0 >= 3) ? bf2f(xrow[(size_t)map_t(brn, t0 - 3) * DI + d]) : 0.f;
  float xm2 = (t0 >= 2) ? bf2f(xrow[(size_t)map_t(brn, t0 - 2) * DI + d]) : 0.f;
  float xm1 = (t0 >= 1) ? bf2f(xrow[(size_t)map_t(brn, t0 - 1) * DI + d]) : 0.f;
  float xc  = bf2f(xrow[(size_t)mt * DI + d]);
  float del = bf2f(drow[(size_t)t0 * DI + d]);
  for (int t = 0; t < LC; ++t) {
    int p5n = p5 + 1;
    int mtn = (p5n == per) ? mt + dB : mt + dA;
    if (p5n == per) p5n = 0;
    float xn = 0.f, deln = 0.f;
    if (t + 1 < LC) {
      xn = bf2f(xrow[(size_t)mtn * DI + d]);
      deln = bf2f(drow[(size_t)(t0 + t + 1) * DI + d]);
    }
    float xa = silu_f(fmaf(w.w, xc, fmaf(w.z, xm1, fmaf(w.y, xm2, w.x * xm3))));
    float dtx = del * xa;
    S += del;
    float2v dc2[8];
    if (fastp) {
      pow_ladder2(exp2f(-del * 1.44269504f), dc2);
    } else {
#pragma unroll
      for (int i = 0; i < 8; ++i)
        dc2[i] = (float2v){exp2f(del * a2[2 * i]), exp2f(del * a2[2 * i + 1])};
    }
    const float2v* B2 = (const float2v*)&BtS[t][0];
    float2v dtx2 = {dtx, dtx};
#pragma unroll
    for (int i = 0; i < 8; ++i)
      h2[i] = __builtin_elementwise_fma(h2[i], dc2[i], dtx2 * B2[i]);
    xm3 = xm2; xm2 = xm1; xm1 = xc; xc = xn; del = deln; mt = mtn; p5 = p5n;
  }
  size_t base = (((size_t)z * NCH + ch) * DI + d) * 16;
#pragma unroll
  for (int i = 0; i < 8; ++i) *(float2v*)&hO[base + i * 2] = h2[i];
  Sc[((size_t)z * NCH + ch) * DI + d] = S;
}

// ---------------- scan phase 2: sequential combine over chunks ----------------
__global__ __launch_bounds__(256) void k_scan2c(float* __restrict__ hO,
                                                const float* __restrict__ Sc,
                                                const float* __restrict__ A_log) {
  int idx = blockIdx.x * 256 + threadIdx.x;
  int z = idx / (DI * 16);
  int rem = idx % (DI * 16);
  int brn = z >> 1;
  float a2 = -__expf(A_log[(size_t)brn * DI * DS + rem]) * 1.44269504f;
  float H = 0.f;
  for (int c = 0; c < NCH; ++c) {
    size_t p = ((size_t)z * NCH + c) * (DI * 16) + rem;
    float th = hO[p];
    float P = exp2f(Sc[((size_t)z * NCH + c) * DI + (rem >> 4)] * a2);
    hO[p] = H;
    H = fmaf(P, H, th);
  }
}

// ---------------- scan phase 3: re-run chunk, gate, write ybuf (packed fp32) ----------------
__global__ __launch_bounds__(256) void k_scan3c(const unsigned short* __restrict__ xTB,
                                                const unsigned short* __restrict__ dT,
                                                const float* __restrict__ BC,
                                                const float* __restrict__ cw_all,
                                                const float* __restrict__ A_log,
                                                const float* __restrict__ Dp,
                                                const float* __restrict__ hO,
                                                const unsigned short* __restrict__ szTB,
                                                unsigned short* __restrict__ ybuf) {
  __shared__ float BCt[LC][32];
  int z = blockIdx.z;
  int brn = z >> 1, b = z & 1;
  int ch = blockIdx.y;
  int t0 = ch * LC;
  int d = blockIdx.x * 256 + threadIdx.x;
  int tid = threadIdx.x;
  for (int i = tid; i < 640; i += 256) {
    int row = i / 20;
    int c4 = (i % 20) * 4;
    float4 v = *(const float4*)&BC[((size_t)z * 32 + row) * L_SEQ + t0 + c4];
    BCt[c4 + 0][row] = v.x; BCt[c4 + 1][row] = v.y;
    BCt[c4 + 2][row] = v.z; BCt[c4 + 3][row] = v.w;
  }
  float4 w = *(const float4*)&cw_all[((size_t)brn * DI + d) * 4];
  float a2[16];
  bool fastp = true;
#pragma unroll
  for (int g = 0; g < 4; ++g) {
    float4 v = *(const float4*)&A_log[((size_t)brn * DI + d) * DS + g * 4];
    float av0 = __expf(v.x), av1 = __expf(v.y), av2 = __expf(v.z), av3 = __expf(v.w);
    a2[g * 4 + 0] = -av0 * 1.44269504f; a2[g * 4 + 1] = -av1 * 1.44269504f;
    a2[g * 4 + 2] = -av2 * 1.44269504f; a2[g * 4 + 3] = -av3 * 1.44269504f;
    fastp = fastp && fabsf(av0 - (float)(g * 4 + 1)) < 1e-3f
                  && fabsf(av1 - (float)(g * 4 + 2)) < 1e-3f
                  && fabsf(av2 - (float)(g * 4 + 3)) < 1e-3f
                  && fabsf(av3 - (float)(g * 4 + 4)) < 1e-3f;
  }
  float Dv = Dp[(size_t)brn * DI + d];
  const unsigned short* xrow = xTB + (size_t)b * L_SEQ * DI;
  const unsigned short* drow = dT + (size_t)z * L_SEQ * DI;
  const unsigned short* szrow = szTB + (size_t)b * L_SEQ * DI;
  float2v h2[8];
  size_t hbase = (((size_t)z * NCH + ch) * DI + d) * 16;
#pragma unroll
  for (int i = 0; i < 8; ++i) h2[i] = *(const float2v*)&hO[hbase + i * 2];
  int per, dA, dB;
  mt_params(brn, per, dA, dB);
  int p5 = t0 % 5;
  int mt = map_t(brn, t0);
  __syncthreads();
  float xm3 = (t0 >= 3) ? bf2f(xrow[(size_t)map_t(brn, t0 - 3) * DI + d]) : 0.f;
  float xm2 = (t0 >= 2) ? bf2f(xrow[(size_t)map_t(brn, t0 - 2) * DI + d]) : 0.f;
  float xm1 = (t0 >= 1) ? bf2f(xrow[(size_t)map_t(brn, t0 - 1) * DI + d]) : 0.f;
  float xc  = bf2f(xrow[(size_t)mt * DI + d]);
  float del = bf2f(drow[(size_t)t0 * DI + d]);
  float sz  = bf2f(szrow[(size_t)mt * DI + d]);
  for (int t = 0; t < LC; ++t) {
    int p5n = p5 + 1;
    int mtn = (p5n == per) ? mt + dB : mt + dA;
    if (p5n == per) p5n = 0;
    float xn = 0.f, deln = 0.f, szn = 0.f;
    if (t + 1 < LC) {
      xn = bf2f(xrow[(size_t)mtn * DI + d]);
      deln = bf2f(drow[(size_t)(t0 + t + 1) * DI + d]);
      szn = bf2f(szrow[(size_t)mtn * DI + d]);
    }
    float xa = silu_f(fmaf(w.w, xc, fmaf(w.z, xm1, fmaf(w.y, xm2, w.x * xm3))));
    float dtx = del * xa;
    float2v dc2[8];
    if (fastp) {
      pow_ladder2(exp2f(-del * 1.44269504f), dc2);
    } else {
#pragma unroll
      for (int i = 0; i < 8; ++i)
        dc2[i] = (float2v){exp2f(del * a2[2 * i]), exp2f(del * a2[2 * i + 1])};
    }
    const float2v* B2 = (const float2v*)&BCt[t][0];
    const float2v* C2 = (const float2v*)&BCt[t][16];
    float2v dtx2 = {dtx, dtx};
    float2v y2 = {0.f, 0.f};
#pragma unroll
    for (int i = 0; i < 8; ++i) {
      h2[i] = __builtin_elementwise_fma(h2[i], dc2[i], dtx2 * B2[i]);
      y2 = __builtin_elementwise_fma(h2[i], C2[i], y2);
    }
    float y = y2[0] + y2[1] + Dv * xa;
    ybuf[((size_t)b * L_SEQ + mt) * (3 * DI) + (size_t)brn * DI + d] = f2bf(y * sz);
    xm3 = xm2; xm2 = xm1; xm1 = xc; xc = xn; del = deln; sz = szn; mt = mtn; p5 = p5n;
  }
}

extern "C" void kernel_launch(void* const* d_in, const int* in_sizes, int n_in,
                              void* d_out, int out_size, void* d_ws, size_t ws_size,
                              hipStream_t stream) {
  const float* hs        = (const float*)d_in[0];
  const float* in_proj_w = (const float*)d_in[1];
  const float* conv_w    = (const float*)d_in[2];
  const float* x_proj_w  = (const float*)d_in[3];
  const float* dt_proj_w = (const float*)d_in[4];
  const float* dt_bias   = (const float*)d_in[5];
  const float* A_log     = (const float*)d_in[6];
  const float* D_param   = (const float*)d_in[7];
  const float* out_proj_w= (const float*)d_in[8];
  float* out = (float*)d_out;
  float* ws = (float*)d_ws;

  unsigned short* xTB  = (unsigned short*)(ws);             // 12,288,000 sh
  unsigned short* szTB = (unsigned short*)(ws + 6144000);   // 12,288,000 sh
  unsigned short* dtrB = (unsigned short*)(ws + 12288000);  // 1,152,000 sh
  float* BC            = ws + 12864000;                     // 768,000 f
  unsigned short* dT   = (unsigned short*)(ws + 13632000);  // 36,864,000 sh
  float* hO            = ws + 32064000;                     // 7,372,800 f
  float* Sc            = ws + 39436800;                     // 460,800 f
  unsigned short* dpwB = (unsigned short*)(ws + 39897600);  // 221,184 sh
  unsigned short* OWb  = (unsigned short*)(ws + 40008192);  // 1,179,648 sh
  // region R (disjoint lifetimes): {hsB, Wb} -> {xaB} -> {ybuf}
  unsigned short* hsB  = (unsigned short*)(ws + 40598016);  // 6,144,000 sh
  unsigned short* Wb   = hsB + 6144000;                     // 2,359,296 sh
  unsigned short* xaB  = (unsigned short*)(ws + 40598016);  // 36,864,000 sh
  unsigned short* ybuf = (unsigned short*)(ws + 40598016);  // 36,864,000 sh
  unsigned short* xpwB = (unsigned short*)(ws + 59030016);  // 368,640 sh
  // total: 59,214,336 floats = 236.9 MB

  k_cast5<<<5016, 256, 0, stream>>>(hs, hsB, in_proj_w, Wb, out_proj_w, OWb,
                                    dt_proj_w, dpwB, x_proj_w, xpwB);

  k_gemm_bt<DM, DM, 1><<<dim3(63, 24), 256, 0, stream>>>(Wb, hsB, nullptr, xTB, szTB);

  k_conv_all<<<dim3(6, 500, 6), 256, 0, stream>>>(xTB, conv_w, xaB);
  k_xprojm<<<dim3(32, 1, 6), 256, 0, stream>>>(xpwB, xaB, dtrB, BC);
  k_dtg<<<dim3(32, 12, 6), 256, 0, stream>>>(dpwB, dtrB, dt_bias, dT);

  k_scan1c<<<dim3(6, NCH, 6), 256, 0, stream>>>(xTB, dT, BC, conv_w, A_log, hO, Sc);
  k_scan2c<<<576, 256, 0, stream>>>(hO, Sc, A_log);
  k_scan3c<<<dim3(6, NCH, 6), 256, 0, stream>>>(xTB, dT, BC, conv_w, A_log, D_param,
                                                hO, szTB, ybuf);

  k_gemm_bt<3 * DI, DI, 0><<<dim3(63, 6), 256, 0, stream>>>(OWb, ybuf, out, nullptr, nullptr);
}

// Round 8
// 640.220 us; speedup vs baseline: 6.8932x; 1.0362x over previous
//
#include <hip/hip_runtime.h>
#include <math.h>

#define L_SEQ 4000
#define DM 768
#define DI 1536
#define DS 16
#define DTRK 48
#define NCH 50
#define LC 80
#define NBL 8000

typedef __attribute__((ext_vector_type(8))) short short8;
typedef __attribute__((ext_vector_type(8))) unsigned short ushort8;
typedef __attribute__((ext_vector_type(4))) unsigned short ushort4v;
typedef __attribute__((ext_vector_type(4))) float floatx4;
typedef __attribute__((ext_vector_type(2))) float float2v;

__device__ __forceinline__ float silu_f(float x) { return x / (1.f + __expf(-x)); }
__device__ __forceinline__ float softplus_f(float x) {
  return fmaxf(x, 0.f) + log1pf(__expf(-fabsf(x)));
}
__device__ __forceinline__ int map_t(int branch, int t) {
  if (branch == 0) return t;
  if (branch == 1) return L_SEQ - 1 - t;
  return (t % 5) * 800 + t / 5;
}
__device__ __forceinline__ unsigned short f2bf(float f) {
  unsigned int u = __float_as_uint(f);
  u = (u + 0x7fffu + ((u >> 16) & 1u)) >> 16;
  return (unsigned short)u;
}
__device__ __forceinline__ float bf2f(unsigned short u) {
  return __uint_as_float(((unsigned int)u) << 16);
}
__device__ __forceinline__ void glds16(const void* g, void* l) {
  __builtin_amdgcn_global_load_lds((const __attribute__((address_space(1))) void*)g,
                                   (__attribute__((address_space(3))) void*)l, 16, 0, 0);
}
// packed power ladder: dc2[i] = {E^(2i+1), E^(2i+2)} for i=0..7
__device__ __forceinline__ void pow_ladder2(float E1, float2v* dc2) {
  float E2 = E1 * E1;
  float2v Ev = {E2, E2};
  dc2[0] = (float2v){E1, E2};
#pragma unroll
  for (int i = 1; i < 8; ++i) dc2[i] = dc2[i - 1] * Ev;
}

// ---------------- merged cast fp32 -> bf16 for all 5 weight/input arrays ----------------
__device__ __forceinline__ void cast_seg(const float* __restrict__ src,
                                         unsigned short* __restrict__ dst,
                                         int blk, int n) {
  int i = (blk * 256 + (int)threadIdx.x) * 8;
  if (i >= n) return;
  float4 v0 = *(const float4*)&src[i];
  float4 v1 = *(const float4*)&src[i + 4];
  ushort8 r;
  r[0] = f2bf(v0.x); r[1] = f2bf(v0.y); r[2] = f2bf(v0.z); r[3] = f2bf(v0.w);
  r[4] = f2bf(v1.x); r[5] = f2bf(v1.y); r[6] = f2bf(v1.z); r[7] = f2bf(v1.w);
  *(ushort8*)&dst[i] = r;
}
__global__ __launch_bounds__(256) void k_cast5(const float* s0, unsigned short* d0,
                                               const float* s1, unsigned short* d1,
                                               const float* s2, unsigned short* d2,
                                               const float* s3, unsigned short* d3,
                                               const float* s4, unsigned short* d4) {
  int blk = blockIdx.x;
  if (blk < 3000)      cast_seg(s0, d0, blk,        6144000);
  else if (blk < 4152) cast_seg(s1, d1, blk - 3000, 2359296);
  else if (blk < 4728) cast_seg(s2, d2, blk - 4152, 1179648);
  else if (blk < 4836) cast_seg(s3, d3, blk - 4728, 221184);
  else                 cast_seg(s4, d4, blk - 4836, 368640);
}

// ---------------- MFMA GEMM (bt): C[m][n] = sum_k A[m][(k%KA)]*B[n][k] ----
// MODE 0 (out_proj): grid is (m-tiles, n-tiles) -> m fastest for B-tile L2 reuse.
// MODE 1 (in_proj):  grid is (n-tiles, m-tiles).
template <int KDIM, int KA, int MODE>
__global__ __launch_bounds__(256) void k_gemm_bt(const unsigned short* __restrict__ A,
                                                 const unsigned short* __restrict__ B,
                                                 float* __restrict__ O0f,
                                                 unsigned short* __restrict__ O0h,
                                                 unsigned short* __restrict__ O1h) {
  __shared__ unsigned short As[128 * 32];
  __shared__ unsigned short Bs[128 * 32];
  int m0 = (MODE == 0 ? blockIdx.x : blockIdx.y) * 128;
  int n0 = (MODE == 0 ? blockIdx.y : blockIdx.x) * 128;
  int tid = threadIdx.x;
  int lane = tid & 63;
  int wm = (tid >> 6) & 1;
  int wn = tid >> 7;
  int srow = tid >> 2;
  int skof = (tid & 3) * 8;
  int brow0 = n0 + srow;       if (brow0 >= NBL) brow0 = NBL - 1;
  int brow1 = n0 + srow + 64;  if (brow1 >= NBL) brow1 = NBL - 1;
  floatx4 zero = {0.f, 0.f, 0.f, 0.f};
  floatx4 acc[4][4];
#pragma unroll
  for (int i = 0; i < 4; ++i)
#pragma unroll
    for (int j = 0; j < 4; ++j) acc[i][j] = zero;
  int ar = wm * 64 + (lane & 15);
  int br = wn * 64 + (lane & 15);
  int kq = (lane >> 4) * 8;
  for (int k0 = 0; k0 < KDIM; k0 += 32) {
    int ka = (k0 % KA);
    glds16(&A[(size_t)(m0 + srow) * KA + ka + skof],      &As[tid * 8]);
    glds16(&A[(size_t)(m0 + srow + 64) * KA + ka + skof], &As[tid * 8 + 2048]);
    glds16(&B[(size_t)brow0 * KDIM + k0 + skof], &Bs[tid * 8]);
    glds16(&B[(size_t)brow1 * KDIM + k0 + skof], &Bs[tid * 8 + 2048]);
    __syncthreads();
    short8 a[4], b[4];
#pragma unroll
    for (int i = 0; i < 4; ++i) a[i] = *(const short8*)&As[(ar + i * 16) * 32 + kq];
#pragma unroll
    for (int i = 0; i < 4; ++i) b[i] = *(const short8*)&Bs[(br + i * 16) * 32 + kq];
#pragma unroll
    for (int mt = 0; mt < 4; ++mt)
#pragma unroll
      for (int nt = 0; nt < 4; ++nt)
        acc[mt][nt] = __builtin_amdgcn_mfma_f32_16x16x32_bf16(a[mt], b[nt], acc[mt][nt], 0, 0, 0);
    __syncthreads();
  }
  int mq = m0 + wm * 64 + ((lane >> 4) << 2);
  int nq = n0 + wn * 64 + (lane & 15);
#pragma unroll
  for (int nt = 0; nt < 4; ++nt) {
    int n = nq + nt * 16;
    if (n >= NBL) continue;
#pragma unroll
    for (int mt = 0; mt < 4; ++mt) {
      int m = mq + mt * 16;
      floatx4 v = acc[mt][nt];
      if (MODE == 0) {
        *(floatx4*)&O0f[(size_t)n * DM + m] = v;
      } else {
        if (m < DI) {
          ushort4v r;
          r[0] = f2bf(v[0]); r[1] = f2bf(v[1]); r[2] = f2bf(v[2]); r[3] = f2bf(v[3]);
          *(ushort4v*)&O0h[(size_t)n * DI + m] = r;
        } else {
          ushort4v r;
          r[0] = f2bf(silu_f(v[0])); r[1] = f2bf(silu_f(v[1]));
          r[2] = f2bf(silu_f(v[2])); r[3] = f2bf(silu_f(v[3]));
          *(ushort4v*)&O1h[(size_t)n * DI + m - DI] = r;
        }
      }
    }
  }
}

// ---------------- conv+silu materialization: xTB[b][l][d] -> xaB[z][t][d] bf16 ----------------
__global__ __launch_bounds__(256) void k_conv_all(const unsigned short* __restrict__ xTB,
                                                  const float* __restrict__ cw_all,
                                                  unsigned short* __restrict__ xaB) {
  int z = blockIdx.z;
  int brn = z >> 1, b = z & 1;
  int d = blockIdx.x * 256 + threadIdx.x;
  int t0 = blockIdx.y * 8;
  const unsigned short* xrow = xTB + (size_t)b * L_SEQ * DI;
  float4 w = *(const float4*)&cw_all[((size_t)brn * DI + d) * 4];
  float xm3 = (t0 >= 3) ? bf2f(xrow[(size_t)map_t(brn, t0 - 3) * DI + d]) : 0.f;
  float xm2 = (t0 >= 2) ? bf2f(xrow[(size_t)map_t(brn, t0 - 2) * DI + d]) : 0.f;
  float xm1 = (t0 >= 1) ? bf2f(xrow[(size_t)map_t(brn, t0 - 1) * DI + d]) : 0.f;
#pragma unroll
  for (int i = 0; i < 8; ++i) {
    int t = t0 + i;
    float xc = bf2f(xrow[(size_t)map_t(brn, t) * DI + d]);
    float xa = silu_f(fmaf(w.w, xc, fmaf(w.z, xm1, fmaf(w.y, xm2, w.x * xm3))));
    xaB[((size_t)z * L_SEQ + t) * DI + d] = f2bf(xa);
    xm3 = xm2; xm2 = xm1; xm1 = xc;
  }
}

// ---------------- xproj MFMA: C[j][t] = sum_d xpw[j][d]*xa[z][t][d] ----------------
__global__ __launch_bounds__(256) void k_xprojm(const unsigned short* __restrict__ xpwB,
                                                const unsigned short* __restrict__ xaB,
                                                unsigned short* __restrict__ dtrB,
                                                float* __restrict__ BC) {
  __shared__ unsigned short As[128 * 32];
  __shared__ unsigned short Bs[128 * 32];
  int z = blockIdx.z;
  int brn = z >> 1;
  int n0 = blockIdx.x * 128;
  int tid = threadIdx.x;
  int lane = tid & 63;
  int wm = (tid >> 6) & 1;
  int wn = tid >> 7;
  int srow = tid >> 2;
  int skof = (tid & 3) * 8;
  int arow0 = srow;       if (arow0 > 79) arow0 = 79;
  int arow1 = srow + 64;  if (arow1 > 79) arow1 = 79;
  int brow0 = n0 + srow;       if (brow0 >= L_SEQ) brow0 = L_SEQ - 1;
  int brow1 = n0 + srow + 64;  if (brow1 >= L_SEQ) brow1 = L_SEQ - 1;
  const unsigned short* A = xpwB + (size_t)brn * 80 * DI;
  const unsigned short* Bm = xaB + (size_t)z * L_SEQ * DI;
  floatx4 zero = {0.f, 0.f, 0.f, 0.f};
  floatx4 acc[4][4];
#pragma unroll
  for (int i = 0; i < 4; ++i)
#pragma unroll
    for (int j = 0; j < 4; ++j) acc[i][j] = zero;
  int ar = wm * 64 + (lane & 15);
  int br = wn * 64 + (lane & 15);
  int kq = (lane >> 4) * 8;
  for (int k0 = 0; k0 < DI; k0 += 32) {
    glds16(&A[(size_t)arow0 * DI + k0 + skof], &As[tid * 8]);
    glds16(&A[(size_t)arow1 * DI + k0 + skof], &As[tid * 8 + 2048]);
    glds16(&Bm[(size_t)brow0 * DI + k0 + skof], &Bs[tid * 8]);
    glds16(&Bm[(size_t)brow1 * DI + k0 + skof], &Bs[tid * 8 + 2048]);
    __syncthreads();
    short8 a[4], b[4];
#pragma unroll
    for (int i = 0; i < 4; ++i) a[i] = *(const short8*)&As[(ar + i * 16) * 32 + kq];
#pragma unroll
    for (int i = 0; i < 4; ++i) b[i] = *(const short8*)&Bs[(br + i * 16) * 32 + kq];
#pragma unroll
    for (int mt = 0; mt < 4; ++mt)
#pragma unroll
      for (int nt = 0; nt < 4; ++nt)
        acc[mt][nt] = __builtin_amdgcn_mfma_f32_16x16x32_bf16(a[mt], b[nt], acc[mt][nt], 0, 0, 0);
    __syncthreads();
  }
  int mq = wm * 64 + ((lane >> 4) << 2);
  int nq = n0 + wn * 64 + (lane & 15);
#pragma unroll
  for (int nt = 0; nt < 4; ++nt) {
    int t = nq + nt * 16;
    if (t >= L_SEQ) continue;
#pragma unroll
    for (int mt = 0; mt < 4; ++mt) {
      int j = mq + mt * 16;
      if (j >= 80) continue;
      floatx4 v = acc[mt][nt];
      if (j < 48) {
        ushort4v r;
        r[0] = f2bf(v[0]); r[1] = f2bf(v[1]); r[2] = f2bf(v[2]); r[3] = f2bf(v[3]);
        *(ushort4v*)&dtrB[((size_t)z * L_SEQ + t) * DTRK + j] = r;
      } else {
#pragma unroll
        for (int r = 0; r < 4; ++r)
          BC[((size_t)z * 32 + (j + r - 48)) * L_SEQ + t] = v[r];
      }
    }
  }
}

// ---------------- delta GEMM (MFMA, K=48 padded to 64) + softplus -> bf16 [z][t][d]
__global__ __launch_bounds__(256) void k_dtg(const unsigned short* __restrict__ dpwB,
                                             const unsigned short* __restrict__ dtrB,
                                             const float* __restrict__ dbias,
                                             unsigned short* __restrict__ dT) {
  __shared__ unsigned short As[128 * 64];
  __shared__ unsigned short Bs[128 * 64];
  int z = blockIdx.z;
  int brn = z >> 1;
  int m0 = blockIdx.y * 128;
  int n0 = blockIdx.x * 128;
  int tid = threadIdx.x;
  int lane = tid & 63;
  int wm = (tid >> 6) & 1;
  int wn = tid >> 7;
  {
    int zr = tid >> 1, zc = 48 + (tid & 1) * 8;
    ushort8 zz = {0, 0, 0, 0, 0, 0, 0, 0};
    *(ushort8*)&As[zr * 64 + zc] = zz;
    *(ushort8*)&Bs[zr * 64 + zc] = zz;
  }
  {
    int row = tid >> 1;
    int p0 = (tid & 1) * 3;
    const unsigned short* Ag = dpwB + (size_t)brn * DI * DTRK + (size_t)(m0 + row) * DTRK;
    int bro = n0 + row; if (bro > L_SEQ - 1) bro = L_SEQ - 1;
    const unsigned short* Bg = dtrB + ((size_t)z * L_SEQ + bro) * DTRK;
#pragma unroll
    for (int i = 0; i < 3; ++i) {
      int off = (p0 + i) * 8;
      *(ushort8*)&As[row * 64 + off] = *(const ushort8*)&Ag[off];
      *(ushort8*)&Bs[row * 64 + off] = *(const ushort8*)&Bg[off];
    }
  }
  __syncthreads();
  int ar = wm * 64 + (lane & 15);
  int brr = wn * 64 + (lane & 15);
  int kq = (lane >> 4) * 8;
  floatx4 zero = {0.f, 0.f, 0.f, 0.f};
  floatx4 acc[4][4];
#pragma unroll
  for (int i = 0; i < 4; ++i)
#pragma unroll
    for (int j = 0; j < 4; ++j) acc[i][j] = zero;
#pragma unroll
  for (int kk = 0; kk < 2; ++kk) {
    short8 a[4], b[4];
#pragma unroll
    for (int i = 0; i < 4; ++i) a[i] = *(const short8*)&As[(ar + i * 16) * 64 + kk * 32 + kq];
#pragma unroll
    for (int i = 0; i < 4; ++i) b[i] = *(const short8*)&Bs[(brr + i * 16) * 64 + kk * 32 + kq];
#pragma unroll
    for (int mt = 0; mt < 4; ++mt)
#pragma unroll
      for (int nt = 0; nt < 4; ++nt)
        acc[mt][nt] = __builtin_amdgcn_mfma_f32_16x16x32_bf16(a[mt], b[nt], acc[mt][nt], 0, 0, 0);
  }
  int mq = m0 + wm * 64 + ((lane >> 4) << 2);
  int nq = n0 + wn * 64 + (lane & 15);
#pragma unroll
  for (int nt = 0; nt < 4; ++nt) {
    int n = nq + nt * 16;
    if (n >= L_SEQ) continue;
#pragma unroll
    for (int mt = 0; mt < 4; ++mt) {
      int m = mq + mt * 16;
      float4 bi = *(const float4*)&dbias[(size_t)brn * DI + m];
      floatx4 v = acc[mt][nt];
      ushort4v r;
      r[0] = f2bf(softplus_f(v[0] + bi.x));
      r[1] = f2bf(softplus_f(v[1] + bi.y));
      r[2] = f2bf(softplus_f(v[2] + bi.z));
      r[3] = f2bf(softplus_f(v[3] + bi.w));
      *(ushort4v*)&dT[((size_t)z * L_SEQ + n) * DI + m] = r;
    }
  }
}

// per-branch incremental time-map parameters
__device__ __forceinline__ void mt_params(int brn, int& per, int& dA, int& dB) {
  if (brn == 0) { per = 1 << 30; dA = 1; dB = 1; }
  else if (brn == 1) { per = 1 << 30; dA = -1; dB = -1; }
  else { per = 5; dA = 800; dB = -3199; }
}

// ---------------- scan phase 1: per-chunk local state + delta-sum (reads xaB) ----------------
__global__ __launch_bounds__(256) void k_scan1c(const unsigned short* __restrict__ xaB,
                                                const unsigned short* __restrict__ dT,
                                                const float* __restrict__ BC,
                                                const float* __restrict__ A_log,
                                                float* __restrict__ hO,
                                                float* __restrict__ Sc) {
  __shared__ float BtS[LC][16];
  int z = blockIdx.z;
  int brn = z >> 1;
  int ch = blockIdx.y;
  int t0 = ch * LC;
  int d = blockIdx.x * 256 + threadIdx.x;
  int tid = threadIdx.x;
  for (int i = tid; i < 320; i += 256) {
    int row = i / 20;
    int c4 = (i % 20) * 4;
    float4 v = *(const float4*)&BC[((size_t)z * 32 + row) * L_SEQ + t0 + c4];
    BtS[c4 + 0][row] = v.x; BtS[c4 + 1][row] = v.y;
    BtS[c4 + 2][row] = v.z; BtS[c4 + 3][row] = v.w;
  }
  float a2[16];
  bool fastp = true;
#pragma unroll
  for (int g = 0; g < 4; ++g) {
    float4 v = *(const float4*)&A_log[((size_t)brn * DI + d) * DS + g * 4];
    float av0 = __expf(v.x), av1 = __expf(v.y), av2 = __expf(v.z), av3 = __expf(v.w);
    a2[g * 4 + 0] = -av0 * 1.44269504f; a2[g * 4 + 1] = -av1 * 1.44269504f;
    a2[g * 4 + 2] = -av2 * 1.44269504f; a2[g * 4 + 3] = -av3 * 1.44269504f;
    fastp = fastp && fabsf(av0 - (float)(g * 4 + 1)) < 1e-3f
                  && fabsf(av1 - (float)(g * 4 + 2)) < 1e-3f
                  && fabsf(av2 - (float)(g * 4 + 3)) < 1e-3f
                  && fabsf(av3 - (float)(g * 4 + 4)) < 1e-3f;
  }
  const unsigned short* xarow = xaB + (size_t)z * L_SEQ * DI;
  const unsigned short* drow = dT + (size_t)z * L_SEQ * DI;
  float2v h2[8];
#pragma unroll
  for (int i = 0; i < 8; ++i) h2[i] = (float2v){0.f, 0.f};
  float S = 0.f;
  __syncthreads();
  float xa  = bf2f(xarow[(size_t)t0 * DI + d]);
  float del = bf2f(drow[(size_t)t0 * DI + d]);
  for (int t = 0; t < LC; ++t) {
    float xan = 0.f, deln = 0.f;
    if (t + 1 < LC) {
      size_t off = (size_t)(t0 + t + 1) * DI + d;
      xan = bf2f(xarow[off]);
      deln = bf2f(drow[off]);
    }
    float dtx = del * xa;
    S += del;
    float2v dc2[8];
    if (fastp) {
      pow_ladder2(exp2f(-del * 1.44269504f), dc2);
    } else {
#pragma unroll
      for (int i = 0; i < 8; ++i)
        dc2[i] = (float2v){exp2f(del * a2[2 * i]), exp2f(del * a2[2 * i + 1])};
    }
    const float2v* B2 = (const float2v*)&BtS[t][0];
    float2v dtx2 = {dtx, dtx};
#pragma unroll
    for (int i = 0; i < 8; ++i)
      h2[i] = __builtin_elementwise_fma(h2[i], dc2[i], dtx2 * B2[i]);
    xa = xan; del = deln;
  }
  size_t base = (((size_t)z * NCH + ch) * DI + d) * 16;
#pragma unroll
  for (int i = 0; i < 8; ++i) *(float2v*)&hO[base + i * 2] = h2[i];
  Sc[((size_t)z * NCH + ch) * DI + d] = S;
}

// ---------------- scan phase 2: sequential combine over chunks ----------------
__global__ __launch_bounds__(256) void k_scan2c(float* __restrict__ hO,
                                                const float* __restrict__ Sc,
                                                const float* __restrict__ A_log) {
  int idx = blockIdx.x * 256 + threadIdx.x;
  int z = idx / (DI * 16);
  int rem = idx % (DI * 16);
  int brn = z >> 1;
  float a2 = -__expf(A_log[(size_t)brn * DI * DS + rem]) * 1.44269504f;
  float H = 0.f;
  for (int c = 0; c < NCH; ++c) {
    size_t p = ((size_t)z * NCH + c) * (DI * 16) + rem;
    float th = hO[p];
    float P = exp2f(Sc[((size_t)z * NCH + c) * DI + (rem >> 4)] * a2);
    hO[p] = H;
    H = fmaf(P, H, th);
  }
}

// ---------------- scan phase 3: re-run chunk, gate, write ybuf (conv recompute) ----------------
__global__ __launch_bounds__(256) void k_scan3c(const unsigned short* __restrict__ xTB,
                                                const unsigned short* __restrict__ dT,
                                                const float* __restrict__ BC,
                                                const float* __restrict__ cw_all,
                                                const float* __restrict__ A_log,
                                                const float* __restrict__ Dp,
                                                const float* __restrict__ hO,
                                                const unsigned short* __restrict__ szTB,
                                                unsigned short* __restrict__ ybuf) {
  __shared__ float BCt[LC][32];
  int z = blockIdx.z;
  int brn = z >> 1, b = z & 1;
  int ch = blockIdx.y;
  int t0 = ch * LC;
  int d = blockIdx.x * 256 + threadIdx.x;
  int tid = threadIdx.x;
  for (int i = tid; i < 640; i += 256) {
    int row = i / 20;
    int c4 = (i % 20) * 4;
    float4 v = *(const float4*)&BC[((size_t)z * 32 + row) * L_SEQ + t0 + c4];
    BCt[c4 + 0][row] = v.x; BCt[c4 + 1][row] = v.y;
    BCt[c4 + 2][row] = v.z; BCt[c4 + 3][row] = v.w;
  }
  float4 w = *(const float4*)&cw_all[((size_t)brn * DI + d) * 4];
  float a2[16];
  bool fastp = true;
#pragma unroll
  for (int g = 0; g < 4; ++g) {
    float4 v = *(const float4*)&A_log[((size_t)brn * DI + d) * DS + g * 4];
    float av0 = __expf(v.x), av1 = __expf(v.y), av2 = __expf(v.z), av3 = __expf(v.w);
    a2[g * 4 + 0] = -av0 * 1.44269504f; a2[g * 4 + 1] = -av1 * 1.44269504f;
    a2[g * 4 + 2] = -av2 * 1.44269504f; a2[g * 4 + 3] = -av3 * 1.44269504f;
    fastp = fastp && fabsf(av0 - (float)(g * 4 + 1)) < 1e-3f
                  && fabsf(av1 - (float)(g * 4 + 2)) < 1e-3f
                  && fabsf(av2 - (float)(g * 4 + 3)) < 1e-3f
                  && fabsf(av3 - (float)(g * 4 + 4)) < 1e-3f;
  }
  float Dv = Dp[(size_t)brn * DI + d];
  const unsigned short* xrow = xTB + (size_t)b * L_SEQ * DI;
  const unsigned short* drow = dT + (size_t)z * L_SEQ * DI;
  const unsigned short* szrow = szTB + (size_t)b * L_SEQ * DI;
  float2v h2[8];
  size_t hbase = (((size_t)z * NCH + ch) * DI + d) * 16;
#pragma unroll
  for (int i = 0; i < 8; ++i) h2[i] = *(const float2v*)&hO[hbase + i * 2];
  int per, dA, dB;
  mt_params(brn, per, dA, dB);
  int p5 = t0 % 5;
  int mt = map_t(brn, t0);
  __syncthreads();
  float xm3 = (t0 >= 3) ? bf2f(xrow[(size_t)map_t(brn, t0 - 3) * DI + d]) : 0.f;
  float xm2 = (t0 >= 2) ? bf2f(xrow[(size_t)map_t(brn, t0 - 2) * DI + d]) : 0.f;
  float xm1 = (t0 >= 1) ? bf2f(xrow[(size_t)map_t(brn, t0 - 1) * DI + d]) : 0.f;
  float xc  = bf2f(xrow[(size_t)mt * DI + d]);
  float del = bf2f(drow[(size_t)t0 * DI + d]);
  float sz  = bf2f(szrow[(size_t)mt * DI + d]);
  for (int t = 0; t < LC; ++t) {
    int p5n = p5 + 1;
    int mtn = (p5n == per) ? mt + dB : mt + dA;
    if (p5n == per) p5n = 0;
    float xn = 0.f, deln = 0.f, szn = 0.f;
    if (t + 1 < LC) {
      xn = bf2f(xrow[(size_t)mtn * DI + d]);
      deln = bf2f(drow[(size_t)(t0 + t + 1) * DI + d]);
      szn = bf2f(szrow[(size_t)mtn * DI + d]);
    }
    float xa = silu_f(fmaf(w.w, xc, fmaf(w.z, xm1, fmaf(w.y, xm2, w.x * xm3))));
    float dtx = del * xa;
    float2v dc2[8];
    if (fastp) {
      pow_ladder2(exp2f(-del * 1.44269504f), dc2);
    } else {
#pragma unroll
      for (int i = 0; i < 8; ++i)
        dc2[i] = (float2v){exp2f(del * a2[2 * i]), exp2f(del * a2[2 * i + 1])};
    }
    const float2v* B2 = (const float2v*)&BCt[t][0];
    const float2v* C2 = (const float2v*)&BCt[t][16];
    float2v dtx2 = {dtx, dtx};
    float2v y2 = {0.f, 0.f};
#pragma unroll
    for (int i = 0; i < 8; ++i) {
      h2[i] = __builtin_elementwise_fma(h2[i], dc2[i], dtx2 * B2[i]);
      y2 = __builtin_elementwise_fma(h2[i], C2[i], y2);
    }
    float y = y2[0] + y2[1] + Dv * xa;
    ybuf[((size_t)b * L_SEQ + mt) * (3 * DI) + (size_t)brn * DI + d] = f2bf(y * sz);
    xm3 = xm2; xm2 = xm1; xm1 = xc; xc = xn; del = deln; sz = szn; mt = mtn; p5 = p5n;
  }
}

extern "C" void kernel_launch(void* const* d_in, const int* in_sizes, int n_in,
                              void* d_out, int out_size, void* d_ws, size_t ws_size,
                              hipStream_t stream) {
  const float* hs        = (const float*)d_in[0];
  const float* in_proj_w = (const float*)d_in[1];
  const float* conv_w    = (const float*)d_in[2];
  const float* x_proj_w  = (const float*)d_in[3];
  const float* dt_proj_w = (const float*)d_in[4];
  const float* dt_bias   = (const float*)d_in[5];
  const float* A_log     = (const float*)d_in[6];
  const float* D_param   = (const float*)d_in[7];
  const float* out_proj_w= (const float*)d_in[8];
  float* out = (float*)d_out;
  float* ws = (float*)d_ws;

  unsigned short* xTB  = (unsigned short*)(ws);             // 12,288,000 sh
  unsigned short* szTB = (unsigned short*)(ws + 6144000);   // 12,288,000 sh
  unsigned short* dtrB = (unsigned short*)(ws + 12288000);  // 1,152,000 sh
  float* BC            = ws + 12864000;                     // 768,000 f
  unsigned short* dT   = (unsigned short*)(ws + 13632000);  // 36,864,000 sh
  float* hO            = ws + 32064000;                     // 7,372,800 f
  float* Sc            = ws + 39436800;                     // 460,800 f
  unsigned short* dpwB = (unsigned short*)(ws + 39897600);  // 221,184 sh
  unsigned short* OWb  = (unsigned short*)(ws + 40008192);  // 1,179,648 sh
  // region R (disjoint lifetimes): {hsB, Wb} -> {xaB} -> {ybuf}
  unsigned short* hsB  = (unsigned short*)(ws + 40598016);  // 6,144,000 sh
  unsigned short* Wb   = hsB + 6144000;                     // 2,359,296 sh
  unsigned short* xaB  = (unsigned short*)(ws + 40598016);  // 36,864,000 sh
  unsigned short* ybuf = (unsigned short*)(ws + 40598016);  // 36,864,000 sh
  unsigned short* xpwB = (unsigned short*)(ws + 59030016);  // 368,640 sh
  // total: 59,214,336 floats = 236.9 MB

  k_cast5<<<5016, 256, 0, stream>>>(hs, hsB, in_proj_w, Wb, out_proj_w, OWb,
                                    dt_proj_w, dpwB, x_proj_w, xpwB);

  k_gemm_bt<DM, DM, 1><<<dim3(63, 24), 256, 0, stream>>>(Wb, hsB, nullptr, xTB, szTB);

  k_conv_all<<<dim3(6, 500, 6), 256, 0, stream>>>(xTB, conv_w, xaB);
  k_xprojm<<<dim3(32, 1, 6), 256, 0, stream>>>(xpwB, xaB, dtrB, BC);
  k_dtg<<<dim3(32, 12, 6), 256, 0, stream>>>(dpwB, dtrB, dt_bias, dT);

  // scan1c reads xaB (materialized conv) — must complete before scan3c overwrites
  // the aliased region as ybuf. scan3c recomputes conv from xTB.
  k_scan1c<<<dim3(6, NCH, 6), 256, 0, stream>>>(xaB, dT, BC, A_log, hO, Sc);
  k_scan2c<<<576, 256, 0, stream>>>(hO, Sc, A_log);
  k_scan3c<<<dim3(6, NCH, 6), 256, 0, stream>>>(xTB, dT, BC, conv_w, A_log, D_param,
                                                hO, szTB, ybuf);

  // out_proj: grid (m-tiles, n-tiles) — m fastest so the 6 m-tile blocks sharing a
  // ybuf B-tile are dispatched adjacently (L2/L3-resident re-use).
  k_gemm_bt<3 * DI, DI, 0><<<dim3(6, 63), 256, 0, stream>>>(OWb, ybuf, out, nullptr, nullptr);
}

// Round 9
// 638.512 us; speedup vs baseline: 6.9117x; 1.0027x over previous
//
#include <hip/hip_runtime.h>
#include <math.h>

#define L_SEQ 4000
#define DM 768
#define DI 1536
#define DS 16
#define DTRK 48
#define NCH 50
#define LC 80
#define NBL 8000

typedef __attribute__((ext_vector_type(8))) short short8;
typedef __attribute__((ext_vector_type(8))) unsigned short ushort8;
typedef __attribute__((ext_vector_type(4))) unsigned short ushort4v;
typedef __attribute__((ext_vector_type(4))) float floatx4;
typedef __attribute__((ext_vector_type(2))) float float2v;

__device__ __forceinline__ float silu_f(float x) { return x / (1.f + __expf(-x)); }
__device__ __forceinline__ float softplus_f(float x) {
  return fmaxf(x, 0.f) + log1pf(__expf(-fabsf(x)));
}
__device__ __forceinline__ int map_t(int branch, int t) {
  if (branch == 0) return t;
  if (branch == 1) return L_SEQ - 1 - t;
  return (t % 5) * 800 + t / 5;
}
__device__ __forceinline__ unsigned short f2bf(float f) {
  unsigned int u = __float_as_uint(f);
  u = (u + 0x7fffu + ((u >> 16) & 1u)) >> 16;
  return (unsigned short)u;
}
__device__ __forceinline__ float bf2f(unsigned short u) {
  return __uint_as_float(((unsigned int)u) << 16);
}
__device__ __forceinline__ void glds16(const void* g, void* l) {
  __builtin_amdgcn_global_load_lds((const __attribute__((address_space(1))) void*)g,
                                   (__attribute__((address_space(3))) void*)l, 16, 0, 0);
}
// packed power ladder: dc2[i] = {E^(2i+1), E^(2i+2)} for i=0..7
__device__ __forceinline__ void pow_ladder2(float E1, float2v* dc2) {
  float E2 = E1 * E1;
  float2v Ev = {E2, E2};
  dc2[0] = (float2v){E1, E2};
#pragma unroll
  for (int i = 1; i < 8; ++i) dc2[i] = dc2[i - 1] * Ev;
}

// ---------------- merged cast fp32 -> bf16 for all 5 weight/input arrays ----------------
__device__ __forceinline__ void cast_seg(const float* __restrict__ src,
                                         unsigned short* __restrict__ dst,
                                         int blk, int n) {
  int i = (blk * 256 + (int)threadIdx.x) * 8;
  if (i >= n) return;
  float4 v0 = *(const float4*)&src[i];
  float4 v1 = *(const float4*)&src[i + 4];
  ushort8 r;
  r[0] = f2bf(v0.x); r[1] = f2bf(v0.y); r[2] = f2bf(v0.z); r[3] = f2bf(v0.w);
  r[4] = f2bf(v1.x); r[5] = f2bf(v1.y); r[6] = f2bf(v1.z); r[7] = f2bf(v1.w);
  *(ushort8*)&dst[i] = r;
}
__global__ __launch_bounds__(256) void k_cast5(const float* s0, unsigned short* d0,
                                               const float* s1, unsigned short* d1,
                                               const float* s2, unsigned short* d2,
                                               const float* s3, unsigned short* d3,
                                               const float* s4, unsigned short* d4) {
  int blk = blockIdx.x;
  if (blk < 3000)      cast_seg(s0, d0, blk,        6144000);
  else if (blk < 4152) cast_seg(s1, d1, blk - 3000, 2359296);
  else if (blk < 4728) cast_seg(s2, d2, blk - 4152, 1179648);
  else if (blk < 4836) cast_seg(s3, d3, blk - 4728, 221184);
  else                 cast_seg(s4, d4, blk - 4836, 368640);
}

// ---------------- MFMA GEMM (bt): C[m][n] = sum_k A[m][(k%KA)]*B[n][k] ----
template <int KDIM, int KA, int MODE>
__global__ __launch_bounds__(256) void k_gemm_bt(const unsigned short* __restrict__ A,
                                                 const unsigned short* __restrict__ B,
                                                 float* __restrict__ O0f,
                                                 unsigned short* __restrict__ O0h,
                                                 unsigned short* __restrict__ O1h) {
  __shared__ unsigned short As[128 * 32];
  __shared__ unsigned short Bs[128 * 32];
  int m0 = (MODE == 0 ? blockIdx.x : blockIdx.y) * 128;
  int n0 = (MODE == 0 ? blockIdx.y : blockIdx.x) * 128;
  int tid = threadIdx.x;
  int lane = tid & 63;
  int wm = (tid >> 6) & 1;
  int wn = tid >> 7;
  int srow = tid >> 2;
  int skof = (tid & 3) * 8;
  int brow0 = n0 + srow;       if (brow0 >= NBL) brow0 = NBL - 1;
  int brow1 = n0 + srow + 64;  if (brow1 >= NBL) brow1 = NBL - 1;
  floatx4 zero = {0.f, 0.f, 0.f, 0.f};
  floatx4 acc[4][4];
#pragma unroll
  for (int i = 0; i < 4; ++i)
#pragma unroll
    for (int j = 0; j < 4; ++j) acc[i][j] = zero;
  int ar = wm * 64 + (lane & 15);
  int br = wn * 64 + (lane & 15);
  int kq = (lane >> 4) * 8;
  for (int k0 = 0; k0 < KDIM; k0 += 32) {
    int ka = (k0 % KA);
    glds16(&A[(size_t)(m0 + srow) * KA + ka + skof],      &As[tid * 8]);
    glds16(&A[(size_t)(m0 + srow + 64) * KA + ka + skof], &As[tid * 8 + 2048]);
    glds16(&B[(size_t)brow0 * KDIM + k0 + skof], &Bs[tid * 8]);
    glds16(&B[(size_t)brow1 * KDIM + k0 + skof], &Bs[tid * 8 + 2048]);
    __syncthreads();
    short8 a[4], b[4];
#pragma unroll
    for (int i = 0; i < 4; ++i) a[i] = *(const short8*)&As[(ar + i * 16) * 32 + kq];
#pragma unroll
    for (int i = 0; i < 4; ++i) b[i] = *(const short8*)&Bs[(br + i * 16) * 32 + kq];
#pragma unroll
    for (int mt = 0; mt < 4; ++mt)
#pragma unroll
      for (int nt = 0; nt < 4; ++nt)
        acc[mt][nt] = __builtin_amdgcn_mfma_f32_16x16x32_bf16(a[mt], b[nt], acc[mt][nt], 0, 0, 0);
    __syncthreads();
  }
  int mq = m0 + wm * 64 + ((lane >> 4) << 2);
  int nq = n0 + wn * 64 + (lane & 15);
#pragma unroll
  for (int nt = 0; nt < 4; ++nt) {
    int n = nq + nt * 16;
    if (n >= NBL) continue;
#pragma unroll
    for (int mt = 0; mt < 4; ++mt) {
      int m = mq + mt * 16;
      floatx4 v = acc[mt][nt];
      if (MODE == 0) {
        *(floatx4*)&O0f[(size_t)n * DM + m] = v;
      } else {
        if (m < DI) {
          ushort4v r;
          r[0] = f2bf(v[0]); r[1] = f2bf(v[1]); r[2] = f2bf(v[2]); r[3] = f2bf(v[3]);
          *(ushort4v*)&O0h[(size_t)n * DI + m] = r;
        } else {
          ushort4v r;
          r[0] = f2bf(silu_f(v[0])); r[1] = f2bf(silu_f(v[1]));
          r[2] = f2bf(silu_f(v[2])); r[3] = f2bf(silu_f(v[3]));
          *(ushort4v*)&O1h[(size_t)n * DI + m - DI] = r;
        }
      }
    }
  }
}

// ---------------- conv+silu materialization: xTB[b][l][d] -> xaB[z][t][d] bf16 ----------------
__global__ __launch_bounds__(256) void k_conv_all(const unsigned short* __restrict__ xTB,
                                                  const float* __restrict__ cw_all,
                                                  unsigned short* __restrict__ xaB) {
  int z = blockIdx.z;
  int brn = z >> 1, b = z & 1;
  int d = blockIdx.x * 256 + threadIdx.x;
  int t0 = blockIdx.y * 8;
  const unsigned short* xrow = xTB + (size_t)b * L_SEQ * DI;
  float4 w = *(const float4*)&cw_all[((size_t)brn * DI + d) * 4];
  float xm3 = (t0 >= 3) ? bf2f(xrow[(size_t)map_t(brn, t0 - 3) * DI + d]) : 0.f;
  float xm2 = (t0 >= 2) ? bf2f(xrow[(size_t)map_t(brn, t0 - 2) * DI + d]) : 0.f;
  float xm1 = (t0 >= 1) ? bf2f(xrow[(size_t)map_t(brn, t0 - 1) * DI + d]) : 0.f;
#pragma unroll
  for (int i = 0; i < 8; ++i) {
    int t = t0 + i;
    float xc = bf2f(xrow[(size_t)map_t(brn, t) * DI + d]);
    float xa = silu_f(fmaf(w.w, xc, fmaf(w.z, xm1, fmaf(w.y, xm2, w.x * xm3))));
    xaB[((size_t)z * L_SEQ + t) * DI + d] = f2bf(xa);
    xm3 = xm2; xm2 = xm1; xm1 = xc;
  }
}

// ---------------- xproj MFMA: C[j][t] = sum_d xpw[j][d]*xa[z][t][d] ----------------
__global__ __launch_bounds__(256) void k_xprojm(const unsigned short* __restrict__ xpwB,
                                                const unsigned short* __restrict__ xaB,
                                                unsigned short* __restrict__ dtrB,
                                                float* __restrict__ BC) {
  __shared__ unsigned short As[128 * 32];
  __shared__ unsigned short Bs[128 * 32];
  int z = blockIdx.z;
  int brn = z >> 1;
  int n0 = blockIdx.x * 128;
  int tid = threadIdx.x;
  int lane = tid & 63;
  int wm = (tid >> 6) & 1;
  int wn = tid >> 7;
  int srow = tid >> 2;
  int skof = (tid & 3) * 8;
  int arow0 = srow;       if (arow0 > 79) arow0 = 79;
  int arow1 = srow + 64;  if (arow1 > 79) arow1 = 79;
  int brow0 = n0 + srow;       if (brow0 >= L_SEQ) brow0 = L_SEQ - 1;
  int brow1 = n0 + srow + 64;  if (brow1 >= L_SEQ) brow1 = L_SEQ - 1;
  const unsigned short* A = xpwB + (size_t)brn * 80 * DI;
  const unsigned short* Bm = xaB + (size_t)z * L_SEQ * DI;
  floatx4 zero = {0.f, 0.f, 0.f, 0.f};
  floatx4 acc[4][4];
#pragma unroll
  for (int i = 0; i < 4; ++i)
#pragma unroll
    for (int j = 0; j < 4; ++j) acc[i][j] = zero;
  int ar = wm * 64 + (lane & 15);
  int br = wn * 64 + (lane & 15);
  int kq = (lane >> 4) * 8;
  for (int k0 = 0; k0 < DI; k0 += 32) {
    glds16(&A[(size_t)arow0 * DI + k0 + skof], &As[tid * 8]);
    glds16(&A[(size_t)arow1 * DI + k0 + skof], &As[tid * 8 + 2048]);
    glds16(&Bm[(size_t)brow0 * DI + k0 + skof], &Bs[tid * 8]);
    glds16(&Bm[(size_t)brow1 * DI + k0 + skof], &Bs[tid * 8 + 2048]);
    __syncthreads();
    short8 a[4], b[4];
#pragma unroll
    for (int i = 0; i < 4; ++i) a[i] = *(const short8*)&As[(ar + i * 16) * 32 + kq];
#pragma unroll
    for (int i = 0; i < 4; ++i) b[i] = *(const short8*)&Bs[(br + i * 16) * 32 + kq];
#pragma unroll
    for (int mt = 0; mt < 4; ++mt)
#pragma unroll
      for (int nt = 0; nt < 4; ++nt)
        acc[mt][nt] = __builtin_amdgcn_mfma_f32_16x16x32_bf16(a[mt], b[nt], acc[mt][nt], 0, 0, 0);
    __syncthreads();
  }
  int mq = wm * 64 + ((lane >> 4) << 2);
  int nq = n0 + wn * 64 + (lane & 15);
#pragma unroll
  for (int nt = 0; nt < 4; ++nt) {
    int t = nq + nt * 16;
    if (t >= L_SEQ) continue;
#pragma unroll
    for (int mt = 0; mt < 4; ++mt) {
      int j = mq + mt * 16;
      if (j >= 80) continue;
      floatx4 v = acc[mt][nt];
      if (j < 48) {
        ushort4v r;
        r[0] = f2bf(v[0]); r[1] = f2bf(v[1]); r[2] = f2bf(v[2]); r[3] = f2bf(v[3]);
        *(ushort4v*)&dtrB[((size_t)z * L_SEQ + t) * DTRK + j] = r;
      } else {
#pragma unroll
        for (int r = 0; r < 4; ++r)
          BC[((size_t)z * 32 + (j + r - 48)) * L_SEQ + t] = v[r];
      }
    }
  }
}

// ---------------- delta GEMM (MFMA, K=48 padded to 64) + softplus -> bf16 [z][t][d]
__global__ __launch_bounds__(256) void k_dtg(const unsigned short* __restrict__ dpwB,
                                             const unsigned short* __restrict__ dtrB,
                                             const float* __restrict__ dbias,
                                             unsigned short* __restrict__ dT) {
  __shared__ unsigned short As[128 * 64];
  __shared__ unsigned short Bs[128 * 64];
  int z = blockIdx.z;
  int brn = z >> 1;
  int m0 = blockIdx.y * 128;
  int n0 = blockIdx.x * 128;
  int tid = threadIdx.x;
  int lane = tid & 63;
  int wm = (tid >> 6) & 1;
  int wn = tid >> 7;
  {
    int zr = tid >> 1, zc = 48 + (tid & 1) * 8;
    ushort8 zz = {0, 0, 0, 0, 0, 0, 0, 0};
    *(ushort8*)&As[zr * 64 + zc] = zz;
    *(ushort8*)&Bs[zr * 64 + zc] = zz;
  }
  {
    int row = tid >> 1;
    int p0 = (tid & 1) * 3;
    const unsigned short* Ag = dpwB + (size_t)brn * DI * DTRK + (size_t)(m0 + row) * DTRK;
    int bro = n0 + row; if (bro > L_SEQ - 1) bro = L_SEQ - 1;
    const unsigned short* Bg = dtrB + ((size_t)z * L_SEQ + bro) * DTRK;
#pragma unroll
    for (int i = 0; i < 3; ++i) {
      int off = (p0 + i) * 8;
      *(ushort8*)&As[row * 64 + off] = *(const ushort8*)&Ag[off];
      *(ushort8*)&Bs[row * 64 + off] = *(const ushort8*)&Bg[off];
    }
  }
  __syncthreads();
  int ar = wm * 64 + (lane & 15);
  int brr = wn * 64 + (lane & 15);
  int kq = (lane >> 4) * 8;
  floatx4 zero = {0.f, 0.f, 0.f, 0.f};
  floatx4 acc[4][4];
#pragma unroll
  for (int i = 0; i < 4; ++i)
#pragma unroll
    for (int j = 0; j < 4; ++j) acc[i][j] = zero;
#pragma unroll
  for (int kk = 0; kk < 2; ++kk) {
    short8 a[4], b[4];
#pragma unroll
    for (int i = 0; i < 4; ++i) a[i] = *(const short8*)&As[(ar + i * 16) * 64 + kk * 32 + kq];
#pragma unroll
    for (int i = 0; i < 4; ++i) b[i] = *(const short8*)&Bs[(brr + i * 16) * 64 + kk * 32 + kq];
#pragma unroll
    for (int mt = 0; mt < 4; ++mt)
#pragma unroll
      for (int nt = 0; nt < 4; ++nt)
        acc[mt][nt] = __builtin_amdgcn_mfma_f32_16x16x32_bf16(a[mt], b[nt], acc[mt][nt], 0, 0, 0);
  }
  int mq = m0 + wm * 64 + ((lane >> 4) << 2);
  int nq = n0 + wn * 64 + (lane & 15);
#pragma unroll
  for (int nt = 0; nt < 4; ++nt) {
    int n = nq + nt * 16;
    if (n >= L_SEQ) continue;
#pragma unroll
    for (int mt = 0; mt < 4; ++mt) {
      int m = mq + mt * 16;
      float4 bi = *(const float4*)&dbias[(size_t)brn * DI + m];
      floatx4 v = acc[mt][nt];
      ushort4v r;
      r[0] = f2bf(softplus_f(v[0] + bi.x));
      r[1] = f2bf(softplus_f(v[1] + bi.y));
      r[2] = f2bf(softplus_f(v[2] + bi.z));
      r[3] = f2bf(softplus_f(v[3] + bi.w));
      *(ushort4v*)&dT[((size_t)z * L_SEQ + n) * DI + m] = r;
    }
  }
}

// per-branch incremental time-map parameters (fallback scan3c)
__device__ __forceinline__ void mt_params(int brn, int& per, int& dA, int& dB) {
  if (brn == 0) { per = 1 << 30; dA = 1; dB = 1; }
  else if (brn == 1) { per = 1 << 30; dA = -1; dB = -1; }
  else { per = 5; dA = 800; dB = -3199; }
}

__device__ __forceinline__ void load_a2(const float* __restrict__ A_log, int brn, int d,
                                        float* a2, bool& fastp) {
  fastp = true;
#pragma unroll
  for (int g = 0; g < 4; ++g) {
    float4 v = *(const float4*)&A_log[((size_t)brn * DI + d) * DS + g * 4];
    float av0 = __expf(v.x), av1 = __expf(v.y), av2 = __expf(v.z), av3 = __expf(v.w);
    a2[g * 4 + 0] = -av0 * 1.44269504f; a2[g * 4 + 1] = -av1 * 1.44269504f;
    a2[g * 4 + 2] = -av2 * 1.44269504f; a2[g * 4 + 3] = -av3 * 1.44269504f;
    fastp = fastp && fabsf(av0 - (float)(g * 4 + 1)) < 1e-3f
                  && fabsf(av1 - (float)(g * 4 + 2)) < 1e-3f
                  && fabsf(av2 - (float)(g * 4 + 3)) < 1e-3f
                  && fabsf(av3 - (float)(g * 4 + 4)) < 1e-3f;
  }
}

// ---------------- scan phase 1: per-chunk local state + delta-sum (peeled pipeline) ----------------
__global__ __launch_bounds__(256) void k_scan1c(const unsigned short* __restrict__ xaB,
                                                const unsigned short* __restrict__ dT,
                                                const float* __restrict__ BC,
                                                const float* __restrict__ A_log,
                                                float* __restrict__ hO,
                                                float* __restrict__ Sc) {
  __shared__ float BtS[LC][16];
  int z = blockIdx.z;
  int brn = z >> 1;
  int ch = blockIdx.y;
  int t0 = ch * LC;
  int d = blockIdx.x * 256 + threadIdx.x;
  int tid = threadIdx.x;
  for (int i = tid; i < 320; i += 256) {
    int row = i / 20;
    int c4 = (i % 20) * 4;
    float4 v = *(const float4*)&BC[((size_t)z * 32 + row) * L_SEQ + t0 + c4];
    BtS[c4 + 0][row] = v.x; BtS[c4 + 1][row] = v.y;
    BtS[c4 + 2][row] = v.z; BtS[c4 + 3][row] = v.w;
  }
  float a2[16]; bool fastp;
  load_a2(A_log, brn, d, a2, fastp);
  const unsigned short* pxa = xaB + ((size_t)z * L_SEQ + t0) * DI + d;
  const unsigned short* pdl = dT + ((size_t)z * L_SEQ + t0) * DI + d;
  float2v h2[8];
#pragma unroll
  for (int i = 0; i < 8; ++i) h2[i] = (float2v){0.f, 0.f};
  float S = 0.f;
  __syncthreads();
  float xa = bf2f(*pxa);
  float del = bf2f(*pdl);
  for (int t = 0; t < LC - 1; ++t) {
    float xan = bf2f(pxa[DI]);
    float deln = bf2f(pdl[DI]);
    float dtx = del * xa;
    S += del;
    float2v dc2[8];
    if (fastp) {
      pow_ladder2(exp2f(-del * 1.44269504f), dc2);
    } else {
#pragma unroll
      for (int i = 0; i < 8; ++i)
        dc2[i] = (float2v){exp2f(del * a2[2 * i]), exp2f(del * a2[2 * i + 1])};
    }
    const float2v* B2 = (const float2v*)&BtS[t][0];
    float2v dtx2 = {dtx, dtx};
#pragma unroll
    for (int i = 0; i < 8; ++i)
      h2[i] = __builtin_elementwise_fma(h2[i], dc2[i], dtx2 * B2[i]);
    pxa += DI; pdl += DI;
    xa = xan; del = deln;
  }
  {  // last step (t = LC-1), no prefetch
    float dtx = del * xa;
    S += del;
    float2v dc2[8];
    if (fastp) {
      pow_ladder2(exp2f(-del * 1.44269504f), dc2);
    } else {
#pragma unroll
      for (int i = 0; i < 8; ++i)
        dc2[i] = (float2v){exp2f(del * a2[2 * i]), exp2f(del * a2[2 * i + 1])};
    }
    const float2v* B2 = (const float2v*)&BtS[LC - 1][0];
    float2v dtx2 = {dtx, dtx};
#pragma unroll
    for (int i = 0; i < 8; ++i)
      h2[i] = __builtin_elementwise_fma(h2[i], dc2[i], dtx2 * B2[i]);
  }
  size_t base = (((size_t)z * NCH + ch) * DI + d) * 16;
#pragma unroll
  for (int i = 0; i < 8; ++i) *(float2v*)&hO[base + i * 2] = h2[i];
  Sc[((size_t)z * NCH + ch) * DI + d] = S;
}

// ---------------- scan phase 2: sequential combine over chunks ----------------
__global__ __launch_bounds__(256) void k_scan2c(float* __restrict__ hO,
                                                const float* __restrict__ Sc,
                                                const float* __restrict__ A_log) {
  int idx = blockIdx.x * 256 + threadIdx.x;
  int z = idx / (DI * 16);
  int rem = idx % (DI * 16);
  int brn = z >> 1;
  float a2 = -__expf(A_log[(size_t)brn * DI * DS + rem]) * 1.44269504f;
  float H = 0.f;
  for (int c = 0; c < NCH; ++c) {
    size_t p = ((size_t)z * NCH + c) * (DI * 16) + rem;
    float th = hO[p];
    float P = exp2f(Sc[((size_t)z * NCH + c) * DI + (rem >> 4)] * a2);
    hO[p] = H;
    H = fmaf(P, H, th);
  }
}

// ---------------- scan phase 3 (big-ws): reads xaB, branch-templated, peeled pipeline ----------------
template <int BRN>
__global__ __launch_bounds__(256) void k_scan3x(const unsigned short* __restrict__ xaB,
                                                const unsigned short* __restrict__ dT,
                                                const float* __restrict__ BC,
                                                const float* __restrict__ A_log,
                                                const float* __restrict__ Dp,
                                                const float* __restrict__ hO,
                                                const unsigned short* __restrict__ szTB,
                                                unsigned short* __restrict__ ybuf) {
  __shared__ float BCt[LC][32];
  int b = blockIdx.z;
  int z = BRN * 2 + b;
  int ch = blockIdx.y;
  int t0 = ch * LC;
  int d = blockIdx.x * 256 + threadIdx.x;
  int tid = threadIdx.x;
  for (int i = tid; i < 640; i += 256) {
    int row = i / 20;
    int c4 = (i % 20) * 4;
    float4 v = *(const float4*)&BC[((size_t)z * 32 + row) * L_SEQ + t0 + c4];
    BCt[c4 + 0][row] = v.x; BCt[c4 + 1][row] = v.y;
    BCt[c4 + 2][row] = v.z; BCt[c4 + 3][row] = v.w;
  }
  float a2[16]; bool fastp;
  load_a2(A_log, BRN, d, a2, fastp);
  float Dv = Dp[(size_t)BRN * DI + d];
  float2v h2[8];
  size_t hbase = (((size_t)z * NCH + ch) * DI + d) * 16;
#pragma unroll
  for (int i = 0; i < 8; ++i) h2[i] = *(const float2v*)&hO[hbase + i * 2];
  int mt = map_t(BRN, t0);
  const unsigned short* pxa = xaB + ((size_t)z * L_SEQ + t0) * DI + d;
  const unsigned short* pdl = dT + ((size_t)z * L_SEQ + t0) * DI + d;
  const unsigned short* psz = szTB + ((size_t)b * L_SEQ + mt) * DI + d;
  unsigned short* pyb = ybuf + ((size_t)b * L_SEQ + mt) * (3 * DI) + BRN * DI + d;
  int p5 = t0 % 5;  // only used when BRN == 2
  __syncthreads();
  float xa = bf2f(*pxa);
  float del = bf2f(*pdl);
  float sz = bf2f(*psz);
  for (int t = 0; t < LC - 1; ++t) {
    int stepS;
    if (BRN == 0) stepS = DI;
    else if (BRN == 1) stepS = -DI;
    else {
      ++p5;
      if (p5 == 5) { p5 = 0; stepS = -3199 * DI; }
      else stepS = 800 * DI;
    }
    float xan = bf2f(pxa[DI]);
    float deln = bf2f(pdl[DI]);
    float szn;
    if (BRN == 0) szn = bf2f(psz[DI]);
    else if (BRN == 1) szn = bf2f(psz[-DI]);
    else szn = bf2f(psz[stepS]);
    float dtx = del * xa;
    float2v dc2[8];
    if (fastp) {
      pow_ladder2(exp2f(-del * 1.44269504f), dc2);
    } else {
#pragma unroll
      for (int i = 0; i < 8; ++i)
        dc2[i] = (float2v){exp2f(del * a2[2 * i]), exp2f(del * a2[2 * i + 1])};
    }
    const float2v* B2 = (const float2v*)&BCt[t][0];
    const float2v* C2 = (const float2v*)&BCt[t][16];
    float2v dtx2 = {dtx, dtx};
    float2v y2 = {0.f, 0.f};
#pragma unroll
    for (int i = 0; i < 8; ++i) {
      h2[i] = __builtin_elementwise_fma(h2[i], dc2[i], dtx2 * B2[i]);
      y2 = __builtin_elementwise_fma(h2[i], C2[i], y2);
    }
    float y = y2[0] + y2[1] + Dv * xa;
    *pyb = f2bf(y * sz);
    pxa += DI; pdl += DI; psz += stepS; pyb += stepS * 3;
    xa = xan; del = deln; sz = szn;
  }
  {  // last step, no prefetch
    float dtx = del * xa;
    float2v dc2[8];
    if (fastp) {
      pow_ladder2(exp2f(-del * 1.44269504f), dc2);
    } else {
#pragma unroll
      for (int i = 0; i < 8; ++i)
        dc2[i] = (float2v){exp2f(del * a2[2 * i]), exp2f(del * a2[2 * i + 1])};
    }
    const float2v* B2 = (const float2v*)&BCt[LC - 1][0];
    const float2v* C2 = (const float2v*)&BCt[LC - 1][16];
    float2v dtx2 = {dtx, dtx};
    float2v y2 = {0.f, 0.f};
#pragma unroll
    for (int i = 0; i < 8; ++i) {
      h2[i] = __builtin_elementwise_fma(h2[i], dc2[i], dtx2 * B2[i]);
      y2 = __builtin_elementwise_fma(h2[i], C2[i], y2);
    }
    float y = y2[0] + y2[1] + Dv * xa;
    *pyb = f2bf(y * sz);
  }
}

// ---------------- scan phase 3 (fallback, small ws): conv recompute — round-8 proven ----------------
__global__ __launch_bounds__(256) void k_scan3c(const unsigned short* __restrict__ xTB,
                                                const unsigned short* __restrict__ dT,
                                                const float* __restrict__ BC,
                                                const float* __restrict__ cw_all,
                                                const float* __restrict__ A_log,
                                                const float* __restrict__ Dp,
                                                const float* __restrict__ hO,
                                                const unsigned short* __restrict__ szTB,
                                                unsigned short* __restrict__ ybuf) {
  __shared__ float BCt[LC][32];
  int z = blockIdx.z;
  int brn = z >> 1, b = z & 1;
  int ch = blockIdx.y;
  int t0 = ch * LC;
  int d = blockIdx.x * 256 + threadIdx.x;
  int tid = threadIdx.x;
  for (int i = tid; i < 640; i += 256) {
    int row = i / 20;
    int c4 = (i % 20) * 4;
    float4 v = *(const float4*)&BC[((size_t)z * 32 + row) * L_SEQ + t0 + c4];
    BCt[c4 + 0][row] = v.x; BCt[c4 + 1][row] = v.y;
    BCt[c4 + 2][row] = v.z; BCt[c4 + 3][row] = v.w;
  }
  float4 w = *(const float4*)&cw_all[((size_t)brn * DI + d) * 4];
  float a2[16]; bool fastp;
  load_a2(A_log, brn, d, a2, fastp);
  float Dv = Dp[(size_t)brn * DI + d];
  const unsigned short* xrow = xTB + (size_t)b * L_SEQ * DI;
  const unsigned short* drow = dT + (size_t)z * L_SEQ * DI;
  const unsigned short* szrow = szTB + (size_t)b * L_SEQ * DI;
  float2v h2[8];
  size_t hbase = (((size_t)z * NCH + ch) * DI + d) * 16;
#pragma unroll
  for (int i = 0; i < 8; ++i) h2[i] = *(const float2v*)&hO[hbase + i * 2];
  int per, dA, dB;
  mt_params(brn, per, dA, dB);
  int p5 = t0 % 5;
  int mt = map_t(brn, t0);
  __syncthreads();
  float xm3 = (t0 >= 3) ? bf2f(xrow[(size_t)map_t(brn, t0 - 3) * DI + d]) : 0.f;
  float xm2 = (t0 >= 2) ? bf2f(xrow[(size_t)map_t(brn, t0 - 2) * DI + d]) : 0.f;
  float xm1 = (t0 >= 1) ? bf2f(xrow[(size_t)map_t(brn, t0 - 1) * DI + d]) : 0.f;
  float xc  = bf2f(xrow[(size_t)mt * DI + d]);
  float del = bf2f(drow[(size_t)t0 * DI + d]);
  float sz  = bf2f(szrow[(size_t)mt * DI + d]);
  for (int t = 0; t < LC; ++t) {
    int p5n = p5 + 1;
    int mtn = (p5n == per) ? mt + dB : mt + dA;
    if (p5n == per) p5n = 0;
    float xn = 0.f, deln = 0.f, szn = 0.f;
    if (t + 1 < LC) {
      xn = bf2f(xrow[(size_t)mtn * DI + d]);
      deln = bf2f(drow[(size_t)(t0 + t + 1) * DI + d]);
      szn = bf2f(szrow[(size_t)mtn * DI + d]);
    }
    float xa = silu_f(fmaf(w.w, xc, fmaf(w.z, xm1, fmaf(w.y, xm2, w.x * xm3))));
    float dtx = del * xa;
    float2v dc2[8];
    if (fastp) {
      pow_ladder2(exp2f(-del * 1.44269504f), dc2);
    } else {
#pragma unroll
      for (int i = 0; i < 8; ++i)
        dc2[i] = (float2v){exp2f(del * a2[2 * i]), exp2f(del * a2[2 * i + 1])};
    }
    const float2v* B2 = (const float2v*)&BCt[t][0];
    const float2v* C2 = (const float2v*)&BCt[t][16];
    float2v dtx2 = {dtx, dtx};
    float2v y2 = {0.f, 0.f};
#pragma unroll
    for (int i = 0; i < 8; ++i) {
      h2[i] = __builtin_elementwise_fma(h2[i], dc2[i], dtx2 * B2[i]);
      y2 = __builtin_elementwise_fma(h2[i], C2[i], y2);
    }
    float y = y2[0] + y2[1] + Dv * xa;
    ybuf[((size_t)b * L_SEQ + mt) * (3 * DI) + (size_t)brn * DI + d] = f2bf(y * sz);
    xm3 = xm2; xm2 = xm1; xm1 = xc; xc = xn; del = deln; sz = szn; mt = mtn; p5 = p5n;
  }
}

extern "C" void kernel_launch(void* const* d_in, const int* in_sizes, int n_in,
                              void* d_out, int out_size, void* d_ws, size_t ws_size,
                              hipStream_t stream) {
  const float* hs        = (const float*)d_in[0];
  const float* in_proj_w = (const float*)d_in[1];
  const float* conv_w    = (const float*)d_in[2];
  const float* x_proj_w  = (const float*)d_in[3];
  const float* dt_proj_w = (const float*)d_in[4];
  const float* dt_bias   = (const float*)d_in[5];
  const float* A_log     = (const float*)d_in[6];
  const float* D_param   = (const float*)d_in[7];
  const float* out_proj_w= (const float*)d_in[8];
  float* out = (float*)d_out;
  float* ws = (float*)d_ws;

  unsigned short* xTB  = (unsigned short*)(ws);             // 12,288,000 sh
  unsigned short* szTB = (unsigned short*)(ws + 6144000);   // 12,288,000 sh
  unsigned short* dtrB = (unsigned short*)(ws + 12288000);  // 1,152,000 sh
  float* BC            = ws + 12864000;                     // 768,000 f
  unsigned short* dT   = (unsigned short*)(ws + 13632000);  // 36,864,000 sh
  float* hO            = ws + 32064000;                     // 7,372,800 f
  float* Sc            = ws + 39436800;                     // 460,800 f
  unsigned short* dpwB = (unsigned short*)(ws + 39897600);  // 221,184 sh
  unsigned short* OWb  = (unsigned short*)(ws + 40008192);  // 1,179,648 sh
  // region R (disjoint lifetimes): {hsB, Wb} -> {xaB} [-> {ybuf} in small-ws fallback]
  unsigned short* hsB  = (unsigned short*)(ws + 40598016);  // 6,144,000 sh
  unsigned short* Wb   = hsB + 6144000;                     // 2,359,296 sh
  unsigned short* xaB  = (unsigned short*)(ws + 40598016);  // 36,864,000 sh
  unsigned short* xpwB = (unsigned short*)(ws + 59030016);  // 368,640 sh
  // big-ws path: separate ybuf keeps xaB alive for scan3x (needs 310.6 MB total)
  unsigned short* ybufBig = (unsigned short*)(ws + 59214336);  // 36,864,000 sh
  bool big = ws_size >= (size_t)77646336 * 4;
  unsigned short* ybuf = big ? ybufBig : xaB;

  k_cast5<<<5016, 256, 0, stream>>>(hs, hsB, in_proj_w, Wb, out_proj_w, OWb,
                                    dt_proj_w, dpwB, x_proj_w, xpwB);

  k_gemm_bt<DM, DM, 1><<<dim3(63, 24), 256, 0, stream>>>(Wb, hsB, nullptr, xTB, szTB);

  k_conv_all<<<dim3(6, 500, 6), 256, 0, stream>>>(xTB, conv_w, xaB);
  k_xprojm<<<dim3(32, 1, 6), 256, 0, stream>>>(xpwB, xaB, dtrB, BC);
  k_dtg<<<dim3(32, 12, 6), 256, 0, stream>>>(dpwB, dtrB, dt_bias, dT);

  k_scan1c<<<dim3(6, NCH, 6), 256, 0, stream>>>(xaB, dT, BC, A_log, hO, Sc);
  k_scan2c<<<576, 256, 0, stream>>>(hO, Sc, A_log);
  if (big) {
    k_scan3x<0><<<dim3(6, NCH, 2), 256, 0, stream>>>(xaB, dT, BC, A_log, D_param, hO, szTB, ybuf);
    k_scan3x<1><<<dim3(6, NCH, 2), 256, 0, stream>>>(xaB, dT, BC, A_log, D_param, hO, szTB, ybuf);
    k_scan3x<2><<<dim3(6, NCH, 2), 256, 0, stream>>>(xaB, dT, BC, A_log, D_param, hO, szTB, ybuf);
  } else {
    // fallback: ybuf aliases xaB; scan3c recomputes conv from xTB (round-8 proven path)
    k_scan3c<<<dim3(6, NCH, 6), 256, 0, stream>>>(xTB, dT, BC, conv_w, A_log, D_param,
                                                  hO, szTB, ybuf);
  }

  k_gemm_bt<3 * DI, DI, 0><<<dim3(6, 63), 256, 0, stream>>>(OWb, ybuf, out, nullptr, nullptr);
}